// Round 9
// baseline (435.018 us; speedup 1.0000x reference)
//
#include <hip/hip_runtime.h>

#define B_ 8
#define N_ 8192
#define S_ 2048
#define D1_ 128
#define D2_ 256
#define C0_ 384
#define C1_ 256
#define C2_ 128
#define BN_EPS 1e-5f

typedef unsigned long long ull;
typedef unsigned short u16;
typedef __bf16 bf16x8 __attribute__((ext_vector_type(8)));
typedef float f32x4 __attribute__((ext_vector_type(4)));
typedef short short8_ __attribute__((ext_vector_type(8)));

__device__ __forceinline__ u16 f2bf(float x) {
  unsigned int u = __float_as_uint(x);
  unsigned int r = u + 0x7fffu + ((u >> 16) & 1u);
  return (u16)(r >> 16);
}
__device__ __forceinline__ float bf2f(u16 h) {
  return __uint_as_float(((unsigned int)h) << 16);
}

// async global->LDS DMA, 16B/lane. LDS dest wave-uniform (HW adds lane*16);
// global src per-lane. This round: src is CONTIGUOUS per wave (1KB linear).
__device__ __forceinline__ void gld16(const void* g, void* l) {
  __builtin_amdgcn_global_load_lds(
      (const __attribute__((address_space(1))) void*)g,
      (__attribute__((address_space(3))) void*)l,
      16, 0, 0);
}

// branchless sorted-insert of key k into ascending top-3 (k0<=k1<=k2)
__device__ __forceinline__ void ins3(ull k, ull& k0, ull& k1, ull& k2) {
  ull t = k < k2 ? k : k2;
  ull u = k1 < t ? k1 : t;
  k2 = k1 < t ? t : k1;
  k1 = k0 < u ? u : k0;
  k0 = k0 < u ? k0 : u;
}

// ---------------------------------------------------------------------------
// weights f32 [O][K] -> bf16 k-chunked [K/32][O][32]
// ---------------------------------------------------------------------------
__global__ void cvtW_kernel(const float* __restrict__ src, u16* __restrict__ dst,
                            int O, int K)
{
  int i = blockIdx.x * blockDim.x + threadIdx.x;
  if (i < O * K) {
    int o = i / K, kk = i - o * K;
    dst[(((size_t)(kk >> 5) * O + o) << 5) + (kk & 31)] = f2bf(src[i]);
  }
}

// ---------------------------------------------------------------------------
// transpose points_now [B][D2][S] -> pnT [B][S][D2]  (fp32, for knn gather)
// ---------------------------------------------------------------------------
__global__ __launch_bounds__(256) void transpose_kernel(
    const float* __restrict__ in, float* __restrict__ out)
{
  __shared__ float tile[32][33];
  const int b  = blockIdx.z;
  const int s0 = blockIdx.x * 32;
  const int d0 = blockIdx.y * 32;
  const int tx = threadIdx.x & 31, ty = threadIdx.x >> 5;

  const float* inb = in + ((size_t)b * D2_ + d0) * S_ + s0;
  #pragma unroll
  for (int r = 0; r < 4; ++r) {
    int d = r * 8 + ty;
    tile[d][tx] = inb[(size_t)d * S_ + tx];
  }
  __syncthreads();
  float* outb = out + ((size_t)b * S_ + s0) * D2_ + d0;
  #pragma unroll
  for (int r = 0; r < 4; ++r) {
    int s = r * 8 + ty;
    outb[(size_t)s * D2_ + tx] = tile[tx][s];
  }
}

// ---------------------------------------------------------------------------
// points_sa [B][D1][N] f32 -> xcat chunks 0..3  ([12][N][32] per batch, bf16)
// block handles 32 n x 32 d (one chunk)
// ---------------------------------------------------------------------------
__global__ __launch_bounds__(256) void psaT_kernel(
    const float* __restrict__ in, u16* __restrict__ xcat)
{
  __shared__ float tile[32][33];
  const int b  = blockIdx.z;
  const int n0 = blockIdx.x * 32;
  const int d0 = blockIdx.y * 32;     // chunk = d0>>5
  const int tx = threadIdx.x & 31, ty = threadIdx.x >> 5;

  const float* inb = in + ((size_t)b * D1_ + d0) * N_ + n0;
  #pragma unroll
  for (int r = 0; r < 4; ++r) {
    int d = r * 8 + ty;
    tile[d][tx] = inb[(size_t)d * N_ + tx];
  }
  __syncthreads();
  u16* outb = xcat + (((size_t)b * 12 + (d0 >> 5)) * N_ + n0) * 32;
  #pragma unroll
  for (int r = 0; r < 4; ++r) {
    int n = r * 8 + ty;
    outb[(size_t)n * 32 + tx] = f2bf(tile[tx][n]);   // 64B full lines per n
  }
}

// ---------------------------------------------------------------------------
// K1: 3-NN + interpolation. 128 queries/block. Writes xcat chunks 4..11.
// ---------------------------------------------------------------------------
__global__ __launch_bounds__(256) void knn_interp_kernel(
    const float* __restrict__ xyz_sa, const float* __restrict__ xyz_now,
    const float* __restrict__ pnT, u16* __restrict__ xcat)
{
  __shared__ float4 sp[S_];
  __shared__ int   s_idx[128][3];
  __shared__ float s_w[128][3];

  const int b  = blockIdx.y;
  const int n0 = blockIdx.x * 128;

  const float* xb = xyz_now + (size_t)b * 3 * S_;
  for (int i = threadIdx.x; i < S_; i += 256) {
    float px = xb[i], py = xb[S_ + i], pz = xb[2 * S_ + i];
    sp[i] = make_float4(px, py, pz, px * px + py * py + pz * pz);
  }
  __syncthreads();

  const int qg = threadIdx.x >> 3;   // 0..31 query group (4 queries)
  const int t  = threadIdx.x & 7;    // scanner 0..7
  const int nb = n0 + qg * 4;

  const float* xq = xyz_sa + (size_t)b * 3 * N_;
  float qx[4], qy[4], qz[4], qq[4];
  #pragma unroll
  for (int w = 0; w < 4; ++w) {
    int n = nb + w;
    qx[w] = xq[n]; qy[w] = xq[N_ + n]; qz[w] = xq[2 * N_ + n];
    qq[w] = qx[w] * qx[w] + qy[w] * qy[w] + qz[w] * qz[w];
  }

  ull K0[4], K1[4], K2[4];
  #pragma unroll
  for (int w = 0; w < 4; ++w) { K0[w] = ~0ull; K1[w] = ~0ull; K2[w] = ~0ull; }

  #pragma unroll 2
  for (int it = 0; it < S_ / 8; ++it) {
    int s = (it << 3) | t;
    float4 p = sp[s];
    #pragma unroll
    for (int w = 0; w < 4; ++w) {
      float dot = qx[w] * p.x + qy[w] * p.y + qz[w] * p.z;
      float d = qq[w] - 2.0f * dot + p.w;
      unsigned int bits = __float_as_uint(d);
      unsigned int u = bits ^ (0x80000000u | (unsigned int)((int)bits >> 31));
      ull k = ((ull)u << 32) | (unsigned int)s;
      ins3(k, K0[w], K1[w], K2[w]);
    }
  }

  #pragma unroll
  for (int m = 1; m <= 4; m <<= 1) {
    #pragma unroll
    for (int w = 0; w < 4; ++w) {
      ull o0 = __shfl_xor(K0[w], m), o1 = __shfl_xor(K1[w], m), o2 = __shfl_xor(K2[w], m);
      ins3(o0, K0[w], K1[w], K2[w]);
      ins3(o1, K0[w], K1[w], K2[w]);
      ins3(o2, K0[w], K1[w], K2[w]);
    }
  }

  if (t == 0) {
    #pragma unroll
    for (int w = 0; w < 4; ++w) {
      unsigned int u0 = (unsigned int)(K0[w] >> 32);
      unsigned int u1 = (unsigned int)(K1[w] >> 32);
      unsigned int u2 = (unsigned int)(K2[w] >> 32);
      float d0 = __uint_as_float(u0 ^ (0x80000000u | ~(unsigned int)((int)u0 >> 31)));
      float d1 = __uint_as_float(u1 ^ (0x80000000u | ~(unsigned int)((int)u1 >> 31)));
      float d2 = __uint_as_float(u2 ^ (0x80000000u | ~(unsigned int)((int)u2 >> 31)));
      float r0 = 1.0f / (d0 + 1e-8f);
      float r1 = 1.0f / (d1 + 1e-8f);
      float r2 = 1.0f / (d2 + 1e-8f);
      float rs = 1.0f / (r0 + r1 + r2);
      int qi = qg * 4 + w;
      s_idx[qi][0] = (int)(K0[w] & 0xFFFFFFFFu);
      s_idx[qi][1] = (int)(K1[w] & 0xFFFFFFFFu);
      s_idx[qi][2] = (int)(K2[w] & 0xFFFFFFFFu);
      s_w[qi][0] = r0 * rs; s_w[qi][1] = r1 * rs; s_w[qi][2] = r2 * rs;
    }
  }
  __syncthreads();

  // Phase 2: wave-per-query gather. Lane l covers channels (l>>3)*32+(l&7)*4
  // (chunk 4+(l>>3)); per (qi,chunk) the 8 lanes write one full 64B line.
  const int wave = threadIdx.x >> 6;
  const int lane = threadIdx.x & 63;
  const int c8 = lane >> 3;          // 0..7 -> chunk 4+c8
  const int k4 = (lane & 7) * 4;     // within-chunk channel offset
  const float* pb = pnT + (size_t)b * S_ * D2_ + c8 * 32 + k4;
  u16* ob = xcat + (((size_t)b * 12 + 4 + c8) * N_ + n0) * 32 + k4;
  #pragma unroll 2
  for (int i = 0; i < 32; ++i) {
    const int qi = wave * 32 + i;
    const int j0 = s_idx[qi][0], j1 = s_idx[qi][1], j2 = s_idx[qi][2];
    const float w0 = s_w[qi][0], w1 = s_w[qi][1], w2 = s_w[qi][2];
    float4 f0 = *(const float4*)(pb + (size_t)j0 * D2_);
    float4 f1 = *(const float4*)(pb + (size_t)j1 * D2_);
    float4 f2 = *(const float4*)(pb + (size_t)j2 * D2_);
    float rx = w0 * f0.x + w1 * f1.x + w2 * f2.x;
    float ry = w0 * f0.y + w1 * f1.y + w2 * f2.y;
    float rz = w0 * f0.z + w1 * f1.z + w2 * f2.z;
    float rw = w0 * f0.w + w1 * f1.w + w2 * f2.w;
    unsigned int lo = (unsigned int)f2bf(rx) | ((unsigned int)f2bf(ry) << 16);
    unsigned int hi = (unsigned int)f2bf(rz) | ((unsigned int)f2bf(rw) << 16);
    *(uint2*)(ob + (size_t)qi * 32) = make_uint2(lo, hi);
  }
}

// ---------------------------------------------------------------------------
union SMg {
  struct { u16 As[2][4096]; u16 Bs[2][4096]; } p;   // [128 rows][32 k] x dbuf
  u16 stage[128][136];
};

// ---------------------------------------------------------------------------
// GEMM1 (m97, contiguous DMA): y0[b,n,o] = W0 . xcat + b0; k-chunked in/out.
// ---------------------------------------------------------------------------
__global__ __launch_bounds__(256) void gemm1_mfma_kernel(
    const u16* __restrict__ xcat, const u16* __restrict__ W0b,
    const float* __restrict__ b0, u16* __restrict__ y0b, float* __restrict__ stats)
{
  __shared__ SMg sm;

  const int bz = blockIdx.z;
  const int n0 = blockIdx.x * 128;
  const int o0 = blockIdx.y * 128;
  const int tid = threadIdx.x;
  const int wid = tid >> 6, lane = tid & 63;
  const int wo = wid & 1, wn = wid >> 1;
  const int m = lane & 15, g = lane >> 4;

  f32x4 acc[4][4];
  #pragma unroll
  for (int i = 0; i < 4; ++i)
    #pragma unroll
    for (int j = 0; j < 4; ++j) acc[i][j] = (f32x4){0.f, 0.f, 0.f, 0.f};

  // chunk c: A panel = W0b[(c*256+o0)*32 ..] 8KB contig; B = xcat panel 8KB contig
  auto STAGE = [&](int buf, int c) {
    const u16* asrc = W0b  + ((size_t)c * C1_ + o0) * 32;
    const u16* bsrc = xcat + (((size_t)bz * 12 + c) * N_ + n0) * 32;
    #pragma unroll
    for (int i2 = 0; i2 < 2; ++i2) {
      const int i = wid * 2 + i2;          // 1KB slice i of the 8KB panel
      gld16(asrc + i * 512 + lane * 8, &sm.p.As[buf][i * 512]);
      gld16(bsrc + i * 512 + lane * 8, &sm.p.Bs[buf][i * 512]);
    }
  };

  STAGE(0, 0);
  __syncthreads();

  for (int kt = 0; kt < 12; ++kt) {
    const int cur = kt & 1;
    if (kt < 11) STAGE(cur ^ 1, kt + 1);

    bf16x8 af[4], bfv[4];
    #pragma unroll
    for (int f = 0; f < 4; ++f)
      af[f] = __builtin_bit_cast(bf16x8,
          *(const short8_*)&sm.p.As[cur][(wo * 64 + f * 16 + m) * 32 + g * 8]);
    #pragma unroll
    for (int f = 0; f < 4; ++f)
      bfv[f] = __builtin_bit_cast(bf16x8,
          *(const short8_*)&sm.p.Bs[cur][(wn * 64 + f * 16 + m) * 32 + g * 8]);
    #pragma unroll
    for (int i = 0; i < 4; ++i)
      #pragma unroll
      for (int j = 0; j < 4; ++j)
        acc[i][j] = __builtin_amdgcn_mfma_f32_16x16x32_bf16(af[i], bfv[j], acc[i][j], 0, 0, 0);

    __syncthreads();
  }

  // epilogue: bias + stats; stage [n][o] tile; stream out k-chunked full lines
  #pragma unroll
  for (int of = 0; of < 4; ++of) {
    const int ol = wo * 64 + of * 16 + g * 4;
    const int ob = o0 + ol;
    float bias[4], s1[4], s2[4];
    #pragma unroll
    for (int r = 0; r < 4; ++r) { bias[r] = b0[ob + r]; s1[r] = 0.f; s2[r] = 0.f; }
    #pragma unroll
    for (int nf = 0; nf < 4; ++nf) {
      const int nl = wn * 64 + nf * 16 + m;
      float y[4];
      #pragma unroll
      for (int r = 0; r < 4; ++r) {
        y[r] = acc[of][nf][r] + bias[r];
        s1[r] += y[r]; s2[r] += y[r] * y[r];
      }
      unsigned int lo = (unsigned int)f2bf(y[0]) | ((unsigned int)f2bf(y[1]) << 16);
      unsigned int hi = (unsigned int)f2bf(y[2]) | ((unsigned int)f2bf(y[3]) << 16);
      *(uint2*)&sm.stage[nl][ol] = make_uint2(lo, hi);
    }
    #pragma unroll
    for (int mk = 1; mk < 16; mk <<= 1)
      #pragma unroll
      for (int r = 0; r < 4; ++r) {
        s1[r] += __shfl_xor(s1[r], mk);
        s2[r] += __shfl_xor(s2[r], mk);
      }
    if (m == 0) {
      #pragma unroll
      for (int r = 0; r < 4; ++r) {
        atomicAdd(&stats[ob + r], s1[r]);
        atomicAdd(&stats[C1_ + ob + r], s2[r]);
      }
    }
  }
  __syncthreads();
  {
    const int rrow = tid >> 4;
    const int col  = (tid & 15) * 8;             // o within 128-tile
    const int c    = (o0 + col) >> 5;            // y0 chunk
    const int ko   = (o0 + col) & 31;
    u16* dst = y0b + (((size_t)bz * 8 + c) * N_ + n0) * 32 + ko;
    #pragma unroll
    for (int pass = 0; pass < 8; ++pass) {
      const int r = pass * 16 + rrow;
      *(uint4*)(dst + (size_t)r * 32) = *(const uint4*)&sm.stage[r][col];
    }
  }
}

// ---------------------------------------------------------------------------
// BN0 + ReLU elementwise on k-chunked y0 [B][8][N][32] (bf16 -> bf16)
// ---------------------------------------------------------------------------
__global__ __launch_bounds__(256) void bn0relu_kernel(
    const u16* __restrict__ y0b, const float* __restrict__ coef, u16* __restrict__ y0r)
{
  __shared__ float cfa[C1_], cfc[C1_];
  cfa[threadIdx.x] = coef[threadIdx.x];
  cfc[threadIdx.x] = coef[C1_ + threadIdx.x];
  __syncthreads();
  const size_t total8 = (size_t)B_ * N_ * C1_ / 8;
  const size_t stride = (size_t)gridDim.x * blockDim.x;
  for (size_t i = (size_t)blockIdx.x * blockDim.x + threadIdx.x; i < total8; i += stride) {
    uint4 v = *(const uint4*)(y0b + i * 8);
    const int ch = (int)(((i >> 15) & 7) * 32 + ((i * 8) & 31));  // chunk*32 + k
    float f0 = fmaxf(0.f, fmaf(bf2f((u16)(v.x & 0xffff)), cfa[ch + 0], cfc[ch + 0]));
    float f1 = fmaxf(0.f, fmaf(bf2f((u16)(v.x >> 16)),    cfa[ch + 1], cfc[ch + 1]));
    float f2 = fmaxf(0.f, fmaf(bf2f((u16)(v.y & 0xffff)), cfa[ch + 2], cfc[ch + 2]));
    float f3 = fmaxf(0.f, fmaf(bf2f((u16)(v.y >> 16)),    cfa[ch + 3], cfc[ch + 3]));
    float f4 = fmaxf(0.f, fmaf(bf2f((u16)(v.z & 0xffff)), cfa[ch + 4], cfc[ch + 4]));
    float f5 = fmaxf(0.f, fmaf(bf2f((u16)(v.z >> 16)),    cfa[ch + 5], cfc[ch + 5]));
    float f6 = fmaxf(0.f, fmaf(bf2f((u16)(v.w & 0xffff)), cfa[ch + 6], cfc[ch + 6]));
    float f7 = fmaxf(0.f, fmaf(bf2f((u16)(v.w >> 16)),    cfa[ch + 7], cfc[ch + 7]));
    uint4 o;
    o.x = (unsigned int)f2bf(f0) | ((unsigned int)f2bf(f1) << 16);
    o.y = (unsigned int)f2bf(f2) | ((unsigned int)f2bf(f3) << 16);
    o.z = (unsigned int)f2bf(f4) | ((unsigned int)f2bf(f5) << 16);
    o.w = (unsigned int)f2bf(f6) | ((unsigned int)f2bf(f7) << 16);
    *(uint4*)(y0r + i * 8) = o;
  }
}

// ---------------------------------------------------------------------------
// GEMM2 (m97, contiguous DMA): y1b[b,p,n] = W1 . y0r + b1; k-chunked inputs.
// ---------------------------------------------------------------------------
__global__ __launch_bounds__(256) void gemm2_mfma_kernel(
    const u16* __restrict__ y0r, const u16* __restrict__ W1b,
    const float* __restrict__ b1, u16* __restrict__ y1b, float* __restrict__ stats)
{
  __shared__ SMg sm;

  const int bz = blockIdx.z;
  const int n0 = blockIdx.x * 128;
  const int tid = threadIdx.x;
  const int wid = tid >> 6, lane = tid & 63;
  const int wo = wid & 1, wn = wid >> 1;
  const int m = lane & 15, g = lane >> 4;

  f32x4 acc[4][4];
  #pragma unroll
  for (int i = 0; i < 4; ++i)
    #pragma unroll
    for (int j = 0; j < 4; ++j) acc[i][j] = (f32x4){0.f, 0.f, 0.f, 0.f};

  auto STAGE = [&](int buf, int c) {
    const u16* asrc = W1b + ((size_t)c * C2_) * 32;            // 128 p-rows, 8KB
    const u16* bsrc = y0r + (((size_t)bz * 8 + c) * N_ + n0) * 32;
    #pragma unroll
    for (int i2 = 0; i2 < 2; ++i2) {
      const int i = wid * 2 + i2;
      gld16(asrc + i * 512 + lane * 8, &sm.p.As[buf][i * 512]);
      gld16(bsrc + i * 512 + lane * 8, &sm.p.Bs[buf][i * 512]);
    }
  };

  STAGE(0, 0);
  __syncthreads();

  for (int kt = 0; kt < 8; ++kt) {
    const int cur = kt & 1;
    if (kt < 7) STAGE(cur ^ 1, kt + 1);

    bf16x8 af[4], bfv[4];
    #pragma unroll
    for (int f = 0; f < 4; ++f)
      af[f] = __builtin_bit_cast(bf16x8,
          *(const short8_*)&sm.p.As[cur][(wo * 64 + f * 16 + m) * 32 + g * 8]);
    #pragma unroll
    for (int f = 0; f < 4; ++f)
      bfv[f] = __builtin_bit_cast(bf16x8,
          *(const short8_*)&sm.p.Bs[cur][(wn * 64 + f * 16 + m) * 32 + g * 8]);
    #pragma unroll
    for (int i = 0; i < 4; ++i)
      #pragma unroll
      for (int j = 0; j < 4; ++j)
        acc[i][j] = __builtin_amdgcn_mfma_f32_16x16x32_bf16(af[i], bfv[j], acc[i][j], 0, 0, 0);

    __syncthreads();
  }

  // epilogue: stage [p][n] tile (y1b is [B][C2][N]); stats as before
  #pragma unroll
  for (int of = 0; of < 4; ++of) {
    const int pb = wo * 64 + of * 16 + g * 4;
    float bias[4], s1[4], s2[4];
    #pragma unroll
    for (int r = 0; r < 4; ++r) { bias[r] = b1[pb + r]; s1[r] = 0.f; s2[r] = 0.f; }
    #pragma unroll
    for (int nf = 0; nf < 4; ++nf) {
      const int nl = wn * 64 + nf * 16 + m;
      #pragma unroll
      for (int r = 0; r < 4; ++r) {
        float y = acc[of][nf][r] + bias[r];
        s1[r] += y; s2[r] += y * y;
        sm.stage[pb + r][nl] = f2bf(y);
      }
    }
    #pragma unroll
    for (int mk = 1; mk < 16; mk <<= 1)
      #pragma unroll
      for (int r = 0; r < 4; ++r) {
        s1[r] += __shfl_xor(s1[r], mk);
        s2[r] += __shfl_xor(s2[r], mk);
      }
    if (m == 0) {
      #pragma unroll
      for (int r = 0; r < 4; ++r) {
        atomicAdd(&stats[pb + r], s1[r]);
        atomicAdd(&stats[C2_ + pb + r], s2[r]);
      }
    }
  }
  __syncthreads();
  {
    #pragma unroll
    for (int pass = 0; pass < 8; ++pass) {
      const int idx = pass * 256 + tid;
      const int p = idx >> 4;
      const int c8 = (idx & 15) * 8;
      uint4 v = *(const uint4*)&sm.stage[p][c8];
      *(uint4*)(y1b + ((size_t)bz * C2_ + p) * N_ + n0 + c8) = v;
    }
  }
}

// ---------------------------------------------------------------------------
__global__ void bn_coef_kernel(const float* __restrict__ g, const float* __restrict__ be,
                               const float* __restrict__ stats, float* __restrict__ coef,
                               int C)
{
  int o = threadIdx.x;
  if (o < C) {
    const float invM = 1.0f / 65536.0f;   // B*N
    float mean = stats[o] * invM;
    float var  = stats[C + o] * invM - mean * mean;
    float a = g[o] / sqrtf(var + BN_EPS);
    float c = be[o] - mean * a;
    coef[o] = a;
    coef[C + o] = c;
  }
}

__global__ void zero_kernel(float* __restrict__ p, int n)
{
  int i = blockIdx.x * blockDim.x + threadIdx.x;
  if (i < n) p[i] = 0.0f;
}

// ---------------------------------------------------------------------------
// final: BN1 + ReLU elementwise, bf16 in -> fp32 out  (y1b is [B][C2][N])
// ---------------------------------------------------------------------------
__global__ __launch_bounds__(256) void final_kernel(
    const u16* __restrict__ y1b, const float* __restrict__ cf, float* __restrict__ out)
{
  const size_t total4 = (size_t)B_ * C2_ * N_ / 4;
  const size_t stride = (size_t)gridDim.x * blockDim.x;
  for (size_t f = (size_t)blockIdx.x * blockDim.x + threadIdx.x; f < total4; f += stride) {
    size_t base = f * 4;
    int p = (int)((base >> 13) & (C2_ - 1));
    float a = cf[p], c = cf[C2_ + p];
    uint2 v = *(const uint2*)(y1b + base);
    float4 r;
    r.x = fmaxf(0.0f, fmaf(bf2f((u16)(v.x & 0xffff)), a, c));
    r.y = fmaxf(0.0f, fmaf(bf2f((u16)(v.x >> 16)),    a, c));
    r.z = fmaxf(0.0f, fmaf(bf2f((u16)(v.y & 0xffff)), a, c));
    r.w = fmaxf(0.0f, fmaf(bf2f((u16)(v.y >> 16)),    a, c));
    *(float4*)(out + base) = r;
  }
}

// ---------------------------------------------------------------------------
extern "C" void kernel_launch(void* const* d_in, const int* in_sizes, int n_in,
                              void* d_out, int out_size, void* d_ws, size_t ws_size,
                              hipStream_t stream)
{
  const float* xyz_sa     = (const float*)d_in[0];
  const float* xyz_now    = (const float*)d_in[1];
  const float* points_sa  = (const float*)d_in[2];
  const float* points_now = (const float*)d_in[3];
  const float* W0  = (const float*)d_in[4];
  const float* b0  = (const float*)d_in[5];
  const float* g0  = (const float*)d_in[6];
  const float* be0 = (const float*)d_in[7];
  const float* W1  = (const float*)d_in[8];
  const float* b1  = (const float*)d_in[9];
  const float* g1  = (const float*)d_in[10];
  const float* be1 = (const float*)d_in[11];

  const size_t MB = 1048576ull;
  char* base = (char*)d_ws;
  u16*   xcat  = (u16*)(base + 0);            // [B][12][N][32] bf16  48MB
  u16*   y0r   = (u16*)(base + 0);            // [B][8][N][32] bf16   32MB (xcat dead)
  float* pnT   = (float*)(base + 48 * MB);    // [B][S][256] f32      16MB (dead after knn)
  u16*   y1b   = (u16*)(base + 48 * MB);      // [B][C2][N] bf16      16MB (overlays pnT)
  u16*   y0b   = (u16*)(base + 64 * MB);      // [B][8][N][32] bf16   32MB
  u16*   W0b   = (u16*)(base + 96 * MB);      // [12][256][32] bf16
  u16*   W1b   = (u16*)(base + 96 * MB + 512 * 1024); // [8][128][32] bf16
  float* stats = (float*)(base + 97 * MB);    // 768 f
  float* coef  = stats + 768;                 // 768 f
  float* out   = (float*)d_out;

  hipLaunchKernelGGL(zero_kernel, dim3(1), dim3(768), 0, stream, stats, 768);
  hipLaunchKernelGGL(cvtW_kernel, dim3((C1_ * C0_ + 255) / 256), dim3(256), 0, stream,
                     W0, W0b, C1_, C0_);
  hipLaunchKernelGGL(cvtW_kernel, dim3((C2_ * C1_ + 255) / 256), dim3(256), 0, stream,
                     W1, W1b, C2_, C1_);
  hipLaunchKernelGGL(transpose_kernel, dim3(S_ / 32, D2_ / 32, B_), dim3(256), 0, stream,
                     points_now, pnT);
  hipLaunchKernelGGL(psaT_kernel, dim3(N_ / 32, D1_ / 32, B_), dim3(256), 0, stream,
                     points_sa, xcat);
  hipLaunchKernelGGL(knn_interp_kernel, dim3(N_ / 128, B_), dim3(256), 0, stream,
                     xyz_sa, xyz_now, pnT, xcat);
  hipLaunchKernelGGL(gemm1_mfma_kernel, dim3(N_ / 128, 2, B_), dim3(256), 0, stream,
                     xcat, W0b, b0, y0b, stats);
  hipLaunchKernelGGL(bn_coef_kernel, dim3(1), dim3(256), 0, stream,
                     g0, be0, stats, coef, C1_);
  hipLaunchKernelGGL(bn0relu_kernel, dim3(2048), dim3(256), 0, stream,
                     y0b, coef, y0r);
  hipLaunchKernelGGL(gemm2_mfma_kernel, dim3(N_ / 128, 1, B_), dim3(256), 0, stream,
                     y0r, W1b, b1, y1b, stats + 512);
  hipLaunchKernelGGL(bn_coef_kernel, dim3(1), dim3(128), 0, stream,
                     g1, be1, stats + 512, coef + 512, C2_);
  hipLaunchKernelGGL(final_kernel, dim3(2048), dim3(256), 0, stream,
                     y1b, coef + 512, out);
}

// Round 10
// 214.888 us; speedup vs baseline: 2.0244x; 2.0244x over previous
//
#include <hip/hip_runtime.h>

#define B_ 8
#define N_ 8192
#define S_ 2048
#define D1_ 128
#define D2_ 256
#define C0_ 384
#define C1_ 256
#define C2_ 128
#define BN_EPS 1e-5f

typedef unsigned long long ull;
typedef unsigned short u16;
typedef __bf16 bf16x8 __attribute__((ext_vector_type(8)));
typedef float f32x4 __attribute__((ext_vector_type(4)));
typedef short short8_ __attribute__((ext_vector_type(8)));

__device__ __forceinline__ u16 f2bf(float x) {
  unsigned int u = __float_as_uint(x);
  unsigned int r = u + 0x7fffu + ((u >> 16) & 1u);
  return (u16)(r >> 16);
}
__device__ __forceinline__ float bf2f(u16 h) {
  return __uint_as_float(((unsigned int)h) << 16);
}

// async global->LDS DMA, 16B/lane; wave-contiguous 1KB source panels.
__device__ __forceinline__ void gld16(const void* g, void* l) {
  __builtin_amdgcn_global_load_lds(
      (const __attribute__((address_space(1))) void*)g,
      (__attribute__((address_space(3))) void*)l,
      16, 0, 0);
}

// branchless sorted-insert of key k into ascending top-3 (k0<=k1<=k2)
__device__ __forceinline__ void ins3(ull k, ull& k0, ull& k1, ull& k2) {
  ull t = k < k2 ? k : k2;
  ull u = k1 < t ? k1 : t;
  k2 = k1 < t ? t : k1;
  k1 = k0 < u ? u : k0;
  k0 = k0 < u ? k0 : u;
}

// ---------------------------------------------------------------------------
// weights f32 [O][K] -> bf16 k-chunked [K/32][O][32]
// ---------------------------------------------------------------------------
__global__ void cvtW_kernel(const float* __restrict__ src, u16* __restrict__ dst,
                            int O, int K)
{
  int i = blockIdx.x * blockDim.x + threadIdx.x;
  if (i < O * K) {
    int o = i / K, kk = i - o * K;
    dst[(((size_t)(kk >> 5) * O + o) << 5) + (kk & 31)] = f2bf(src[i]);
  }
}

// ---------------------------------------------------------------------------
// transpose points_now [B][D2][S] -> pnT [B][S][D2]  (fp32, for knn gather)
// ---------------------------------------------------------------------------
__global__ __launch_bounds__(256) void transpose_kernel(
    const float* __restrict__ in, float* __restrict__ out)
{
  __shared__ float tile[32][33];
  const int b  = blockIdx.z;
  const int s0 = blockIdx.x * 32;
  const int d0 = blockIdx.y * 32;
  const int tx = threadIdx.x & 31, ty = threadIdx.x >> 5;

  const float* inb = in + ((size_t)b * D2_ + d0) * S_ + s0;
  #pragma unroll
  for (int r = 0; r < 4; ++r) {
    int d = r * 8 + ty;
    tile[d][tx] = inb[(size_t)d * S_ + tx];
  }
  __syncthreads();
  float* outb = out + ((size_t)b * S_ + s0) * D2_ + d0;
  #pragma unroll
  for (int r = 0; r < 4; ++r) {
    int s = r * 8 + ty;
    outb[(size_t)s * D2_ + tx] = tile[tx][s];
  }
}

// ---------------------------------------------------------------------------
// points_sa [B][D1][N] f32 -> xcat chunks 0..3  ([12][N][32] per batch, bf16)
// ---------------------------------------------------------------------------
__global__ __launch_bounds__(256) void psaT_kernel(
    const float* __restrict__ in, u16* __restrict__ xcat)
{
  __shared__ float tile[32][33];
  const int b  = blockIdx.z;
  const int n0 = blockIdx.x * 32;
  const int d0 = blockIdx.y * 32;     // chunk = d0>>5
  const int tx = threadIdx.x & 31, ty = threadIdx.x >> 5;

  const float* inb = in + ((size_t)b * D1_ + d0) * N_ + n0;
  #pragma unroll
  for (int r = 0; r < 4; ++r) {
    int d = r * 8 + ty;
    tile[d][tx] = inb[(size_t)d * N_ + tx];
  }
  __syncthreads();
  u16* outb = xcat + (((size_t)b * 12 + (d0 >> 5)) * N_ + n0) * 32;
  #pragma unroll
  for (int r = 0; r < 4; ++r) {
    int n = r * 8 + ty;
    outb[(size_t)n * 32 + tx] = f2bf(tile[tx][n]);
  }
}

// ---------------------------------------------------------------------------
// K1: 3-NN + interpolation. 128 queries/block. Writes xcat chunks 4..11.
// ---------------------------------------------------------------------------
__global__ __launch_bounds__(256) void knn_interp_kernel(
    const float* __restrict__ xyz_sa, const float* __restrict__ xyz_now,
    const float* __restrict__ pnT, u16* __restrict__ xcat)
{
  __shared__ float4 sp[S_];
  __shared__ int   s_idx[128][3];
  __shared__ float s_w[128][3];

  const int b  = blockIdx.y;
  const int n0 = blockIdx.x * 128;

  const float* xb = xyz_now + (size_t)b * 3 * S_;
  for (int i = threadIdx.x; i < S_; i += 256) {
    float px = xb[i], py = xb[S_ + i], pz = xb[2 * S_ + i];
    sp[i] = make_float4(px, py, pz, px * px + py * py + pz * pz);
  }
  __syncthreads();

  const int qg = threadIdx.x >> 3;   // 0..31 query group (4 queries)
  const int t  = threadIdx.x & 7;    // scanner 0..7
  const int nb = n0 + qg * 4;

  const float* xq = xyz_sa + (size_t)b * 3 * N_;
  float qx[4], qy[4], qz[4], qq[4];
  #pragma unroll
  for (int w = 0; w < 4; ++w) {
    int n = nb + w;
    qx[w] = xq[n]; qy[w] = xq[N_ + n]; qz[w] = xq[2 * N_ + n];
    qq[w] = qx[w] * qx[w] + qy[w] * qy[w] + qz[w] * qz[w];
  }

  ull K0[4], K1[4], K2[4];
  #pragma unroll
  for (int w = 0; w < 4; ++w) { K0[w] = ~0ull; K1[w] = ~0ull; K2[w] = ~0ull; }

  #pragma unroll 2
  for (int it = 0; it < S_ / 8; ++it) {
    int s = (it << 3) | t;
    float4 p = sp[s];
    #pragma unroll
    for (int w = 0; w < 4; ++w) {
      float dot = qx[w] * p.x + qy[w] * p.y + qz[w] * p.z;
      float d = qq[w] - 2.0f * dot + p.w;
      unsigned int bits = __float_as_uint(d);
      unsigned int u = bits ^ (0x80000000u | (unsigned int)((int)bits >> 31));
      ull k = ((ull)u << 32) | (unsigned int)s;
      ins3(k, K0[w], K1[w], K2[w]);
    }
  }

  #pragma unroll
  for (int m = 1; m <= 4; m <<= 1) {
    #pragma unroll
    for (int w = 0; w < 4; ++w) {
      ull o0 = __shfl_xor(K0[w], m), o1 = __shfl_xor(K1[w], m), o2 = __shfl_xor(K2[w], m);
      ins3(o0, K0[w], K1[w], K2[w]);
      ins3(o1, K0[w], K1[w], K2[w]);
      ins3(o2, K0[w], K1[w], K2[w]);
    }
  }

  if (t == 0) {
    #pragma unroll
    for (int w = 0; w < 4; ++w) {
      unsigned int u0 = (unsigned int)(K0[w] >> 32);
      unsigned int u1 = (unsigned int)(K1[w] >> 32);
      unsigned int u2 = (unsigned int)(K2[w] >> 32);
      float d0 = __uint_as_float(u0 ^ (0x80000000u | ~(unsigned int)((int)u0 >> 31)));
      float d1 = __uint_as_float(u1 ^ (0x80000000u | ~(unsigned int)((int)u1 >> 31)));
      float d2 = __uint_as_float(u2 ^ (0x80000000u | ~(unsigned int)((int)u2 >> 31)));
      float r0 = 1.0f / (d0 + 1e-8f);
      float r1 = 1.0f / (d1 + 1e-8f);
      float r2 = 1.0f / (d2 + 1e-8f);
      float rs = 1.0f / (r0 + r1 + r2);
      int qi = qg * 4 + w;
      s_idx[qi][0] = (int)(K0[w] & 0xFFFFFFFFu);
      s_idx[qi][1] = (int)(K1[w] & 0xFFFFFFFFu);
      s_idx[qi][2] = (int)(K2[w] & 0xFFFFFFFFu);
      s_w[qi][0] = r0 * rs; s_w[qi][1] = r1 * rs; s_w[qi][2] = r2 * rs;
    }
  }
  __syncthreads();

  // Phase 2: wave-per-query gather; lane covers chunk 4+(l>>3), 4 channels.
  const int wave = threadIdx.x >> 6;
  const int lane = threadIdx.x & 63;
  const int c8 = lane >> 3;
  const int k4 = (lane & 7) * 4;
  const float* pb = pnT + (size_t)b * S_ * D2_ + c8 * 32 + k4;
  u16* ob = xcat + (((size_t)b * 12 + 4 + c8) * N_ + n0) * 32 + k4;
  #pragma unroll 2
  for (int i = 0; i < 32; ++i) {
    const int qi = wave * 32 + i;
    const int j0 = s_idx[qi][0], j1 = s_idx[qi][1], j2 = s_idx[qi][2];
    const float w0 = s_w[qi][0], w1 = s_w[qi][1], w2 = s_w[qi][2];
    float4 f0 = *(const float4*)(pb + (size_t)j0 * D2_);
    float4 f1 = *(const float4*)(pb + (size_t)j1 * D2_);
    float4 f2 = *(const float4*)(pb + (size_t)j2 * D2_);
    float rx = w0 * f0.x + w1 * f1.x + w2 * f2.x;
    float ry = w0 * f0.y + w1 * f1.y + w2 * f2.y;
    float rz = w0 * f0.z + w1 * f1.z + w2 * f2.z;
    float rw = w0 * f0.w + w1 * f1.w + w2 * f2.w;
    unsigned int lo = (unsigned int)f2bf(rx) | ((unsigned int)f2bf(ry) << 16);
    unsigned int hi = (unsigned int)f2bf(rz) | ((unsigned int)f2bf(rw) << 16);
    *(uint2*)(ob + (size_t)qi * 32) = make_uint2(lo, hi);
  }
}

// ---------------------------------------------------------------------------
union SMg {
  struct { u16 As[2][4096]; u16 Bs[2][4096]; } p;   // [128 rows][32 k] x dbuf
  u16 stage[128][136];
};

// ---------------------------------------------------------------------------
// GEMM1: y0[b,n,o] = W0 . xcat + b0. NO atomics: per-(block,wn) partial
// sums stored to unique slots; reduced later.
// partials1: [1024 slots][512]  (cols 0..255 sum, 256..511 sumsq)
// ---------------------------------------------------------------------------
__global__ __launch_bounds__(256) void gemm1_mfma_kernel(
    const u16* __restrict__ xcat, const u16* __restrict__ W0b,
    const float* __restrict__ b0, u16* __restrict__ y0b, float* __restrict__ partials)
{
  __shared__ SMg sm;

  const int bz = blockIdx.z;
  const int n0 = blockIdx.x * 128;
  const int o0 = blockIdx.y * 128;
  const int tid = threadIdx.x;
  const int wid = tid >> 6, lane = tid & 63;
  const int wo = wid & 1, wn = wid >> 1;
  const int m = lane & 15, g = lane >> 4;

  f32x4 acc[4][4];
  #pragma unroll
  for (int i = 0; i < 4; ++i)
    #pragma unroll
    for (int j = 0; j < 4; ++j) acc[i][j] = (f32x4){0.f, 0.f, 0.f, 0.f};

  auto STAGE = [&](int buf, int c) {
    const u16* asrc = W0b  + ((size_t)c * C1_ + o0) * 32;
    const u16* bsrc = xcat + (((size_t)bz * 12 + c) * N_ + n0) * 32;
    #pragma unroll
    for (int i2 = 0; i2 < 2; ++i2) {
      const int i = wid * 2 + i2;
      gld16(asrc + i * 512 + lane * 8, &sm.p.As[buf][i * 512]);
      gld16(bsrc + i * 512 + lane * 8, &sm.p.Bs[buf][i * 512]);
    }
  };

  STAGE(0, 0);
  __syncthreads();

  for (int kt = 0; kt < 12; ++kt) {
    const int cur = kt & 1;
    if (kt < 11) STAGE(cur ^ 1, kt + 1);

    bf16x8 af[4], bfv[4];
    #pragma unroll
    for (int f = 0; f < 4; ++f)
      af[f] = __builtin_bit_cast(bf16x8,
          *(const short8_*)&sm.p.As[cur][(wo * 64 + f * 16 + m) * 32 + g * 8]);
    #pragma unroll
    for (int f = 0; f < 4; ++f)
      bfv[f] = __builtin_bit_cast(bf16x8,
          *(const short8_*)&sm.p.Bs[cur][(wn * 64 + f * 16 + m) * 32 + g * 8]);
    #pragma unroll
    for (int i = 0; i < 4; ++i)
      #pragma unroll
      for (int j = 0; j < 4; ++j)
        acc[i][j] = __builtin_amdgcn_mfma_f32_16x16x32_bf16(af[i], bfv[j], acc[i][j], 0, 0, 0);

    __syncthreads();
  }

  const int slot = (blockIdx.x * 8 + bz) * 2 + wn;   // 0..1023 unique
  float* prow = partials + (size_t)slot * 512;

  #pragma unroll
  for (int of = 0; of < 4; ++of) {
    const int ol = wo * 64 + of * 16 + g * 4;
    const int ob = o0 + ol;
    float bias[4], s1[4], s2[4];
    #pragma unroll
    for (int r = 0; r < 4; ++r) { bias[r] = b0[ob + r]; s1[r] = 0.f; s2[r] = 0.f; }
    #pragma unroll
    for (int nf = 0; nf < 4; ++nf) {
      const int nl = wn * 64 + nf * 16 + m;
      float y[4];
      #pragma unroll
      for (int r = 0; r < 4; ++r) {
        y[r] = acc[of][nf][r] + bias[r];
        s1[r] += y[r]; s2[r] += y[r] * y[r];
      }
      unsigned int lo = (unsigned int)f2bf(y[0]) | ((unsigned int)f2bf(y[1]) << 16);
      unsigned int hi = (unsigned int)f2bf(y[2]) | ((unsigned int)f2bf(y[3]) << 16);
      *(uint2*)&sm.stage[nl][ol] = make_uint2(lo, hi);
    }
    #pragma unroll
    for (int mk = 1; mk < 16; mk <<= 1)
      #pragma unroll
      for (int r = 0; r < 4; ++r) {
        s1[r] += __shfl_xor(s1[r], mk);
        s2[r] += __shfl_xor(s2[r], mk);
      }
    if (m == 0) {
      *(float4*)(prow + ob)        = make_float4(s1[0], s1[1], s1[2], s1[3]);
      *(float4*)(prow + 256 + ob)  = make_float4(s2[0], s2[1], s2[2], s2[3]);
    }
  }
  __syncthreads();
  {
    const int rrow = tid >> 4;
    const int col  = (tid & 15) * 8;
    const int c    = (o0 + col) >> 5;
    const int ko   = (o0 + col) & 31;
    u16* dst = y0b + (((size_t)bz * 8 + c) * N_ + n0) * 32 + ko;
    #pragma unroll
    for (int pass = 0; pass < 8; ++pass) {
      const int r = pass * 16 + rrow;
      *(uint4*)(dst + (size_t)r * 32) = *(const uint4*)&sm.stage[r][col];
    }
  }
}

// ---------------------------------------------------------------------------
// reduce partials -> BN coef. grid = C blocks; partial row width R floats.
// ---------------------------------------------------------------------------
__global__ __launch_bounds__(256) void reduce_coef_kernel(
    const float* __restrict__ partials, int R, int C,
    const float* __restrict__ g, const float* __restrict__ be,
    float* __restrict__ coef)
{
  const int ch = blockIdx.x;
  const int tid = threadIdx.x;
  float s = 0.f, q = 0.f;
  #pragma unroll
  for (int k = 0; k < 4; ++k) {
    const float* row = partials + (size_t)(tid + k * 256) * R;
    s += row[ch];
    q += row[C + ch];
  }
  #pragma unroll
  for (int mk = 1; mk < 64; mk <<= 1) { s += __shfl_xor(s, mk); q += __shfl_xor(q, mk); }
  __shared__ float ls[4], lq[4];
  const int wid = tid >> 6;
  if ((tid & 63) == 0) { ls[wid] = s; lq[wid] = q; }
  __syncthreads();
  if (tid == 0) {
    s = ls[0] + ls[1] + ls[2] + ls[3];
    q = lq[0] + lq[1] + lq[2] + lq[3];
    const float invM = 1.0f / 65536.0f;   // B*N
    float mean = s * invM;
    float var  = q * invM - mean * mean;
    float a = g[ch] / sqrtf(var + BN_EPS);
    float c = be[ch] - mean * a;
    coef[ch] = a;
    coef[C + ch] = c;
  }
}

// ---------------------------------------------------------------------------
// BN0 + ReLU elementwise on k-chunked y0 [B][8][N][32] (bf16 -> bf16)
// ---------------------------------------------------------------------------
__global__ __launch_bounds__(256) void bn0relu_kernel(
    const u16* __restrict__ y0b, const float* __restrict__ coef, u16* __restrict__ y0r)
{
  __shared__ float cfa[C1_], cfc[C1_];
  cfa[threadIdx.x] = coef[threadIdx.x];
  cfc[threadIdx.x] = coef[C1_ + threadIdx.x];
  __syncthreads();
  const size_t total8 = (size_t)B_ * N_ * C1_ / 8;
  const size_t stride = (size_t)gridDim.x * blockDim.x;
  for (size_t i = (size_t)blockIdx.x * blockDim.x + threadIdx.x; i < total8; i += stride) {
    uint4 v = *(const uint4*)(y0b + i * 8);
    const int ch = (int)(((i >> 15) & 7) * 32 + ((i * 8) & 31));  // chunk*32 + k
    float f0 = fmaxf(0.f, fmaf(bf2f((u16)(v.x & 0xffff)), cfa[ch + 0], cfc[ch + 0]));
    float f1 = fmaxf(0.f, fmaf(bf2f((u16)(v.x >> 16)),    cfa[ch + 1], cfc[ch + 1]));
    float f2 = fmaxf(0.f, fmaf(bf2f((u16)(v.y & 0xffff)), cfa[ch + 2], cfc[ch + 2]));
    float f3 = fmaxf(0.f, fmaf(bf2f((u16)(v.y >> 16)),    cfa[ch + 3], cfc[ch + 3]));
    float f4 = fmaxf(0.f, fmaf(bf2f((u16)(v.z & 0xffff)), cfa[ch + 4], cfc[ch + 4]));
    float f5 = fmaxf(0.f, fmaf(bf2f((u16)(v.z >> 16)),    cfa[ch + 5], cfc[ch + 5]));
    float f6 = fmaxf(0.f, fmaf(bf2f((u16)(v.w & 0xffff)), cfa[ch + 6], cfc[ch + 6]));
    float f7 = fmaxf(0.f, fmaf(bf2f((u16)(v.w >> 16)),    cfa[ch + 7], cfc[ch + 7]));
    uint4 o;
    o.x = (unsigned int)f2bf(f0) | ((unsigned int)f2bf(f1) << 16);
    o.y = (unsigned int)f2bf(f2) | ((unsigned int)f2bf(f3) << 16);
    o.z = (unsigned int)f2bf(f4) | ((unsigned int)f2bf(f5) << 16);
    o.w = (unsigned int)f2bf(f6) | ((unsigned int)f2bf(f7) << 16);
    *(uint4*)(y0r + i * 8) = o;
  }
}

// ---------------------------------------------------------------------------
// GEMM2: y1b[b,p,n] = W1 . y0r + b1. partials2: [1024 slots][256].
// ---------------------------------------------------------------------------
__global__ __launch_bounds__(256) void gemm2_mfma_kernel(
    const u16* __restrict__ y0r, const u16* __restrict__ W1b,
    const float* __restrict__ b1, u16* __restrict__ y1b, float* __restrict__ partials)
{
  __shared__ SMg sm;

  const int bz = blockIdx.z;
  const int n0 = blockIdx.x * 128;
  const int tid = threadIdx.x;
  const int wid = tid >> 6, lane = tid & 63;
  const int wo = wid & 1, wn = wid >> 1;
  const int m = lane & 15, g = lane >> 4;

  f32x4 acc[4][4];
  #pragma unroll
  for (int i = 0; i < 4; ++i)
    #pragma unroll
    for (int j = 0; j < 4; ++j) acc[i][j] = (f32x4){0.f, 0.f, 0.f, 0.f};

  auto STAGE = [&](int buf, int c) {
    const u16* asrc = W1b + ((size_t)c * C2_) * 32;
    const u16* bsrc = y0r + (((size_t)bz * 8 + c) * N_ + n0) * 32;
    #pragma unroll
    for (int i2 = 0; i2 < 2; ++i2) {
      const int i = wid * 2 + i2;
      gld16(asrc + i * 512 + lane * 8, &sm.p.As[buf][i * 512]);
      gld16(bsrc + i * 512 + lane * 8, &sm.p.Bs[buf][i * 512]);
    }
  };

  STAGE(0, 0);
  __syncthreads();

  for (int kt = 0; kt < 8; ++kt) {
    const int cur = kt & 1;
    if (kt < 7) STAGE(cur ^ 1, kt + 1);

    bf16x8 af[4], bfv[4];
    #pragma unroll
    for (int f = 0; f < 4; ++f)
      af[f] = __builtin_bit_cast(bf16x8,
          *(const short8_*)&sm.p.As[cur][(wo * 64 + f * 16 + m) * 32 + g * 8]);
    #pragma unroll
    for (int f = 0; f < 4; ++f)
      bfv[f] = __builtin_bit_cast(bf16x8,
          *(const short8_*)&sm.p.Bs[cur][(wn * 64 + f * 16 + m) * 32 + g * 8]);
    #pragma unroll
    for (int i = 0; i < 4; ++i)
      #pragma unroll
      for (int j = 0; j < 4; ++j)
        acc[i][j] = __builtin_amdgcn_mfma_f32_16x16x32_bf16(af[i], bfv[j], acc[i][j], 0, 0, 0);

    __syncthreads();
  }

  const int slot = (blockIdx.x * 8 + bz) * 2 + wn;   // 0..1023 unique
  float* prow = partials + (size_t)slot * 256;

  #pragma unroll
  for (int of = 0; of < 4; ++of) {
    const int pb = wo * 64 + of * 16 + g * 4;
    float bias[4], s1[4], s2[4];
    #pragma unroll
    for (int r = 0; r < 4; ++r) { bias[r] = b1[pb + r]; s1[r] = 0.f; s2[r] = 0.f; }
    #pragma unroll
    for (int nf = 0; nf < 4; ++nf) {
      const int nl = wn * 64 + nf * 16 + m;
      #pragma unroll
      for (int r = 0; r < 4; ++r) {
        float y = acc[of][nf][r] + bias[r];
        s1[r] += y; s2[r] += y * y;
        sm.stage[pb + r][nl] = f2bf(y);
      }
    }
    #pragma unroll
    for (int mk = 1; mk < 16; mk <<= 1)
      #pragma unroll
      for (int r = 0; r < 4; ++r) {
        s1[r] += __shfl_xor(s1[r], mk);
        s2[r] += __shfl_xor(s2[r], mk);
      }
    if (m == 0) {
      *(float4*)(prow + pb)        = make_float4(s1[0], s1[1], s1[2], s1[3]);
      *(float4*)(prow + 128 + pb)  = make_float4(s2[0], s2[1], s2[2], s2[3]);
    }
  }
  __syncthreads();
  {
    #pragma unroll
    for (int pass = 0; pass < 8; ++pass) {
      const int idx = pass * 256 + tid;
      const int p = idx >> 4;
      const int c8 = (idx & 15) * 8;
      uint4 v = *(const uint4*)&sm.stage[p][c8];
      *(uint4*)(y1b + ((size_t)bz * C2_ + p) * N_ + n0 + c8) = v;
    }
  }
}

// ---------------------------------------------------------------------------
// final: BN1 + ReLU elementwise, bf16 in -> fp32 out  (y1b is [B][C2][N])
// ---------------------------------------------------------------------------
__global__ __launch_bounds__(256) void final_kernel(
    const u16* __restrict__ y1b, const float* __restrict__ cf, float* __restrict__ out)
{
  const size_t total4 = (size_t)B_ * C2_ * N_ / 4;
  const size_t stride = (size_t)gridDim.x * blockDim.x;
  for (size_t f = (size_t)blockIdx.x * blockDim.x + threadIdx.x; f < total4; f += stride) {
    size_t base = f * 4;
    int p = (int)((base >> 13) & (C2_ - 1));
    float a = cf[p], c = cf[C2_ + p];
    uint2 v = *(const uint2*)(y1b + base);
    float4 r;
    r.x = fmaxf(0.0f, fmaf(bf2f((u16)(v.x & 0xffff)), a, c));
    r.y = fmaxf(0.0f, fmaf(bf2f((u16)(v.x >> 16)),    a, c));
    r.z = fmaxf(0.0f, fmaf(bf2f((u16)(v.y & 0xffff)), a, c));
    r.w = fmaxf(0.0f, fmaf(bf2f((u16)(v.y >> 16)),    a, c));
    *(float4*)(out + base) = r;
  }
}

// ---------------------------------------------------------------------------
extern "C" void kernel_launch(void* const* d_in, const int* in_sizes, int n_in,
                              void* d_out, int out_size, void* d_ws, size_t ws_size,
                              hipStream_t stream)
{
  const float* xyz_sa     = (const float*)d_in[0];
  const float* xyz_now    = (const float*)d_in[1];
  const float* points_sa  = (const float*)d_in[2];
  const float* points_now = (const float*)d_in[3];
  const float* W0  = (const float*)d_in[4];
  const float* b0  = (const float*)d_in[5];
  const float* g0  = (const float*)d_in[6];
  const float* be0 = (const float*)d_in[7];
  const float* W1  = (const float*)d_in[8];
  const float* b1  = (const float*)d_in[9];
  const float* g1  = (const float*)d_in[10];
  const float* be1 = (const float*)d_in[11];

  const size_t MB = 1048576ull;
  char* base = (char*)d_ws;
  u16*   xcat  = (u16*)(base + 0);            // [B][12][N][32] bf16  48MB
  u16*   y0r   = (u16*)(base + 0);            // [B][8][N][32] bf16   32MB (xcat dead)
  float* pnT   = (float*)(base + 48 * MB);    // [B][S][256] f32      16MB (dead after knn)
  u16*   y1b   = (u16*)(base + 48 * MB);      // [B][C2][N] bf16      16MB (overlays pnT)
  u16*   y0b   = (u16*)(base + 64 * MB);      // [B][8][N][32] bf16   32MB
  u16*   W0b   = (u16*)(base + 96 * MB);      // [12][256][32] bf16
  u16*   W1b   = (u16*)(base + 96 * MB + 512 * 1024); // [8][128][32] bf16
  float* coef  = (float*)(base + 97 * MB);    // 768 f
  float* part1 = (float*)(base + 98 * MB);    // [1024][512] f32 2MB
  float* part2 = (float*)(base + 100 * MB);   // [1024][256] f32 1MB
  float* out   = (float*)d_out;

  hipLaunchKernelGGL(cvtW_kernel, dim3((C1_ * C0_ + 255) / 256), dim3(256), 0, stream,
                     W0, W0b, C1_, C0_);
  hipLaunchKernelGGL(cvtW_kernel, dim3((C2_ * C1_ + 255) / 256), dim3(256), 0, stream,
                     W1, W1b, C2_, C1_);
  hipLaunchKernelGGL(transpose_kernel, dim3(S_ / 32, D2_ / 32, B_), dim3(256), 0, stream,
                     points_now, pnT);
  hipLaunchKernelGGL(psaT_kernel, dim3(N_ / 32, D1_ / 32, B_), dim3(256), 0, stream,
                     points_sa, xcat);
  hipLaunchKernelGGL(knn_interp_kernel, dim3(N_ / 128, B_), dim3(256), 0, stream,
                     xyz_sa, xyz_now, pnT, xcat);
  hipLaunchKernelGGL(gemm1_mfma_kernel, dim3(N_ / 128, 2, B_), dim3(256), 0, stream,
                     xcat, W0b, b0, y0b, part1);
  hipLaunchKernelGGL(reduce_coef_kernel, dim3(C1_), dim3(256), 0, stream,
                     part1, 512, C1_, g0, be0, coef);
  hipLaunchKernelGGL(bn0relu_kernel, dim3(2048), dim3(256), 0, stream,
                     y0b, coef, y0r);
  hipLaunchKernelGGL(gemm2_mfma_kernel, dim3(N_ / 128, 1, B_), dim3(256), 0, stream,
                     y0r, W1b, b1, y1b, part2);
  hipLaunchKernelGGL(reduce_coef_kernel, dim3(C2_), dim3(256), 0, stream,
                     part2, 256, C2_, g1, be1, coef + 512);
  hipLaunchKernelGGL(final_kernel, dim3(2048), dim3(256), 0, stream,
                     y1b, coef + 512, out);
}

// Round 11
// 205.295 us; speedup vs baseline: 2.1190x; 1.0467x over previous
//
#include <hip/hip_runtime.h>

#define B_ 8
#define N_ 8192
#define S_ 2048
#define D1_ 128
#define D2_ 256
#define C0_ 384
#define C1_ 256
#define C2_ 128
#define BN_EPS 1e-5f

typedef unsigned long long ull;
typedef unsigned short u16;
typedef __bf16 bf16x8 __attribute__((ext_vector_type(8)));
typedef float f32x4 __attribute__((ext_vector_type(4)));
typedef short short8_ __attribute__((ext_vector_type(8)));

__device__ __forceinline__ u16 f2bf(float x) {
  unsigned int u = __float_as_uint(x);
  unsigned int r = u + 0x7fffu + ((u >> 16) & 1u);
  return (u16)(r >> 16);
}
__device__ __forceinline__ float bf2f(u16 h) {
  return __uint_as_float(((unsigned int)h) << 16);
}

// async global->LDS DMA, 16B/lane; wave-contiguous 1KB source panels.
__device__ __forceinline__ void gld16(const void* g, void* l) {
  __builtin_amdgcn_global_load_lds(
      (const __attribute__((address_space(1))) void*)g,
      (__attribute__((address_space(3))) void*)l,
      16, 0, 0);
}

// branchless sorted-insert of key k into ascending top-3 (k0<=k1<=k2)
__device__ __forceinline__ void ins3(ull k, ull& k0, ull& k1, ull& k2) {
  ull t = k < k2 ? k : k2;
  ull u = k1 < t ? k1 : t;
  k2 = k1 < t ? t : k1;
  k1 = k0 < u ? u : k0;
  k0 = k0 < u ? k0 : u;
}

// ---------------------------------------------------------------------------
// weights f32 [O][K] -> bf16 k-chunked [K/32][O][32]
// ---------------------------------------------------------------------------
__global__ void cvtW_kernel(const float* __restrict__ src, u16* __restrict__ dst,
                            int O, int K)
{
  int i = blockIdx.x * blockDim.x + threadIdx.x;
  if (i < O * K) {
    int o = i / K, kk = i - o * K;
    dst[(((size_t)(kk >> 5) * O + o) << 5) + (kk & 31)] = f2bf(src[i]);
  }
}

// ---------------------------------------------------------------------------
// transpose points_now [B][D2][S] -> pnT [B][S][D2]  (fp32, for knn gather)
// ---------------------------------------------------------------------------
__global__ __launch_bounds__(256) void transpose_kernel(
    const float* __restrict__ in, float* __restrict__ out)
{
  __shared__ float tile[32][33];
  const int b  = blockIdx.z;
  const int s0 = blockIdx.x * 32;
  const int d0 = blockIdx.y * 32;
  const int tx = threadIdx.x & 31, ty = threadIdx.x >> 5;

  const float* inb = in + ((size_t)b * D2_ + d0) * S_ + s0;
  #pragma unroll
  for (int r = 0; r < 4; ++r) {
    int d = r * 8 + ty;
    tile[d][tx] = inb[(size_t)d * S_ + tx];
  }
  __syncthreads();
  float* outb = out + ((size_t)b * S_ + s0) * D2_ + d0;
  #pragma unroll
  for (int r = 0; r < 4; ++r) {
    int s = r * 8 + ty;
    outb[(size_t)s * D2_ + tx] = tile[tx][s];
  }
}

// ---------------------------------------------------------------------------
// points_sa [B][D1][N] f32 -> xcat chunks 0..3  ([12][N][32] per batch, bf16)
// ---------------------------------------------------------------------------
__global__ __launch_bounds__(256) void psaT_kernel(
    const float* __restrict__ in, u16* __restrict__ xcat)
{
  __shared__ float tile[32][33];
  const int b  = blockIdx.z;
  const int n0 = blockIdx.x * 32;
  const int d0 = blockIdx.y * 32;     // chunk = d0>>5
  const int tx = threadIdx.x & 31, ty = threadIdx.x >> 5;

  const float* inb = in + ((size_t)b * D1_ + d0) * N_ + n0;
  #pragma unroll
  for (int r = 0; r < 4; ++r) {
    int d = r * 8 + ty;
    tile[d][tx] = inb[(size_t)d * N_ + tx];
  }
  __syncthreads();
  u16* outb = xcat + (((size_t)b * 12 + (d0 >> 5)) * N_ + n0) * 32;
  #pragma unroll
  for (int r = 0; r < 4; ++r) {
    int n = r * 8 + ty;
    outb[(size_t)n * 32 + tx] = f2bf(tile[tx][n]);
  }
}

// ---------------------------------------------------------------------------
// K1: 3-NN + interpolation. 64 queries/block (grid 128xB = 1024 blocks ->
// 4 blocks/CU). Phase 1: 4 queries/thread, 16 scanners (128 cands each);
// sp holds (-2p, |p|^2) so d = 1 add + 3 fma. Exact u64 tie-break keys.
// ---------------------------------------------------------------------------
__global__ __launch_bounds__(256) void knn_interp_kernel(
    const float* __restrict__ xyz_sa, const float* __restrict__ xyz_now,
    const float* __restrict__ pnT, u16* __restrict__ xcat)
{
  __shared__ float4 sp[S_];
  __shared__ int   s_idx[64][3];
  __shared__ float s_w[64][3];

  const int b  = blockIdx.y;
  const int n0 = blockIdx.x * 64;

  const float* xb = xyz_now + (size_t)b * 3 * S_;
  for (int i = threadIdx.x; i < S_; i += 256) {
    float px = xb[i], py = xb[S_ + i], pz = xb[2 * S_ + i];
    sp[i] = make_float4(-2.f * px, -2.f * py, -2.f * pz,
                        px * px + py * py + pz * pz);
  }
  __syncthreads();

  const int qg = threadIdx.x >> 4;   // 0..15 query group (4 queries)
  const int t  = threadIdx.x & 15;   // scanner 0..15
  const int nb = n0 + qg * 4;

  const float* xq = xyz_sa + (size_t)b * 3 * N_;
  float qx[4], qy[4], qz[4], qq[4];
  #pragma unroll
  for (int w = 0; w < 4; ++w) {
    int n = nb + w;
    qx[w] = xq[n]; qy[w] = xq[N_ + n]; qz[w] = xq[2 * N_ + n];
    qq[w] = qx[w] * qx[w] + qy[w] * qy[w] + qz[w] * qz[w];
  }

  ull K0[4], K1[4], K2[4];
  #pragma unroll
  for (int w = 0; w < 4; ++w) { K0[w] = ~0ull; K1[w] = ~0ull; K2[w] = ~0ull; }

  #pragma unroll 2
  for (int it = 0; it < S_ / 16; ++it) {
    int s = (it << 4) | t;
    float4 p = sp[s];
    #pragma unroll
    for (int w = 0; w < 4; ++w) {
      float d = fmaf(p.x, qx[w], fmaf(p.y, qy[w], fmaf(p.z, qz[w], qq[w] + p.w)));
      unsigned int bits = __float_as_uint(d);
      unsigned int u = bits ^ (0x80000000u | (unsigned int)((int)bits >> 31));
      ull k = ((ull)u << 32) | (unsigned int)s;
      ins3(k, K0[w], K1[w], K2[w]);
    }
  }

  // merge the 16 scanners via shuffle butterfly (stays within 16-lane group)
  #pragma unroll
  for (int m = 1; m <= 8; m <<= 1) {
    #pragma unroll
    for (int w = 0; w < 4; ++w) {
      ull o0 = __shfl_xor(K0[w], m), o1 = __shfl_xor(K1[w], m), o2 = __shfl_xor(K2[w], m);
      ins3(o0, K0[w], K1[w], K2[w]);
      ins3(o1, K0[w], K1[w], K2[w]);
      ins3(o2, K0[w], K1[w], K2[w]);
    }
  }

  if (t == 0) {
    #pragma unroll
    for (int w = 0; w < 4; ++w) {
      unsigned int u0 = (unsigned int)(K0[w] >> 32);
      unsigned int u1 = (unsigned int)(K1[w] >> 32);
      unsigned int u2 = (unsigned int)(K2[w] >> 32);
      float d0 = __uint_as_float(u0 ^ (0x80000000u | ~(unsigned int)((int)u0 >> 31)));
      float d1 = __uint_as_float(u1 ^ (0x80000000u | ~(unsigned int)((int)u1 >> 31)));
      float d2 = __uint_as_float(u2 ^ (0x80000000u | ~(unsigned int)((int)u2 >> 31)));
      float r0 = 1.0f / (d0 + 1e-8f);
      float r1 = 1.0f / (d1 + 1e-8f);
      float r2 = 1.0f / (d2 + 1e-8f);
      float rs = 1.0f / (r0 + r1 + r2);
      int qi = qg * 4 + w;
      s_idx[qi][0] = (int)(K0[w] & 0xFFFFFFFFu);
      s_idx[qi][1] = (int)(K1[w] & 0xFFFFFFFFu);
      s_idx[qi][2] = (int)(K2[w] & 0xFFFFFFFFu);
      s_w[qi][0] = r0 * rs; s_w[qi][1] = r1 * rs; s_w[qi][2] = r2 * rs;
    }
  }
  __syncthreads();

  // Phase 2: wave-per-query gather; lane covers chunk 4+(l>>3), 4 channels.
  const int wave = threadIdx.x >> 6;
  const int lane = threadIdx.x & 63;
  const int c8 = lane >> 3;
  const int k4 = (lane & 7) * 4;
  const float* pb = pnT + (size_t)b * S_ * D2_ + c8 * 32 + k4;
  u16* ob = xcat + (((size_t)b * 12 + 4 + c8) * N_ + n0) * 32 + k4;
  #pragma unroll 2
  for (int i = 0; i < 16; ++i) {
    const int qi = wave * 16 + i;
    const int j0 = s_idx[qi][0], j1 = s_idx[qi][1], j2 = s_idx[qi][2];
    const float w0 = s_w[qi][0], w1 = s_w[qi][1], w2 = s_w[qi][2];
    float4 f0 = *(const float4*)(pb + (size_t)j0 * D2_);
    float4 f1 = *(const float4*)(pb + (size_t)j1 * D2_);
    float4 f2 = *(const float4*)(pb + (size_t)j2 * D2_);
    float rx = w0 * f0.x + w1 * f1.x + w2 * f2.x;
    float ry = w0 * f0.y + w1 * f1.y + w2 * f2.y;
    float rz = w0 * f0.z + w1 * f1.z + w2 * f2.z;
    float rw = w0 * f0.w + w1 * f1.w + w2 * f2.w;
    unsigned int lo = (unsigned int)f2bf(rx) | ((unsigned int)f2bf(ry) << 16);
    unsigned int hi = (unsigned int)f2bf(rz) | ((unsigned int)f2bf(rw) << 16);
    *(uint2*)(ob + (size_t)qi * 32) = make_uint2(lo, hi);
  }
}

// ---------------------------------------------------------------------------
union SMg {
  struct { u16 As[2][4096]; u16 Bs[2][4096]; } p;   // [128 rows][32 k] x dbuf
  u16 stage[128][136];
};

// ---------------------------------------------------------------------------
// GEMM1: y0[b,n,o] = W0 . xcat + b0. NO atomics: per-(block,wn) partial
// sums stored to unique slots; reduced later.
// partials1: [1024 slots][512]  (cols 0..255 sum, 256..511 sumsq)
// ---------------------------------------------------------------------------
__global__ __launch_bounds__(256) void gemm1_mfma_kernel(
    const u16* __restrict__ xcat, const u16* __restrict__ W0b,
    const float* __restrict__ b0, u16* __restrict__ y0b, float* __restrict__ partials)
{
  __shared__ SMg sm;

  const int bz = blockIdx.z;
  const int n0 = blockIdx.x * 128;
  const int o0 = blockIdx.y * 128;
  const int tid = threadIdx.x;
  const int wid = tid >> 6, lane = tid & 63;
  const int wo = wid & 1, wn = wid >> 1;
  const int m = lane & 15, g = lane >> 4;

  f32x4 acc[4][4];
  #pragma unroll
  for (int i = 0; i < 4; ++i)
    #pragma unroll
    for (int j = 0; j < 4; ++j) acc[i][j] = (f32x4){0.f, 0.f, 0.f, 0.f};

  auto STAGE = [&](int buf, int c) {
    const u16* asrc = W0b  + ((size_t)c * C1_ + o0) * 32;
    const u16* bsrc = xcat + (((size_t)bz * 12 + c) * N_ + n0) * 32;
    #pragma unroll
    for (int i2 = 0; i2 < 2; ++i2) {
      const int i = wid * 2 + i2;
      gld16(asrc + i * 512 + lane * 8, &sm.p.As[buf][i * 512]);
      gld16(bsrc + i * 512 + lane * 8, &sm.p.Bs[buf][i * 512]);
    }
  };

  STAGE(0, 0);
  __syncthreads();

  for (int kt = 0; kt < 12; ++kt) {
    const int cur = kt & 1;
    if (kt < 11) STAGE(cur ^ 1, kt + 1);

    bf16x8 af[4], bfv[4];
    #pragma unroll
    for (int f = 0; f < 4; ++f)
      af[f] = __builtin_bit_cast(bf16x8,
          *(const short8_*)&sm.p.As[cur][(wo * 64 + f * 16 + m) * 32 + g * 8]);
    #pragma unroll
    for (int f = 0; f < 4; ++f)
      bfv[f] = __builtin_bit_cast(bf16x8,
          *(const short8_*)&sm.p.Bs[cur][(wn * 64 + f * 16 + m) * 32 + g * 8]);
    #pragma unroll
    for (int i = 0; i < 4; ++i)
      #pragma unroll
      for (int j = 0; j < 4; ++j)
        acc[i][j] = __builtin_amdgcn_mfma_f32_16x16x32_bf16(af[i], bfv[j], acc[i][j], 0, 0, 0);

    __syncthreads();
  }

  const int slot = (blockIdx.x * 8 + bz) * 2 + wn;   // 0..1023 unique
  float* prow = partials + (size_t)slot * 512;

  #pragma unroll
  for (int of = 0; of < 4; ++of) {
    const int ol = wo * 64 + of * 16 + g * 4;
    const int ob = o0 + ol;
    float bias[4], s1[4], s2[4];
    #pragma unroll
    for (int r = 0; r < 4; ++r) { bias[r] = b0[ob + r]; s1[r] = 0.f; s2[r] = 0.f; }
    #pragma unroll
    for (int nf = 0; nf < 4; ++nf) {
      const int nl = wn * 64 + nf * 16 + m;
      float y[4];
      #pragma unroll
      for (int r = 0; r < 4; ++r) {
        y[r] = acc[of][nf][r] + bias[r];
        s1[r] += y[r]; s2[r] += y[r] * y[r];
      }
      unsigned int lo = (unsigned int)f2bf(y[0]) | ((unsigned int)f2bf(y[1]) << 16);
      unsigned int hi = (unsigned int)f2bf(y[2]) | ((unsigned int)f2bf(y[3]) << 16);
      *(uint2*)&sm.stage[nl][ol] = make_uint2(lo, hi);
    }
    #pragma unroll
    for (int mk = 1; mk < 16; mk <<= 1)
      #pragma unroll
      for (int r = 0; r < 4; ++r) {
        s1[r] += __shfl_xor(s1[r], mk);
        s2[r] += __shfl_xor(s2[r], mk);
      }
    if (m == 0) {
      *(float4*)(prow + ob)        = make_float4(s1[0], s1[1], s1[2], s1[3]);
      *(float4*)(prow + 256 + ob)  = make_float4(s2[0], s2[1], s2[2], s2[3]);
    }
  }
  __syncthreads();
  {
    const int rrow = tid >> 4;
    const int col  = (tid & 15) * 8;
    const int c    = (o0 + col) >> 5;
    const int ko   = (o0 + col) & 31;
    u16* dst = y0b + (((size_t)bz * 8 + c) * N_ + n0) * 32 + ko;
    #pragma unroll
    for (int pass = 0; pass < 8; ++pass) {
      const int r = pass * 16 + rrow;
      *(uint4*)(dst + (size_t)r * 32) = *(const uint4*)&sm.stage[r][col];
    }
  }
}

// ---------------------------------------------------------------------------
// reduce partials -> BN coef. grid = C blocks; partial row width R floats.
// ---------------------------------------------------------------------------
__global__ __launch_bounds__(256) void reduce_coef_kernel(
    const float* __restrict__ partials, int R, int C,
    const float* __restrict__ g, const float* __restrict__ be,
    float* __restrict__ coef)
{
  const int ch = blockIdx.x;
  const int tid = threadIdx.x;
  float s = 0.f, q = 0.f;
  #pragma unroll
  for (int k = 0; k < 4; ++k) {
    const float* row = partials + (size_t)(tid + k * 256) * R;
    s += row[ch];
    q += row[C + ch];
  }
  #pragma unroll
  for (int mk = 1; mk < 64; mk <<= 1) { s += __shfl_xor(s, mk); q += __shfl_xor(q, mk); }
  __shared__ float ls[4], lq[4];
  const int wid = tid >> 6;
  if ((tid & 63) == 0) { ls[wid] = s; lq[wid] = q; }
  __syncthreads();
  if (tid == 0) {
    s = ls[0] + ls[1] + ls[2] + ls[3];
    q = lq[0] + lq[1] + lq[2] + lq[3];
    const float invM = 1.0f / 65536.0f;   // B*N
    float mean = s * invM;
    float var  = q * invM - mean * mean;
    float a = g[ch] / sqrtf(var + BN_EPS);
    float c = be[ch] - mean * a;
    coef[ch] = a;
    coef[C + ch] = c;
  }
}

// ---------------------------------------------------------------------------
// BN0 + ReLU elementwise on k-chunked y0 [B][8][N][32] (bf16 -> bf16)
// ---------------------------------------------------------------------------
__global__ __launch_bounds__(256) void bn0relu_kernel(
    const u16* __restrict__ y0b, const float* __restrict__ coef, u16* __restrict__ y0r)
{
  __shared__ float cfa[C1_], cfc[C1_];
  cfa[threadIdx.x] = coef[threadIdx.x];
  cfc[threadIdx.x] = coef[C1_ + threadIdx.x];
  __syncthreads();
  const size_t total8 = (size_t)B_ * N_ * C1_ / 8;
  const size_t stride = (size_t)gridDim.x * blockDim.x;
  for (size_t i = (size_t)blockIdx.x * blockDim.x + threadIdx.x; i < total8; i += stride) {
    uint4 v = *(const uint4*)(y0b + i * 8);
    const int ch = (int)(((i >> 15) & 7) * 32 + ((i * 8) & 31));  // chunk*32 + k
    float f0 = fmaxf(0.f, fmaf(bf2f((u16)(v.x & 0xffff)), cfa[ch + 0], cfc[ch + 0]));
    float f1 = fmaxf(0.f, fmaf(bf2f((u16)(v.x >> 16)),    cfa[ch + 1], cfc[ch + 1]));
    float f2 = fmaxf(0.f, fmaf(bf2f((u16)(v.y & 0xffff)), cfa[ch + 2], cfc[ch + 2]));
    float f3 = fmaxf(0.f, fmaf(bf2f((u16)(v.y >> 16)),    cfa[ch + 3], cfc[ch + 3]));
    float f4 = fmaxf(0.f, fmaf(bf2f((u16)(v.z & 0xffff)), cfa[ch + 4], cfc[ch + 4]));
    float f5 = fmaxf(0.f, fmaf(bf2f((u16)(v.z >> 16)),    cfa[ch + 5], cfc[ch + 5]));
    float f6 = fmaxf(0.f, fmaf(bf2f((u16)(v.w & 0xffff)), cfa[ch + 6], cfc[ch + 6]));
    float f7 = fmaxf(0.f, fmaf(bf2f((u16)(v.w >> 16)),    cfa[ch + 7], cfc[ch + 7]));
    uint4 o;
    o.x = (unsigned int)f2bf(f0) | ((unsigned int)f2bf(f1) << 16);
    o.y = (unsigned int)f2bf(f2) | ((unsigned int)f2bf(f3) << 16);
    o.z = (unsigned int)f2bf(f4) | ((unsigned int)f2bf(f5) << 16);
    o.w = (unsigned int)f2bf(f6) | ((unsigned int)f2bf(f7) << 16);
    *(uint4*)(y0r + i * 8) = o;
  }
}

// ---------------------------------------------------------------------------
// GEMM2: y1b[b,p,n] = W1 . y0r + b1. partials2: [1024 slots][256].
// ---------------------------------------------------------------------------
__global__ __launch_bounds__(256) void gemm2_mfma_kernel(
    const u16* __restrict__ y0r, const u16* __restrict__ W1b,
    const float* __restrict__ b1, u16* __restrict__ y1b, float* __restrict__ partials)
{
  __shared__ SMg sm;

  const int bz = blockIdx.z;
  const int n0 = blockIdx.x * 128;
  const int tid = threadIdx.x;
  const int wid = tid >> 6, lane = tid & 63;
  const int wo = wid & 1, wn = wid >> 1;
  const int m = lane & 15, g = lane >> 4;

  f32x4 acc[4][4];
  #pragma unroll
  for (int i = 0; i < 4; ++i)
    #pragma unroll
    for (int j = 0; j < 4; ++j) acc[i][j] = (f32x4){0.f, 0.f, 0.f, 0.f};

  auto STAGE = [&](int buf, int c) {
    const u16* asrc = W1b + ((size_t)c * C2_) * 32;
    const u16* bsrc = y0r + (((size_t)bz * 8 + c) * N_ + n0) * 32;
    #pragma unroll
    for (int i2 = 0; i2 < 2; ++i2) {
      const int i = wid * 2 + i2;
      gld16(asrc + i * 512 + lane * 8, &sm.p.As[buf][i * 512]);
      gld16(bsrc + i * 512 + lane * 8, &sm.p.Bs[buf][i * 512]);
    }
  };

  STAGE(0, 0);
  __syncthreads();

  for (int kt = 0; kt < 8; ++kt) {
    const int cur = kt & 1;
    if (kt < 7) STAGE(cur ^ 1, kt + 1);

    bf16x8 af[4], bfv[4];
    #pragma unroll
    for (int f = 0; f < 4; ++f)
      af[f] = __builtin_bit_cast(bf16x8,
          *(const short8_*)&sm.p.As[cur][(wo * 64 + f * 16 + m) * 32 + g * 8]);
    #pragma unroll
    for (int f = 0; f < 4; ++f)
      bfv[f] = __builtin_bit_cast(bf16x8,
          *(const short8_*)&sm.p.Bs[cur][(wn * 64 + f * 16 + m) * 32 + g * 8]);
    #pragma unroll
    for (int i = 0; i < 4; ++i)
      #pragma unroll
      for (int j = 0; j < 4; ++j)
        acc[i][j] = __builtin_amdgcn_mfma_f32_16x16x32_bf16(af[i], bfv[j], acc[i][j], 0, 0, 0);

    __syncthreads();
  }

  const int slot = (blockIdx.x * 8 + bz) * 2 + wn;   // 0..1023 unique
  float* prow = partials + (size_t)slot * 256;

  #pragma unroll
  for (int of = 0; of < 4; ++of) {
    const int pb = wo * 64 + of * 16 + g * 4;
    float bias[4], s1[4], s2[4];
    #pragma unroll
    for (int r = 0; r < 4; ++r) { bias[r] = b1[pb + r]; s1[r] = 0.f; s2[r] = 0.f; }
    #pragma unroll
    for (int nf = 0; nf < 4; ++nf) {
      const int nl = wn * 64 + nf * 16 + m;
      #pragma unroll
      for (int r = 0; r < 4; ++r) {
        float y = acc[of][nf][r] + bias[r];
        s1[r] += y; s2[r] += y * y;
        sm.stage[pb + r][nl] = f2bf(y);
      }
    }
    #pragma unroll
    for (int mk = 1; mk < 16; mk <<= 1)
      #pragma unroll
      for (int r = 0; r < 4; ++r) {
        s1[r] += __shfl_xor(s1[r], mk);
        s2[r] += __shfl_xor(s2[r], mk);
      }
    if (m == 0) {
      *(float4*)(prow + pb)        = make_float4(s1[0], s1[1], s1[2], s1[3]);
      *(float4*)(prow + 128 + pb)  = make_float4(s2[0], s2[1], s2[2], s2[3]);
    }
  }
  __syncthreads();
  {
    #pragma unroll
    for (int pass = 0; pass < 8; ++pass) {
      const int idx = pass * 256 + tid;
      const int p = idx >> 4;
      const int c8 = (idx & 15) * 8;
      uint4 v = *(const uint4*)&sm.stage[p][c8];
      *(uint4*)(y1b + ((size_t)bz * C2_ + p) * N_ + n0 + c8) = v;
    }
  }
}

// ---------------------------------------------------------------------------
// final: BN1 + ReLU elementwise, bf16 in -> fp32 out  (y1b is [B][C2][N])
// ---------------------------------------------------------------------------
__global__ __launch_bounds__(256) void final_kernel(
    const u16* __restrict__ y1b, const float* __restrict__ cf, float* __restrict__ out)
{
  const size_t total4 = (size_t)B_ * C2_ * N_ / 4;
  const size_t stride = (size_t)gridDim.x * blockDim.x;
  for (size_t f = (size_t)blockIdx.x * blockDim.x + threadIdx.x; f < total4; f += stride) {
    size_t base = f * 4;
    int p = (int)((base >> 13) & (C2_ - 1));
    float a = cf[p], c = cf[C2_ + p];
    uint2 v = *(const uint2*)(y1b + base);
    float4 r;
    r.x = fmaxf(0.0f, fmaf(bf2f((u16)(v.x & 0xffff)), a, c));
    r.y = fmaxf(0.0f, fmaf(bf2f((u16)(v.x >> 16)),    a, c));
    r.z = fmaxf(0.0f, fmaf(bf2f((u16)(v.y & 0xffff)), a, c));
    r.w = fmaxf(0.0f, fmaf(bf2f((u16)(v.y >> 16)),    a, c));
    *(float4*)(out + base) = r;
  }
}

// ---------------------------------------------------------------------------
extern "C" void kernel_launch(void* const* d_in, const int* in_sizes, int n_in,
                              void* d_out, int out_size, void* d_ws, size_t ws_size,
                              hipStream_t stream)
{
  const float* xyz_sa     = (const float*)d_in[0];
  const float* xyz_now    = (const float*)d_in[1];
  const float* points_sa  = (const float*)d_in[2];
  const float* points_now = (const float*)d_in[3];
  const float* W0  = (const float*)d_in[4];
  const float* b0  = (const float*)d_in[5];
  const float* g0  = (const float*)d_in[6];
  const float* be0 = (const float*)d_in[7];
  const float* W1  = (const float*)d_in[8];
  const float* b1  = (const float*)d_in[9];
  const float* g1  = (const float*)d_in[10];
  const float* be1 = (const float*)d_in[11];

  const size_t MB = 1048576ull;
  char* base = (char*)d_ws;
  u16*   xcat  = (u16*)(base + 0);            // [B][12][N][32] bf16  48MB
  u16*   y0r   = (u16*)(base + 0);            // [B][8][N][32] bf16   32MB (xcat dead)
  float* pnT   = (float*)(base + 48 * MB);    // [B][S][256] f32      16MB (dead after knn)
  u16*   y1b   = (u16*)(base + 48 * MB);      // [B][C2][N] bf16      16MB (overlays pnT)
  u16*   y0b   = (u16*)(base + 64 * MB);      // [B][8][N][32] bf16   32MB
  u16*   W0b   = (u16*)(base + 96 * MB);      // [12][256][32] bf16
  u16*   W1b   = (u16*)(base + 96 * MB + 512 * 1024); // [8][128][32] bf16
  float* coef  = (float*)(base + 97 * MB);    // 768 f
  float* part1 = (float*)(base + 98 * MB);    // [1024][512] f32 2MB
  float* part2 = (float*)(base + 100 * MB);   // [1024][256] f32 1MB
  float* out   = (float*)d_out;

  hipLaunchKernelGGL(cvtW_kernel, dim3((C1_ * C0_ + 255) / 256), dim3(256), 0, stream,
                     W0, W0b, C1_, C0_);
  hipLaunchKernelGGL(cvtW_kernel, dim3((C2_ * C1_ + 255) / 256), dim3(256), 0, stream,
                     W1, W1b, C2_, C1_);
  hipLaunchKernelGGL(transpose_kernel, dim3(S_ / 32, D2_ / 32, B_), dim3(256), 0, stream,
                     points_now, pnT);
  hipLaunchKernelGGL(psaT_kernel, dim3(N_ / 32, D1_ / 32, B_), dim3(256), 0, stream,
                     points_sa, xcat);
  hipLaunchKernelGGL(knn_interp_kernel, dim3(N_ / 64, B_), dim3(256), 0, stream,
                     xyz_sa, xyz_now, pnT, xcat);
  hipLaunchKernelGGL(gemm1_mfma_kernel, dim3(N_ / 128, 2, B_), dim3(256), 0, stream,
                     xcat, W0b, b0, y0b, part1);
  hipLaunchKernelGGL(reduce_coef_kernel, dim3(C1_), dim3(256), 0, stream,
                     part1, 512, C1_, g0, be0, coef);
  hipLaunchKernelGGL(bn0relu_kernel, dim3(2048), dim3(256), 0, stream,
                     y0b, coef, y0r);
  hipLaunchKernelGGL(gemm2_mfma_kernel, dim3(N_ / 128, 1, B_), dim3(256), 0, stream,
                     y0r, W1b, b1, y1b, part2);
  hipLaunchKernelGGL(reduce_coef_kernel, dim3(C2_), dim3(256), 0, stream,
                     part2, 256, C2_, g1, be1, coef + 512);
  hipLaunchKernelGGL(final_kernel, dim3(2048), dim3(256), 0, stream,
                     y1b, coef + 512, out);
}

// Round 12
// 200.707 us; speedup vs baseline: 2.1674x; 1.0229x over previous
//
#include <hip/hip_runtime.h>

#define B_ 8
#define N_ 8192
#define S_ 2048
#define D1_ 128
#define D2_ 256
#define C0_ 384
#define C1_ 256
#define C2_ 128
#define BN_EPS 1e-5f

typedef unsigned long long ull;
typedef unsigned short u16;
typedef __bf16 bf16x8 __attribute__((ext_vector_type(8)));
typedef float f32x4 __attribute__((ext_vector_type(4)));
typedef short short8_ __attribute__((ext_vector_type(8)));

__device__ __forceinline__ u16 f2bf(float x) {
  unsigned int u = __float_as_uint(x);
  unsigned int r = u + 0x7fffu + ((u >> 16) & 1u);
  return (u16)(r >> 16);
}
__device__ __forceinline__ float bf2f(u16 h) {
  return __uint_as_float(((unsigned int)h) << 16);
}

// async global->LDS DMA, 16B/lane; wave-contiguous 1KB source panels.
__device__ __forceinline__ void gld16(const void* g, void* l) {
  __builtin_amdgcn_global_load_lds(
      (const __attribute__((address_space(1))) void*)g,
      (__attribute__((address_space(3))) void*)l,
      16, 0, 0);
}

// branchless sorted-insert of key k into ascending top-3 (k0<=k1<=k2)
__device__ __forceinline__ void ins3(ull k, ull& k0, ull& k1, ull& k2) {
  ull t = k < k2 ? k : k2;
  ull u = k1 < t ? k1 : t;
  k2 = k1 < t ? t : k1;
  k1 = k0 < u ? u : k0;
  k0 = k0 < u ? k0 : u;
}

// ---------------------------------------------------------------------------
// weights f32 [O][K] -> bf16 k-chunked [K/32][O][32]
// ---------------------------------------------------------------------------
__global__ void cvtW_kernel(const float* __restrict__ src, u16* __restrict__ dst,
                            int O, int K)
{
  int i = blockIdx.x * blockDim.x + threadIdx.x;
  if (i < O * K) {
    int o = i / K, kk = i - o * K;
    dst[(((size_t)(kk >> 5) * O + o) << 5) + (kk & 31)] = f2bf(src[i]);
  }
}

// ---------------------------------------------------------------------------
// transpose points_now [B][D2][S] -> pnT [B][S][D2]  (fp32, for knn gather)
// ---------------------------------------------------------------------------
__global__ __launch_bounds__(256) void transpose_kernel(
    const float* __restrict__ in, float* __restrict__ out)
{
  __shared__ float tile[32][33];
  const int b  = blockIdx.z;
  const int s0 = blockIdx.x * 32;
  const int d0 = blockIdx.y * 32;
  const int tx = threadIdx.x & 31, ty = threadIdx.x >> 5;

  const float* inb = in + ((size_t)b * D2_ + d0) * S_ + s0;
  #pragma unroll
  for (int r = 0; r < 4; ++r) {
    int d = r * 8 + ty;
    tile[d][tx] = inb[(size_t)d * S_ + tx];
  }
  __syncthreads();
  float* outb = out + ((size_t)b * S_ + s0) * D2_ + d0;
  #pragma unroll
  for (int r = 0; r < 4; ++r) {
    int s = r * 8 + ty;
    outb[(size_t)s * D2_ + tx] = tile[tx][s];
  }
}

// ---------------------------------------------------------------------------
// points_sa [B][D1][N] f32 -> xcat chunks 0..3  ([12][N][32] per batch, bf16)
// ---------------------------------------------------------------------------
__global__ __launch_bounds__(256) void psaT_kernel(
    const float* __restrict__ in, u16* __restrict__ xcat)
{
  __shared__ float tile[32][33];
  const int b  = blockIdx.z;
  const int n0 = blockIdx.x * 32;
  const int d0 = blockIdx.y * 32;     // chunk = d0>>5
  const int tx = threadIdx.x & 31, ty = threadIdx.x >> 5;

  const float* inb = in + ((size_t)b * D1_ + d0) * N_ + n0;
  #pragma unroll
  for (int r = 0; r < 4; ++r) {
    int d = r * 8 + ty;
    tile[d][tx] = inb[(size_t)d * N_ + tx];
  }
  __syncthreads();
  u16* outb = xcat + (((size_t)b * 12 + (d0 >> 5)) * N_ + n0) * 32;
  #pragma unroll
  for (int r = 0; r < 4; ++r) {
    int n = r * 8 + ty;
    outb[(size_t)n * 32 + tx] = f2bf(tile[tx][n]);
  }
}

// ---------------------------------------------------------------------------
// K1: 3-NN + interpolation. 64 queries/block. LDS cut to ~18KB (2-chunk
// candidate staging, 1024 each) -> 8 blocks/CU = 32 waves (100% occ).
// Keys: d >= 0 on this data (min NN d^2 ~1e-4 >> fp32 rounding ~4e-7), so
// raw float bits are order-exact; fmaxf(d,0) clamp guards the impossible
// negative. Key = (bits<<32)|global_idx — same exact tie-break as before.
// ---------------------------------------------------------------------------
__global__ __launch_bounds__(256) void knn_interp_kernel(
    const float* __restrict__ xyz_sa, const float* __restrict__ xyz_now,
    const float* __restrict__ pnT, u16* __restrict__ xcat)
{
  __shared__ float4 sp[1024];
  __shared__ int   s_idx[64][3];
  __shared__ float s_w[64][3];

  const int b  = blockIdx.y;
  const int n0 = blockIdx.x * 64;

  const int qg = threadIdx.x >> 4;   // 0..15 query group (4 queries)
  const int t  = threadIdx.x & 15;   // scanner 0..15
  const int nb = n0 + qg * 4;

  const float* xq = xyz_sa + (size_t)b * 3 * N_;
  float qx[4], qy[4], qz[4], qq[4];
  #pragma unroll
  for (int w = 0; w < 4; ++w) {
    int n = nb + w;
    qx[w] = xq[n]; qy[w] = xq[N_ + n]; qz[w] = xq[2 * N_ + n];
    qq[w] = qx[w] * qx[w] + qy[w] * qy[w] + qz[w] * qz[w];
  }

  ull K0[4], K1[4], K2[4];
  #pragma unroll
  for (int w = 0; w < 4; ++w) { K0[w] = ~0ull; K1[w] = ~0ull; K2[w] = ~0ull; }

  const float* xb = xyz_now + (size_t)b * 3 * S_;
  for (int chunk = 0; chunk < 2; ++chunk) {
    const int sbase = chunk << 10;
    for (int i = threadIdx.x; i < 1024; i += 256) {
      int sg = sbase + i;
      float px = xb[sg], py = xb[S_ + sg], pz = xb[2 * S_ + sg];
      sp[i] = make_float4(-2.f * px, -2.f * py, -2.f * pz,
                          px * px + py * py + pz * pz);
    }
    __syncthreads();

    #pragma unroll 2
    for (int it = 0; it < 64; ++it) {
      int sl = (it << 4) | t;
      float4 p = sp[sl];
      unsigned int sg = (unsigned int)(sbase + sl);
      #pragma unroll
      for (int w = 0; w < 4; ++w) {
        float d = fmaf(p.x, qx[w], fmaf(p.y, qy[w], fmaf(p.z, qz[w], qq[w] + p.w)));
        d = fmaxf(d, 0.f);
        ull k = ((ull)__float_as_uint(d) << 32) | sg;
        ins3(k, K0[w], K1[w], K2[w]);
      }
    }
    __syncthreads();   // protect sp before next chunk's staging
  }

  // merge the 16 scanners via shuffle butterfly (stays within 16-lane group)
  #pragma unroll
  for (int m = 1; m <= 8; m <<= 1) {
    #pragma unroll
    for (int w = 0; w < 4; ++w) {
      ull o0 = __shfl_xor(K0[w], m), o1 = __shfl_xor(K1[w], m), o2 = __shfl_xor(K2[w], m);
      ins3(o0, K0[w], K1[w], K2[w]);
      ins3(o1, K0[w], K1[w], K2[w]);
      ins3(o2, K0[w], K1[w], K2[w]);
    }
  }

  if (t == 0) {
    #pragma unroll
    for (int w = 0; w < 4; ++w) {
      float d0 = __uint_as_float((unsigned int)(K0[w] >> 32));
      float d1 = __uint_as_float((unsigned int)(K1[w] >> 32));
      float d2 = __uint_as_float((unsigned int)(K2[w] >> 32));
      float r0 = 1.0f / (d0 + 1e-8f);
      float r1 = 1.0f / (d1 + 1e-8f);
      float r2 = 1.0f / (d2 + 1e-8f);
      float rs = 1.0f / (r0 + r1 + r2);
      int qi = qg * 4 + w;
      s_idx[qi][0] = (int)(K0[w] & 0xFFFFFFFFu);
      s_idx[qi][1] = (int)(K1[w] & 0xFFFFFFFFu);
      s_idx[qi][2] = (int)(K2[w] & 0xFFFFFFFFu);
      s_w[qi][0] = r0 * rs; s_w[qi][1] = r1 * rs; s_w[qi][2] = r2 * rs;
    }
  }
  __syncthreads();

  // Phase 2: wave-per-query gather; lane covers chunk 4+(l>>3), 4 channels.
  const int wave = threadIdx.x >> 6;
  const int lane = threadIdx.x & 63;
  const int c8 = lane >> 3;
  const int k4 = (lane & 7) * 4;
  const float* pb = pnT + (size_t)b * S_ * D2_ + c8 * 32 + k4;
  u16* ob = xcat + (((size_t)b * 12 + 4 + c8) * N_ + n0) * 32 + k4;
  #pragma unroll 2
  for (int i = 0; i < 16; ++i) {
    const int qi = wave * 16 + i;
    const int j0 = s_idx[qi][0], j1 = s_idx[qi][1], j2 = s_idx[qi][2];
    const float w0 = s_w[qi][0], w1 = s_w[qi][1], w2 = s_w[qi][2];
    float4 f0 = *(const float4*)(pb + (size_t)j0 * D2_);
    float4 f1 = *(const float4*)(pb + (size_t)j1 * D2_);
    float4 f2 = *(const float4*)(pb + (size_t)j2 * D2_);
    float rx = w0 * f0.x + w1 * f1.x + w2 * f2.x;
    float ry = w0 * f0.y + w1 * f1.y + w2 * f2.y;
    float rz = w0 * f0.z + w1 * f1.z + w2 * f2.z;
    float rw = w0 * f0.w + w1 * f1.w + w2 * f2.w;
    unsigned int lo = (unsigned int)f2bf(rx) | ((unsigned int)f2bf(ry) << 16);
    unsigned int hi = (unsigned int)f2bf(rz) | ((unsigned int)f2bf(rw) << 16);
    *(uint2*)(ob + (size_t)qi * 32) = make_uint2(lo, hi);
  }
}

// ---------------------------------------------------------------------------
union SMg {
  struct { u16 As[2][4096]; u16 Bs[2][4096]; } p;   // [128 rows][32 k] x dbuf
  u16 stage[128][136];
};

// ---------------------------------------------------------------------------
// GEMM1: y0[b,n,o] = W0 . xcat + b0. NO atomics: per-(block,wn) partial
// sums stored to unique slots; reduced later.
// partials1: [1024 slots][512]  (cols 0..255 sum, 256..511 sumsq)
// ---------------------------------------------------------------------------
__global__ __launch_bounds__(256) void gemm1_mfma_kernel(
    const u16* __restrict__ xcat, const u16* __restrict__ W0b,
    const float* __restrict__ b0, u16* __restrict__ y0b, float* __restrict__ partials)
{
  __shared__ SMg sm;

  const int bz = blockIdx.z;
  const int n0 = blockIdx.x * 128;
  const int o0 = blockIdx.y * 128;
  const int tid = threadIdx.x;
  const int wid = tid >> 6, lane = tid & 63;
  const int wo = wid & 1, wn = wid >> 1;
  const int m = lane & 15, g = lane >> 4;

  f32x4 acc[4][4];
  #pragma unroll
  for (int i = 0; i < 4; ++i)
    #pragma unroll
    for (int j = 0; j < 4; ++j) acc[i][j] = (f32x4){0.f, 0.f, 0.f, 0.f};

  auto STAGE = [&](int buf, int c) {
    const u16* asrc = W0b  + ((size_t)c * C1_ + o0) * 32;
    const u16* bsrc = xcat + (((size_t)bz * 12 + c) * N_ + n0) * 32;
    #pragma unroll
    for (int i2 = 0; i2 < 2; ++i2) {
      const int i = wid * 2 + i2;
      gld16(asrc + i * 512 + lane * 8, &sm.p.As[buf][i * 512]);
      gld16(bsrc + i * 512 + lane * 8, &sm.p.Bs[buf][i * 512]);
    }
  };

  STAGE(0, 0);
  __syncthreads();

  for (int kt = 0; kt < 12; ++kt) {
    const int cur = kt & 1;
    if (kt < 11) STAGE(cur ^ 1, kt + 1);

    bf16x8 af[4], bfv[4];
    #pragma unroll
    for (int f = 0; f < 4; ++f)
      af[f] = __builtin_bit_cast(bf16x8,
          *(const short8_*)&sm.p.As[cur][(wo * 64 + f * 16 + m) * 32 + g * 8]);
    #pragma unroll
    for (int f = 0; f < 4; ++f)
      bfv[f] = __builtin_bit_cast(bf16x8,
          *(const short8_*)&sm.p.Bs[cur][(wn * 64 + f * 16 + m) * 32 + g * 8]);
    #pragma unroll
    for (int i = 0; i < 4; ++i)
      #pragma unroll
      for (int j = 0; j < 4; ++j)
        acc[i][j] = __builtin_amdgcn_mfma_f32_16x16x32_bf16(af[i], bfv[j], acc[i][j], 0, 0, 0);

    __syncthreads();
  }

  const int slot = (blockIdx.x * 8 + bz) * 2 + wn;   // 0..1023 unique
  float* prow = partials + (size_t)slot * 512;

  #pragma unroll
  for (int of = 0; of < 4; ++of) {
    const int ol = wo * 64 + of * 16 + g * 4;
    const int ob = o0 + ol;
    float bias[4], s1[4], s2[4];
    #pragma unroll
    for (int r = 0; r < 4; ++r) { bias[r] = b0[ob + r]; s1[r] = 0.f; s2[r] = 0.f; }
    #pragma unroll
    for (int nf = 0; nf < 4; ++nf) {
      const int nl = wn * 64 + nf * 16 + m;
      float y[4];
      #pragma unroll
      for (int r = 0; r < 4; ++r) {
        y[r] = acc[of][nf][r] + bias[r];
        s1[r] += y[r]; s2[r] += y[r] * y[r];
      }
      unsigned int lo = (unsigned int)f2bf(y[0]) | ((unsigned int)f2bf(y[1]) << 16);
      unsigned int hi = (unsigned int)f2bf(y[2]) | ((unsigned int)f2bf(y[3]) << 16);
      *(uint2*)&sm.stage[nl][ol] = make_uint2(lo, hi);
    }
    #pragma unroll
    for (int mk = 1; mk < 16; mk <<= 1)
      #pragma unroll
      for (int r = 0; r < 4; ++r) {
        s1[r] += __shfl_xor(s1[r], mk);
        s2[r] += __shfl_xor(s2[r], mk);
      }
    if (m == 0) {
      *(float4*)(prow + ob)        = make_float4(s1[0], s1[1], s1[2], s1[3]);
      *(float4*)(prow + 256 + ob)  = make_float4(s2[0], s2[1], s2[2], s2[3]);
    }
  }
  __syncthreads();
  {
    const int rrow = tid >> 4;
    const int col  = (tid & 15) * 8;
    const int c    = (o0 + col) >> 5;
    const int ko   = (o0 + col) & 31;
    u16* dst = y0b + (((size_t)bz * 8 + c) * N_ + n0) * 32 + ko;
    #pragma unroll
    for (int pass = 0; pass < 8; ++pass) {
      const int r = pass * 16 + rrow;
      *(uint4*)(dst + (size_t)r * 32) = *(const uint4*)&sm.stage[r][col];
    }
  }
}

// ---------------------------------------------------------------------------
// reduce partials -> BN coef. grid = C blocks; partial row width R floats.
// ---------------------------------------------------------------------------
__global__ __launch_bounds__(256) void reduce_coef_kernel(
    const float* __restrict__ partials, int R, int C,
    const float* __restrict__ g, const float* __restrict__ be,
    float* __restrict__ coef)
{
  const int ch = blockIdx.x;
  const int tid = threadIdx.x;
  float s = 0.f, q = 0.f;
  #pragma unroll
  for (int k = 0; k < 4; ++k) {
    const float* row = partials + (size_t)(tid + k * 256) * R;
    s += row[ch];
    q += row[C + ch];
  }
  #pragma unroll
  for (int mk = 1; mk < 64; mk <<= 1) { s += __shfl_xor(s, mk); q += __shfl_xor(q, mk); }
  __shared__ float ls[4], lq[4];
  const int wid = tid >> 6;
  if ((tid & 63) == 0) { ls[wid] = s; lq[wid] = q; }
  __syncthreads();
  if (tid == 0) {
    s = ls[0] + ls[1] + ls[2] + ls[3];
    q = lq[0] + lq[1] + lq[2] + lq[3];
    const float invM = 1.0f / 65536.0f;   // B*N
    float mean = s * invM;
    float var  = q * invM - mean * mean;
    float a = g[ch] / sqrtf(var + BN_EPS);
    float c = be[ch] - mean * a;
    coef[ch] = a;
    coef[C + ch] = c;
  }
}

// ---------------------------------------------------------------------------
// BN0 + ReLU elementwise on k-chunked y0 [B][8][N][32] (bf16 -> bf16)
// ---------------------------------------------------------------------------
__global__ __launch_bounds__(256) void bn0relu_kernel(
    const u16* __restrict__ y0b, const float* __restrict__ coef, u16* __restrict__ y0r)
{
  __shared__ float cfa[C1_], cfc[C1_];
  cfa[threadIdx.x] = coef[threadIdx.x];
  cfc[threadIdx.x] = coef[C1_ + threadIdx.x];
  __syncthreads();
  const size_t total8 = (size_t)B_ * N_ * C1_ / 8;
  const size_t stride = (size_t)gridDim.x * blockDim.x;
  for (size_t i = (size_t)blockIdx.x * blockDim.x + threadIdx.x; i < total8; i += stride) {
    uint4 v = *(const uint4*)(y0b + i * 8);
    const int ch = (int)(((i >> 15) & 7) * 32 + ((i * 8) & 31));  // chunk*32 + k
    float f0 = fmaxf(0.f, fmaf(bf2f((u16)(v.x & 0xffff)), cfa[ch + 0], cfc[ch + 0]));
    float f1 = fmaxf(0.f, fmaf(bf2f((u16)(v.x >> 16)),    cfa[ch + 1], cfc[ch + 1]));
    float f2 = fmaxf(0.f, fmaf(bf2f((u16)(v.y & 0xffff)), cfa[ch + 2], cfc[ch + 2]));
    float f3 = fmaxf(0.f, fmaf(bf2f((u16)(v.y >> 16)),    cfa[ch + 3], cfc[ch + 3]));
    float f4 = fmaxf(0.f, fmaf(bf2f((u16)(v.z & 0xffff)), cfa[ch + 4], cfc[ch + 4]));
    float f5 = fmaxf(0.f, fmaf(bf2f((u16)(v.z >> 16)),    cfa[ch + 5], cfc[ch + 5]));
    float f6 = fmaxf(0.f, fmaf(bf2f((u16)(v.w & 0xffff)), cfa[ch + 6], cfc[ch + 6]));
    float f7 = fmaxf(0.f, fmaf(bf2f((u16)(v.w >> 16)),    cfa[ch + 7], cfc[ch + 7]));
    uint4 o;
    o.x = (unsigned int)f2bf(f0) | ((unsigned int)f2bf(f1) << 16);
    o.y = (unsigned int)f2bf(f2) | ((unsigned int)f2bf(f3) << 16);
    o.z = (unsigned int)f2bf(f4) | ((unsigned int)f2bf(f5) << 16);
    o.w = (unsigned int)f2bf(f6) | ((unsigned int)f2bf(f7) << 16);
    *(uint4*)(y0r + i * 8) = o;
  }
}

// ---------------------------------------------------------------------------
// GEMM2: y1b[b,p,n] = W1 . y0r + b1. partials2: [1024 slots][256].
// ---------------------------------------------------------------------------
__global__ __launch_bounds__(256) void gemm2_mfma_kernel(
    const u16* __restrict__ y0r, const u16* __restrict__ W1b,
    const float* __restrict__ b1, u16* __restrict__ y1b, float* __restrict__ partials)
{
  __shared__ SMg sm;

  const int bz = blockIdx.z;
  const int n0 = blockIdx.x * 128;
  const int tid = threadIdx.x;
  const int wid = tid >> 6, lane = tid & 63;
  const int wo = wid & 1, wn = wid >> 1;
  const int m = lane & 15, g = lane >> 4;

  f32x4 acc[4][4];
  #pragma unroll
  for (int i = 0; i < 4; ++i)
    #pragma unroll
    for (int j = 0; j < 4; ++j) acc[i][j] = (f32x4){0.f, 0.f, 0.f, 0.f};

  auto STAGE = [&](int buf, int c) {
    const u16* asrc = W1b + ((size_t)c * C2_) * 32;
    const u16* bsrc = y0r + (((size_t)bz * 8 + c) * N_ + n0) * 32;
    #pragma unroll
    for (int i2 = 0; i2 < 2; ++i2) {
      const int i = wid * 2 + i2;
      gld16(asrc + i * 512 + lane * 8, &sm.p.As[buf][i * 512]);
      gld16(bsrc + i * 512 + lane * 8, &sm.p.Bs[buf][i * 512]);
    }
  };

  STAGE(0, 0);
  __syncthreads();

  for (int kt = 0; kt < 8; ++kt) {
    const int cur = kt & 1;
    if (kt < 7) STAGE(cur ^ 1, kt + 1);

    bf16x8 af[4], bfv[4];
    #pragma unroll
    for (int f = 0; f < 4; ++f)
      af[f] = __builtin_bit_cast(bf16x8,
          *(const short8_*)&sm.p.As[cur][(wo * 64 + f * 16 + m) * 32 + g * 8]);
    #pragma unroll
    for (int f = 0; f < 4; ++f)
      bfv[f] = __builtin_bit_cast(bf16x8,
          *(const short8_*)&sm.p.Bs[cur][(wn * 64 + f * 16 + m) * 32 + g * 8]);
    #pragma unroll
    for (int i = 0; i < 4; ++i)
      #pragma unroll
      for (int j = 0; j < 4; ++j)
        acc[i][j] = __builtin_amdgcn_mfma_f32_16x16x32_bf16(af[i], bfv[j], acc[i][j], 0, 0, 0);

    __syncthreads();
  }

  const int slot = (blockIdx.x * 8 + bz) * 2 + wn;   // 0..1023 unique
  float* prow = partials + (size_t)slot * 256;

  #pragma unroll
  for (int of = 0; of < 4; ++of) {
    const int pb = wo * 64 + of * 16 + g * 4;
    float bias[4], s1[4], s2[4];
    #pragma unroll
    for (int r = 0; r < 4; ++r) { bias[r] = b1[pb + r]; s1[r] = 0.f; s2[r] = 0.f; }
    #pragma unroll
    for (int nf = 0; nf < 4; ++nf) {
      const int nl = wn * 64 + nf * 16 + m;
      #pragma unroll
      for (int r = 0; r < 4; ++r) {
        float y = acc[of][nf][r] + bias[r];
        s1[r] += y; s2[r] += y * y;
        sm.stage[pb + r][nl] = f2bf(y);
      }
    }
    #pragma unroll
    for (int mk = 1; mk < 16; mk <<= 1)
      #pragma unroll
      for (int r = 0; r < 4; ++r) {
        s1[r] += __shfl_xor(s1[r], mk);
        s2[r] += __shfl_xor(s2[r], mk);
      }
    if (m == 0) {
      *(float4*)(prow + pb)        = make_float4(s1[0], s1[1], s1[2], s1[3]);
      *(float4*)(prow + 128 + pb)  = make_float4(s2[0], s2[1], s2[2], s2[3]);
    }
  }
  __syncthreads();
  {
    #pragma unroll
    for (int pass = 0; pass < 8; ++pass) {
      const int idx = pass * 256 + tid;
      const int p = idx >> 4;
      const int c8 = (idx & 15) * 8;
      uint4 v = *(const uint4*)&sm.stage[p][c8];
      *(uint4*)(y1b + ((size_t)bz * C2_ + p) * N_ + n0 + c8) = v;
    }
  }
}

// ---------------------------------------------------------------------------
// final: BN1 + ReLU elementwise, bf16 in -> fp32 out  (y1b is [B][C2][N])
// ---------------------------------------------------------------------------
__global__ __launch_bounds__(256) void final_kernel(
    const u16* __restrict__ y1b, const float* __restrict__ cf, float* __restrict__ out)
{
  const size_t total4 = (size_t)B_ * C2_ * N_ / 4;
  const size_t stride = (size_t)gridDim.x * blockDim.x;
  for (size_t f = (size_t)blockIdx.x * blockDim.x + threadIdx.x; f < total4; f += stride) {
    size_t base = f * 4;
    int p = (int)((base >> 13) & (C2_ - 1));
    float a = cf[p], c = cf[C2_ + p];
    uint2 v = *(const uint2*)(y1b + base);
    float4 r;
    r.x = fmaxf(0.0f, fmaf(bf2f((u16)(v.x & 0xffff)), a, c));
    r.y = fmaxf(0.0f, fmaf(bf2f((u16)(v.x >> 16)),    a, c));
    r.z = fmaxf(0.0f, fmaf(bf2f((u16)(v.y & 0xffff)), a, c));
    r.w = fmaxf(0.0f, fmaf(bf2f((u16)(v.y >> 16)),    a, c));
    *(float4*)(out + base) = r;
  }
}

// ---------------------------------------------------------------------------
extern "C" void kernel_launch(void* const* d_in, const int* in_sizes, int n_in,
                              void* d_out, int out_size, void* d_ws, size_t ws_size,
                              hipStream_t stream)
{
  const float* xyz_sa     = (const float*)d_in[0];
  const float* xyz_now    = (const float*)d_in[1];
  const float* points_sa  = (const float*)d_in[2];
  const float* points_now = (const float*)d_in[3];
  const float* W0  = (const float*)d_in[4];
  const float* b0  = (const float*)d_in[5];
  const float* g0  = (const float*)d_in[6];
  const float* be0 = (const float*)d_in[7];
  const float* W1  = (const float*)d_in[8];
  const float* b1  = (const float*)d_in[9];
  const float* g1  = (const float*)d_in[10];
  const float* be1 = (const float*)d_in[11];

  const size_t MB = 1048576ull;
  char* base = (char*)d_ws;
  u16*   xcat  = (u16*)(base + 0);            // [B][12][N][32] bf16  48MB
  u16*   y0r   = (u16*)(base + 0);            // [B][8][N][32] bf16   32MB (xcat dead)
  float* pnT   = (float*)(base + 48 * MB);    // [B][S][256] f32      16MB (dead after knn)
  u16*   y1b   = (u16*)(base + 48 * MB);      // [B][C2][N] bf16      16MB (overlays pnT)
  u16*   y0b   = (u16*)(base + 64 * MB);      // [B][8][N][32] bf16   32MB
  u16*   W0b   = (u16*)(base + 96 * MB);      // [12][256][32] bf16
  u16*   W1b   = (u16*)(base + 96 * MB + 512 * 1024); // [8][128][32] bf16
  float* coef  = (float*)(base + 97 * MB);    // 768 f
  float* part1 = (float*)(base + 98 * MB);    // [1024][512] f32 2MB
  float* part2 = (float*)(base + 100 * MB);   // [1024][256] f32 1MB
  float* out   = (float*)d_out;

  hipLaunchKernelGGL(cvtW_kernel, dim3((C1_ * C0_ + 255) / 256), dim3(256), 0, stream,
                     W0, W0b, C1_, C0_);
  hipLaunchKernelGGL(cvtW_kernel, dim3((C2_ * C1_ + 255) / 256), dim3(256), 0, stream,
                     W1, W1b, C2_, C1_);
  hipLaunchKernelGGL(transpose_kernel, dim3(S_ / 32, D2_ / 32, B_), dim3(256), 0, stream,
                     points_now, pnT);
  hipLaunchKernelGGL(psaT_kernel, dim3(N_ / 32, D1_ / 32, B_), dim3(256), 0, stream,
                     points_sa, xcat);
  hipLaunchKernelGGL(knn_interp_kernel, dim3(N_ / 64, B_), dim3(256), 0, stream,
                     xyz_sa, xyz_now, pnT, xcat);
  hipLaunchKernelGGL(gemm1_mfma_kernel, dim3(N_ / 128, 2, B_), dim3(256), 0, stream,
                     xcat, W0b, b0, y0b, part1);
  hipLaunchKernelGGL(reduce_coef_kernel, dim3(C1_), dim3(256), 0, stream,
                     part1, 512, C1_, g0, be0, coef);
  hipLaunchKernelGGL(bn0relu_kernel, dim3(2048), dim3(256), 0, stream,
                     y0b, coef, y0r);
  hipLaunchKernelGGL(gemm2_mfma_kernel, dim3(N_ / 128, 1, B_), dim3(256), 0, stream,
                     y0r, W1b, b1, y1b, part2);
  hipLaunchKernelGGL(reduce_coef_kernel, dim3(C2_), dim3(256), 0, stream,
                     part2, 256, C2_, g1, be1, coef + 512);
  hipLaunchKernelGGL(final_kernel, dim3(2048), dim3(256), 0, stream,
                     y1b, coef + 512, out);
}

// Round 13
// 196.462 us; speedup vs baseline: 2.2143x; 1.0216x over previous
//
#include <hip/hip_runtime.h>

#define B_ 8
#define N_ 8192
#define S_ 2048
#define D1_ 128
#define D2_ 256
#define C0_ 384
#define C1_ 256
#define C2_ 128
#define BN_EPS 1e-5f

typedef unsigned long long ull;
typedef unsigned short u16;
typedef __bf16 bf16x8 __attribute__((ext_vector_type(8)));
typedef float f32x4 __attribute__((ext_vector_type(4)));
typedef short short8_ __attribute__((ext_vector_type(8)));

__device__ __forceinline__ u16 f2bf(float x) {
  unsigned int u = __float_as_uint(x);
  unsigned int r = u + 0x7fffu + ((u >> 16) & 1u);
  return (u16)(r >> 16);
}
__device__ __forceinline__ float bf2f(u16 h) {
  return __uint_as_float(((unsigned int)h) << 16);
}

// async global->LDS DMA, 16B/lane; wave-contiguous 1KB source panels.
__device__ __forceinline__ void gld16(const void* g, void* l) {
  __builtin_amdgcn_global_load_lds(
      (const __attribute__((address_space(1))) void*)g,
      (__attribute__((address_space(3))) void*)l,
      16, 0, 0);
}

// branchless sorted-insert of key k into ascending top-3 (k0<=k1<=k2)
__device__ __forceinline__ void ins3(ull k, ull& k0, ull& k1, ull& k2) {
  ull t = k < k2 ? k : k2;
  ull u = k1 < t ? k1 : t;
  k2 = k1 < t ? t : k1;
  k1 = k0 < u ? u : k0;
  k0 = k0 < u ? k0 : u;
}

// ---------------------------------------------------------------------------
// weights f32 [O][K] -> bf16 k-chunked [K/32][O][32]
// ---------------------------------------------------------------------------
__global__ void cvtW_kernel(const float* __restrict__ src, u16* __restrict__ dst,
                            int O, int K)
{
  int i = blockIdx.x * blockDim.x + threadIdx.x;
  if (i < O * K) {
    int o = i / K, kk = i - o * K;
    dst[(((size_t)(kk >> 5) * O + o) << 5) + (kk & 31)] = f2bf(src[i]);
  }
}

// ---------------------------------------------------------------------------
// transpose points_now [B][D2][S] -> pnT [B][S][D2]  (fp32, for knn gather)
// ---------------------------------------------------------------------------
__global__ __launch_bounds__(256) void transpose_kernel(
    const float* __restrict__ in, float* __restrict__ out)
{
  __shared__ float tile[32][33];
  const int b  = blockIdx.z;
  const int s0 = blockIdx.x * 32;
  const int d0 = blockIdx.y * 32;
  const int tx = threadIdx.x & 31, ty = threadIdx.x >> 5;

  const float* inb = in + ((size_t)b * D2_ + d0) * S_ + s0;
  #pragma unroll
  for (int r = 0; r < 4; ++r) {
    int d = r * 8 + ty;
    tile[d][tx] = inb[(size_t)d * S_ + tx];
  }
  __syncthreads();
  float* outb = out + ((size_t)b * S_ + s0) * D2_ + d0;
  #pragma unroll
  for (int r = 0; r < 4; ++r) {
    int s = r * 8 + ty;
    outb[(size_t)s * D2_ + tx] = tile[tx][s];
  }
}

// ---------------------------------------------------------------------------
// points_sa [B][D1][N] f32 -> xcat chunks 0..3  ([12][N][32] per batch, bf16)
// ---------------------------------------------------------------------------
__global__ __launch_bounds__(256) void psaT_kernel(
    const float* __restrict__ in, u16* __restrict__ xcat)
{
  __shared__ float tile[32][33];
  const int b  = blockIdx.z;
  const int n0 = blockIdx.x * 32;
  const int d0 = blockIdx.y * 32;     // chunk = d0>>5
  const int tx = threadIdx.x & 31, ty = threadIdx.x >> 5;

  const float* inb = in + ((size_t)b * D1_ + d0) * N_ + n0;
  #pragma unroll
  for (int r = 0; r < 4; ++r) {
    int d = r * 8 + ty;
    tile[d][tx] = inb[(size_t)d * N_ + tx];
  }
  __syncthreads();
  u16* outb = xcat + (((size_t)b * 12 + (d0 >> 5)) * N_ + n0) * 32;
  #pragma unroll
  for (int r = 0; r < 4; ++r) {
    int n = r * 8 + ty;
    outb[(size_t)n * 32 + tx] = f2bf(tile[tx][n]);
  }
}

// ---------------------------------------------------------------------------
// K1: 3-NN + interpolation. 32 queries/block, grid 256xB = 2048 blocks ->
// 8 blocks/CU (LDS ~17KB) = 32 waves/CU. 2 queries/thread, 16 scanners.
// Keys: d>=0 on this data so raw float bits are order-exact; fmaxf(d,0)
// guards the impossible negative. Key=(bits<<32)|global_idx (exact ties).
// ---------------------------------------------------------------------------
__global__ __launch_bounds__(256) void knn_interp_kernel(
    const float* __restrict__ xyz_sa, const float* __restrict__ xyz_now,
    const float* __restrict__ pnT, u16* __restrict__ xcat)
{
  __shared__ float4 sp[1024];
  __shared__ int   s_idx[32][3];
  __shared__ float s_w[32][3];

  const int b  = blockIdx.y;
  const int n0 = blockIdx.x * 32;

  const int qg = threadIdx.x >> 4;   // 0..15 query group (2 queries)
  const int t  = threadIdx.x & 15;   // scanner 0..15
  const int nb = n0 + qg * 2;

  const float* xq = xyz_sa + (size_t)b * 3 * N_;
  float qx[2], qy[2], qz[2], qq[2];
  #pragma unroll
  for (int w = 0; w < 2; ++w) {
    int n = nb + w;
    qx[w] = xq[n]; qy[w] = xq[N_ + n]; qz[w] = xq[2 * N_ + n];
    qq[w] = qx[w] * qx[w] + qy[w] * qy[w] + qz[w] * qz[w];
  }

  ull K0[2], K1[2], K2[2];
  #pragma unroll
  for (int w = 0; w < 2; ++w) { K0[w] = ~0ull; K1[w] = ~0ull; K2[w] = ~0ull; }

  const float* xb = xyz_now + (size_t)b * 3 * S_;
  for (int chunk = 0; chunk < 2; ++chunk) {
    const int sbase = chunk << 10;
    for (int i = threadIdx.x; i < 1024; i += 256) {
      int sg = sbase + i;
      float px = xb[sg], py = xb[S_ + sg], pz = xb[2 * S_ + sg];
      sp[i] = make_float4(-2.f * px, -2.f * py, -2.f * pz,
                          px * px + py * py + pz * pz);
    }
    __syncthreads();

    #pragma unroll 4
    for (int it = 0; it < 64; ++it) {
      int sl = (it << 4) | t;
      float4 p = sp[sl];
      unsigned int sg = (unsigned int)(sbase + sl);
      #pragma unroll
      for (int w = 0; w < 2; ++w) {
        float d = fmaf(p.x, qx[w], fmaf(p.y, qy[w], fmaf(p.z, qz[w], qq[w] + p.w)));
        d = fmaxf(d, 0.f);
        ull k = ((ull)__float_as_uint(d) << 32) | sg;
        ins3(k, K0[w], K1[w], K2[w]);
      }
    }
    __syncthreads();   // protect sp before next chunk's staging
  }

  // merge the 16 scanners via shuffle butterfly (stays within 16-lane group)
  #pragma unroll
  for (int m = 1; m <= 8; m <<= 1) {
    #pragma unroll
    for (int w = 0; w < 2; ++w) {
      ull o0 = __shfl_xor(K0[w], m), o1 = __shfl_xor(K1[w], m), o2 = __shfl_xor(K2[w], m);
      ins3(o0, K0[w], K1[w], K2[w]);
      ins3(o1, K0[w], K1[w], K2[w]);
      ins3(o2, K0[w], K1[w], K2[w]);
    }
  }

  if (t == 0) {
    #pragma unroll
    for (int w = 0; w < 2; ++w) {
      float d0 = __uint_as_float((unsigned int)(K0[w] >> 32));
      float d1 = __uint_as_float((unsigned int)(K1[w] >> 32));
      float d2 = __uint_as_float((unsigned int)(K2[w] >> 32));
      float r0 = 1.0f / (d0 + 1e-8f);
      float r1 = 1.0f / (d1 + 1e-8f);
      float r2 = 1.0f / (d2 + 1e-8f);
      float rs = 1.0f / (r0 + r1 + r2);
      int qi = qg * 2 + w;
      s_idx[qi][0] = (int)(K0[w] & 0xFFFFFFFFu);
      s_idx[qi][1] = (int)(K1[w] & 0xFFFFFFFFu);
      s_idx[qi][2] = (int)(K2[w] & 0xFFFFFFFFu);
      s_w[qi][0] = r0 * rs; s_w[qi][1] = r1 * rs; s_w[qi][2] = r2 * rs;
    }
  }
  __syncthreads();

  // Phase 2: wave-per-query gather; lane covers chunk 4+(l>>3), 4 channels.
  const int wave = threadIdx.x >> 6;
  const int lane = threadIdx.x & 63;
  const int c8 = lane >> 3;
  const int k4 = (lane & 7) * 4;
  const float* pb = pnT + (size_t)b * S_ * D2_ + c8 * 32 + k4;
  u16* ob = xcat + (((size_t)b * 12 + 4 + c8) * N_ + n0) * 32 + k4;
  #pragma unroll 2
  for (int i = 0; i < 8; ++i) {
    const int qi = wave * 8 + i;
    const int j0 = s_idx[qi][0], j1 = s_idx[qi][1], j2 = s_idx[qi][2];
    const float w0 = s_w[qi][0], w1 = s_w[qi][1], w2 = s_w[qi][2];
    float4 f0 = *(const float4*)(pb + (size_t)j0 * D2_);
    float4 f1 = *(const float4*)(pb + (size_t)j1 * D2_);
    float4 f2 = *(const float4*)(pb + (size_t)j2 * D2_);
    float rx = w0 * f0.x + w1 * f1.x + w2 * f2.x;
    float ry = w0 * f0.y + w1 * f1.y + w2 * f2.y;
    float rz = w0 * f0.z + w1 * f1.z + w2 * f2.z;
    float rw = w0 * f0.w + w1 * f1.w + w2 * f2.w;
    unsigned int lo = (unsigned int)f2bf(rx) | ((unsigned int)f2bf(ry) << 16);
    unsigned int hi = (unsigned int)f2bf(rz) | ((unsigned int)f2bf(rw) << 16);
    *(uint2*)(ob + (size_t)qi * 32) = make_uint2(lo, hi);
  }
}

// ---------------------------------------------------------------------------
union SMg {
  struct { u16 As[2][4096]; u16 Bs[2][4096]; } p;   // [128 rows][32 k] x dbuf
  u16 stage[128][136];
};

// ---------------------------------------------------------------------------
// GEMM1: y0[b,n,o] = W0 . xcat + b0. NO atomics: per-(block,wn) partial
// sums stored to unique slots; reduced later.
// partials1: [1024 slots][512]  (cols 0..255 sum, 256..511 sumsq)
// ---------------------------------------------------------------------------
__global__ __launch_bounds__(256) void gemm1_mfma_kernel(
    const u16* __restrict__ xcat, const u16* __restrict__ W0b,
    const float* __restrict__ b0, u16* __restrict__ y0b, float* __restrict__ partials)
{
  __shared__ SMg sm;

  const int bz = blockIdx.z;
  const int n0 = blockIdx.x * 128;
  const int o0 = blockIdx.y * 128;
  const int tid = threadIdx.x;
  const int wid = tid >> 6, lane = tid & 63;
  const int wo = wid & 1, wn = wid >> 1;
  const int m = lane & 15, g = lane >> 4;

  f32x4 acc[4][4];
  #pragma unroll
  for (int i = 0; i < 4; ++i)
    #pragma unroll
    for (int j = 0; j < 4; ++j) acc[i][j] = (f32x4){0.f, 0.f, 0.f, 0.f};

  auto STAGE = [&](int buf, int c) {
    const u16* asrc = W0b  + ((size_t)c * C1_ + o0) * 32;
    const u16* bsrc = xcat + (((size_t)bz * 12 + c) * N_ + n0) * 32;
    #pragma unroll
    for (int i2 = 0; i2 < 2; ++i2) {
      const int i = wid * 2 + i2;
      gld16(asrc + i * 512 + lane * 8, &sm.p.As[buf][i * 512]);
      gld16(bsrc + i * 512 + lane * 8, &sm.p.Bs[buf][i * 512]);
    }
  };

  STAGE(0, 0);
  __syncthreads();

  for (int kt = 0; kt < 12; ++kt) {
    const int cur = kt & 1;
    if (kt < 11) STAGE(cur ^ 1, kt + 1);

    bf16x8 af[4], bfv[4];
    #pragma unroll
    for (int f = 0; f < 4; ++f)
      af[f] = __builtin_bit_cast(bf16x8,
          *(const short8_*)&sm.p.As[cur][(wo * 64 + f * 16 + m) * 32 + g * 8]);
    #pragma unroll
    for (int f = 0; f < 4; ++f)
      bfv[f] = __builtin_bit_cast(bf16x8,
          *(const short8_*)&sm.p.Bs[cur][(wn * 64 + f * 16 + m) * 32 + g * 8]);
    #pragma unroll
    for (int i = 0; i < 4; ++i)
      #pragma unroll
      for (int j = 0; j < 4; ++j)
        acc[i][j] = __builtin_amdgcn_mfma_f32_16x16x32_bf16(af[i], bfv[j], acc[i][j], 0, 0, 0);

    __syncthreads();
  }

  const int slot = (blockIdx.x * 8 + bz) * 2 + wn;   // 0..1023 unique
  float* prow = partials + (size_t)slot * 512;

  #pragma unroll
  for (int of = 0; of < 4; ++of) {
    const int ol = wo * 64 + of * 16 + g * 4;
    const int ob = o0 + ol;
    float bias[4], s1[4], s2[4];
    #pragma unroll
    for (int r = 0; r < 4; ++r) { bias[r] = b0[ob + r]; s1[r] = 0.f; s2[r] = 0.f; }
    #pragma unroll
    for (int nf = 0; nf < 4; ++nf) {
      const int nl = wn * 64 + nf * 16 + m;
      float y[4];
      #pragma unroll
      for (int r = 0; r < 4; ++r) {
        y[r] = acc[of][nf][r] + bias[r];
        s1[r] += y[r]; s2[r] += y[r] * y[r];
      }
      unsigned int lo = (unsigned int)f2bf(y[0]) | ((unsigned int)f2bf(y[1]) << 16);
      unsigned int hi = (unsigned int)f2bf(y[2]) | ((unsigned int)f2bf(y[3]) << 16);
      *(uint2*)&sm.stage[nl][ol] = make_uint2(lo, hi);
    }
    #pragma unroll
    for (int mk = 1; mk < 16; mk <<= 1)
      #pragma unroll
      for (int r = 0; r < 4; ++r) {
        s1[r] += __shfl_xor(s1[r], mk);
        s2[r] += __shfl_xor(s2[r], mk);
      }
    if (m == 0) {
      *(float4*)(prow + ob)        = make_float4(s1[0], s1[1], s1[2], s1[3]);
      *(float4*)(prow + 256 + ob)  = make_float4(s2[0], s2[1], s2[2], s2[3]);
    }
  }
  __syncthreads();
  {
    const int rrow = tid >> 4;
    const int col  = (tid & 15) * 8;
    const int c    = (o0 + col) >> 5;
    const int ko   = (o0 + col) & 31;
    u16* dst = y0b + (((size_t)bz * 8 + c) * N_ + n0) * 32 + ko;
    #pragma unroll
    for (int pass = 0; pass < 8; ++pass) {
      const int r = pass * 16 + rrow;
      *(uint4*)(dst + (size_t)r * 32) = *(const uint4*)&sm.stage[r][col];
    }
  }
}

// ---------------------------------------------------------------------------
// reduce partials -> BN coef. grid = C blocks; partial row width R floats.
// ---------------------------------------------------------------------------
__global__ __launch_bounds__(256) void reduce_coef_kernel(
    const float* __restrict__ partials, int R, int C,
    const float* __restrict__ g, const float* __restrict__ be,
    float* __restrict__ coef)
{
  const int ch = blockIdx.x;
  const int tid = threadIdx.x;
  float s = 0.f, q = 0.f;
  #pragma unroll
  for (int k = 0; k < 4; ++k) {
    const float* row = partials + (size_t)(tid + k * 256) * R;
    s += row[ch];
    q += row[C + ch];
  }
  #pragma unroll
  for (int mk = 1; mk < 64; mk <<= 1) { s += __shfl_xor(s, mk); q += __shfl_xor(q, mk); }
  __shared__ float ls[4], lq[4];
  const int wid = tid >> 6;
  if ((tid & 63) == 0) { ls[wid] = s; lq[wid] = q; }
  __syncthreads();
  if (tid == 0) {
    s = ls[0] + ls[1] + ls[2] + ls[3];
    q = lq[0] + lq[1] + lq[2] + lq[3];
    const float invM = 1.0f / 65536.0f;   // B*N
    float mean = s * invM;
    float var  = q * invM - mean * mean;
    float a = g[ch] / sqrtf(var + BN_EPS);
    float c = be[ch] - mean * a;
    coef[ch] = a;
    coef[C + ch] = c;
  }
}

// ---------------------------------------------------------------------------
// BN0 + ReLU elementwise on k-chunked y0 [B][8][N][32] (bf16 -> bf16)
// ---------------------------------------------------------------------------
__global__ __launch_bounds__(256) void bn0relu_kernel(
    const u16* __restrict__ y0b, const float* __restrict__ coef, u16* __restrict__ y0r)
{
  __shared__ float cfa[C1_], cfc[C1_];
  cfa[threadIdx.x] = coef[threadIdx.x];
  cfc[threadIdx.x] = coef[C1_ + threadIdx.x];
  __syncthreads();
  const size_t total8 = (size_t)B_ * N_ * C1_ / 8;
  const size_t stride = (size_t)gridDim.x * blockDim.x;
  for (size_t i = (size_t)blockIdx.x * blockDim.x + threadIdx.x; i < total8; i += stride) {
    uint4 v = *(const uint4*)(y0b + i * 8);
    const int ch = (int)(((i >> 15) & 7) * 32 + ((i * 8) & 31));  // chunk*32 + k
    float f0 = fmaxf(0.f, fmaf(bf2f((u16)(v.x & 0xffff)), cfa[ch + 0], cfc[ch + 0]));
    float f1 = fmaxf(0.f, fmaf(bf2f((u16)(v.x >> 16)),    cfa[ch + 1], cfc[ch + 1]));
    float f2 = fmaxf(0.f, fmaf(bf2f((u16)(v.y & 0xffff)), cfa[ch + 2], cfc[ch + 2]));
    float f3 = fmaxf(0.f, fmaf(bf2f((u16)(v.y >> 16)),    cfa[ch + 3], cfc[ch + 3]));
    float f4 = fmaxf(0.f, fmaf(bf2f((u16)(v.z & 0xffff)), cfa[ch + 4], cfc[ch + 4]));
    float f5 = fmaxf(0.f, fmaf(bf2f((u16)(v.z >> 16)),    cfa[ch + 5], cfc[ch + 5]));
    float f6 = fmaxf(0.f, fmaf(bf2f((u16)(v.w & 0xffff)), cfa[ch + 6], cfc[ch + 6]));
    float f7 = fmaxf(0.f, fmaf(bf2f((u16)(v.w >> 16)),    cfa[ch + 7], cfc[ch + 7]));
    uint4 o;
    o.x = (unsigned int)f2bf(f0) | ((unsigned int)f2bf(f1) << 16);
    o.y = (unsigned int)f2bf(f2) | ((unsigned int)f2bf(f3) << 16);
    o.z = (unsigned int)f2bf(f4) | ((unsigned int)f2bf(f5) << 16);
    o.w = (unsigned int)f2bf(f6) | ((unsigned int)f2bf(f7) << 16);
    *(uint4*)(y0r + i * 8) = o;
  }
}

// ---------------------------------------------------------------------------
// GEMM2: y1b[b,p,n] = W1 . y0r + b1. partials2: [1024 slots][256].
// ---------------------------------------------------------------------------
__global__ __launch_bounds__(256) void gemm2_mfma_kernel(
    const u16* __restrict__ y0r, const u16* __restrict__ W1b,
    const float* __restrict__ b1, u16* __restrict__ y1b, float* __restrict__ partials)
{
  __shared__ SMg sm;

  const int bz = blockIdx.z;
  const int n0 = blockIdx.x * 128;
  const int tid = threadIdx.x;
  const int wid = tid >> 6, lane = tid & 63;
  const int wo = wid & 1, wn = wid >> 1;
  const int m = lane & 15, g = lane >> 4;

  f32x4 acc[4][4];
  #pragma unroll
  for (int i = 0; i < 4; ++i)
    #pragma unroll
    for (int j = 0; j < 4; ++j) acc[i][j] = (f32x4){0.f, 0.f, 0.f, 0.f};

  auto STAGE = [&](int buf, int c) {
    const u16* asrc = W1b + ((size_t)c * C2_) * 32;
    const u16* bsrc = y0r + (((size_t)bz * 8 + c) * N_ + n0) * 32;
    #pragma unroll
    for (int i2 = 0; i2 < 2; ++i2) {
      const int i = wid * 2 + i2;
      gld16(asrc + i * 512 + lane * 8, &sm.p.As[buf][i * 512]);
      gld16(bsrc + i * 512 + lane * 8, &sm.p.Bs[buf][i * 512]);
    }
  };

  STAGE(0, 0);
  __syncthreads();

  for (int kt = 0; kt < 8; ++kt) {
    const int cur = kt & 1;
    if (kt < 7) STAGE(cur ^ 1, kt + 1);

    bf16x8 af[4], bfv[4];
    #pragma unroll
    for (int f = 0; f < 4; ++f)
      af[f] = __builtin_bit_cast(bf16x8,
          *(const short8_*)&sm.p.As[cur][(wo * 64 + f * 16 + m) * 32 + g * 8]);
    #pragma unroll
    for (int f = 0; f < 4; ++f)
      bfv[f] = __builtin_bit_cast(bf16x8,
          *(const short8_*)&sm.p.Bs[cur][(wn * 64 + f * 16 + m) * 32 + g * 8]);
    #pragma unroll
    for (int i = 0; i < 4; ++i)
      #pragma unroll
      for (int j = 0; j < 4; ++j)
        acc[i][j] = __builtin_amdgcn_mfma_f32_16x16x32_bf16(af[i], bfv[j], acc[i][j], 0, 0, 0);

    __syncthreads();
  }

  const int slot = (blockIdx.x * 8 + bz) * 2 + wn;   // 0..1023 unique
  float* prow = partials + (size_t)slot * 256;

  #pragma unroll
  for (int of = 0; of < 4; ++of) {
    const int pb = wo * 64 + of * 16 + g * 4;
    float bias[4], s1[4], s2[4];
    #pragma unroll
    for (int r = 0; r < 4; ++r) { bias[r] = b1[pb + r]; s1[r] = 0.f; s2[r] = 0.f; }
    #pragma unroll
    for (int nf = 0; nf < 4; ++nf) {
      const int nl = wn * 64 + nf * 16 + m;
      #pragma unroll
      for (int r = 0; r < 4; ++r) {
        float y = acc[of][nf][r] + bias[r];
        s1[r] += y; s2[r] += y * y;
        sm.stage[pb + r][nl] = f2bf(y);
      }
    }
    #pragma unroll
    for (int mk = 1; mk < 16; mk <<= 1)
      #pragma unroll
      for (int r = 0; r < 4; ++r) {
        s1[r] += __shfl_xor(s1[r], mk);
        s2[r] += __shfl_xor(s2[r], mk);
      }
    if (m == 0) {
      *(float4*)(prow + pb)        = make_float4(s1[0], s1[1], s1[2], s1[3]);
      *(float4*)(prow + 128 + pb)  = make_float4(s2[0], s2[1], s2[2], s2[3]);
    }
  }
  __syncthreads();
  {
    #pragma unroll
    for (int pass = 0; pass < 8; ++pass) {
      const int idx = pass * 256 + tid;
      const int p = idx >> 4;
      const int c8 = (idx & 15) * 8;
      uint4 v = *(const uint4*)&sm.stage[p][c8];
      *(uint4*)(y1b + ((size_t)bz * C2_ + p) * N_ + n0 + c8) = v;
    }
  }
}

// ---------------------------------------------------------------------------
// final: BN1 + ReLU elementwise, bf16 in -> fp32 out  (y1b is [B][C2][N])
// ---------------------------------------------------------------------------
__global__ __launch_bounds__(256) void final_kernel(
    const u16* __restrict__ y1b, const float* __restrict__ cf, float* __restrict__ out)
{
  const size_t total4 = (size_t)B_ * C2_ * N_ / 4;
  const size_t stride = (size_t)gridDim.x * blockDim.x;
  for (size_t f = (size_t)blockIdx.x * blockDim.x + threadIdx.x; f < total4; f += stride) {
    size_t base = f * 4;
    int p = (int)((base >> 13) & (C2_ - 1));
    float a = cf[p], c = cf[C2_ + p];
    uint2 v = *(const uint2*)(y1b + base);
    float4 r;
    r.x = fmaxf(0.0f, fmaf(bf2f((u16)(v.x & 0xffff)), a, c));
    r.y = fmaxf(0.0f, fmaf(bf2f((u16)(v.x >> 16)),    a, c));
    r.z = fmaxf(0.0f, fmaf(bf2f((u16)(v.y & 0xffff)), a, c));
    r.w = fmaxf(0.0f, fmaf(bf2f((u16)(v.y >> 16)),    a, c));
    *(float4*)(out + base) = r;
  }
}

// ---------------------------------------------------------------------------
extern "C" void kernel_launch(void* const* d_in, const int* in_sizes, int n_in,
                              void* d_out, int out_size, void* d_ws, size_t ws_size,
                              hipStream_t stream)
{
  const float* xyz_sa     = (const float*)d_in[0];
  const float* xyz_now    = (const float*)d_in[1];
  const float* points_sa  = (const float*)d_in[2];
  const float* points_now = (const float*)d_in[3];
  const float* W0  = (const float*)d_in[4];
  const float* b0  = (const float*)d_in[5];
  const float* g0  = (const float*)d_in[6];
  const float* be0 = (const float*)d_in[7];
  const float* W1  = (const float*)d_in[8];
  const float* b1  = (const float*)d_in[9];
  const float* g1  = (const float*)d_in[10];
  const float* be1 = (const float*)d_in[11];

  const size_t MB = 1048576ull;
  char* base = (char*)d_ws;
  u16*   xcat  = (u16*)(base + 0);            // [B][12][N][32] bf16  48MB
  u16*   y0r   = (u16*)(base + 0);            // [B][8][N][32] bf16   32MB (xcat dead)
  float* pnT   = (float*)(base + 48 * MB);    // [B][S][256] f32      16MB (dead after knn)
  u16*   y1b   = (u16*)(base + 48 * MB);      // [B][C2][N] bf16      16MB (overlays pnT)
  u16*   y0b   = (u16*)(base + 64 * MB);      // [B][8][N][32] bf16   32MB
  u16*   W0b   = (u16*)(base + 96 * MB);      // [12][256][32] bf16
  u16*   W1b   = (u16*)(base + 96 * MB + 512 * 1024); // [8][128][32] bf16
  float* coef  = (float*)(base + 97 * MB);    // 768 f
  float* part1 = (float*)(base + 98 * MB);    // [1024][512] f32 2MB
  float* part2 = (float*)(base + 100 * MB);   // [1024][256] f32 1MB
  float* out   = (float*)d_out;

  hipLaunchKernelGGL(cvtW_kernel, dim3((C1_ * C0_ + 255) / 256), dim3(256), 0, stream,
                     W0, W0b, C1_, C0_);
  hipLaunchKernelGGL(cvtW_kernel, dim3((C2_ * C1_ + 255) / 256), dim3(256), 0, stream,
                     W1, W1b, C2_, C1_);
  hipLaunchKernelGGL(transpose_kernel, dim3(S_ / 32, D2_ / 32, B_), dim3(256), 0, stream,
                     points_now, pnT);
  hipLaunchKernelGGL(psaT_kernel, dim3(N_ / 32, D1_ / 32, B_), dim3(256), 0, stream,
                     points_sa, xcat);
  hipLaunchKernelGGL(knn_interp_kernel, dim3(N_ / 32, B_), dim3(256), 0, stream,
                     xyz_sa, xyz_now, pnT, xcat);
  hipLaunchKernelGGL(gemm1_mfma_kernel, dim3(N_ / 128, 2, B_), dim3(256), 0, stream,
                     xcat, W0b, b0, y0b, part1);
  hipLaunchKernelGGL(reduce_coef_kernel, dim3(C1_), dim3(256), 0, stream,
                     part1, 512, C1_, g0, be0, coef);
  hipLaunchKernelGGL(bn0relu_kernel, dim3(2048), dim3(256), 0, stream,
                     y0b, coef, y0r);
  hipLaunchKernelGGL(gemm2_mfma_kernel, dim3(N_ / 128, 1, B_), dim3(256), 0, stream,
                     y0r, W1b, b1, y1b, part2);
  hipLaunchKernelGGL(reduce_coef_kernel, dim3(C2_), dim3(256), 0, stream,
                     part2, 256, C2_, g1, be1, coef + 512);
  hipLaunchKernelGGL(final_kernel, dim3(2048), dim3(256), 0, stream,
                     y1b, coef + 512, out);
}

// Round 14
// 179.273 us; speedup vs baseline: 2.4266x; 1.0959x over previous
//
#include <hip/hip_runtime.h>

#define B_ 8
#define N_ 8192
#define S_ 2048
#define D1_ 128
#define D2_ 256
#define C0_ 384
#define C1_ 256
#define C2_ 128
#define BN_EPS 1e-5f

typedef unsigned long long ull;
typedef unsigned short u16;
typedef __bf16 bf16x8 __attribute__((ext_vector_type(8)));
typedef float f32x4 __attribute__((ext_vector_type(4)));
typedef short short8_ __attribute__((ext_vector_type(8)));

__device__ __forceinline__ u16 f2bf(float x) {
  unsigned int u = __float_as_uint(x);
  unsigned int r = u + 0x7fffu + ((u >> 16) & 1u);
  return (u16)(r >> 16);
}
__device__ __forceinline__ float bf2f(u16 h) {
  return __uint_as_float(((unsigned int)h) << 16);
}

// async global->LDS DMA, 16B/lane; wave-contiguous 1KB source panels.
__device__ __forceinline__ void gld16(const void* g, void* l) {
  __builtin_amdgcn_global_load_lds(
      (const __attribute__((address_space(1))) void*)g,
      (__attribute__((address_space(3))) void*)l,
      16, 0, 0);
}

// branchless sorted top-3 insert on (f32 d, i32 idx); strict < keeps earlier.
// 3 v_cmp_lt_f32 + 10 v_cndmask (vs 16 ops for the u64-key variant).
__device__ __forceinline__ void insf(float d, int i,
    float& D0, int& I0, float& D1, int& I1, float& D2, int& I2) {
  bool c2 = d < D2, c1 = d < D1, c0 = d < D0;
  D2 = c1 ? D1 : (c2 ? d : D2);  I2 = c1 ? I1 : (c2 ? i : I2);
  D1 = c0 ? D0 : (c1 ? d : D1);  I1 = c0 ? I0 : (c1 ? i : I1);
  D0 = c0 ? d : D0;              I0 = c0 ? i : I0;
}

// ---------------------------------------------------------------------------
// weights f32 [O][K] -> bf16 k-chunked [K/32][O][32]
// ---------------------------------------------------------------------------
__global__ void cvtW_kernel(const float* __restrict__ src, u16* __restrict__ dst,
                            int O, int K)
{
  int i = blockIdx.x * blockDim.x + threadIdx.x;
  if (i < O * K) {
    int o = i / K, kk = i - o * K;
    dst[(((size_t)(kk >> 5) * O + o) << 5) + (kk & 31)] = f2bf(src[i]);
  }
}

// ---------------------------------------------------------------------------
// transpose points_now [B][D2][S] -> pnT [B][S][D2]  (fp32, for knn gather)
// ---------------------------------------------------------------------------
__global__ __launch_bounds__(256) void transpose_kernel(
    const float* __restrict__ in, float* __restrict__ out)
{
  __shared__ float tile[32][33];
  const int b  = blockIdx.z;
  const int s0 = blockIdx.x * 32;
  const int d0 = blockIdx.y * 32;
  const int tx = threadIdx.x & 31, ty = threadIdx.x >> 5;

  const float* inb = in + ((size_t)b * D2_ + d0) * S_ + s0;
  #pragma unroll
  for (int r = 0; r < 4; ++r) {
    int d = r * 8 + ty;
    tile[d][tx] = inb[(size_t)d * S_ + tx];
  }
  __syncthreads();
  float* outb = out + ((size_t)b * S_ + s0) * D2_ + d0;
  #pragma unroll
  for (int r = 0; r < 4; ++r) {
    int s = r * 8 + ty;
    outb[(size_t)s * D2_ + tx] = tile[tx][s];
  }
}

// ---------------------------------------------------------------------------
// points_sa [B][D1][N] f32 -> xcat chunks 0..3  ([12][N][32] per batch, bf16)
// ---------------------------------------------------------------------------
__global__ __launch_bounds__(256) void psaT_kernel(
    const float* __restrict__ in, u16* __restrict__ xcat)
{
  __shared__ float tile[32][33];
  const int b  = blockIdx.z;
  const int n0 = blockIdx.x * 32;
  const int d0 = blockIdx.y * 32;     // chunk = d0>>5
  const int tx = threadIdx.x & 31, ty = threadIdx.x >> 5;

  const float* inb = in + ((size_t)b * D1_ + d0) * N_ + n0;
  #pragma unroll
  for (int r = 0; r < 4; ++r) {
    int d = r * 8 + ty;
    tile[d][tx] = inb[(size_t)d * N_ + tx];
  }
  __syncthreads();
  u16* outb = xcat + (((size_t)b * 12 + (d0 >> 5)) * N_ + n0) * 32;
  #pragma unroll
  for (int r = 0; r < 4; ++r) {
    int n = r * 8 + ty;
    outb[(size_t)n * 32 + tx] = f2bf(tile[tx][n]);
  }
}

// ---------------------------------------------------------------------------
// K1: 3-NN + interpolation. 32 queries/block, 2048 blocks, 8 blocks/CU.
// Scan key is d_rel = |p|^2 - 2 q.p (ordering per query invariant under
// +|q|^2; constant added back for the 3 winners only). f32 compares, so
// negatives are fine; 3 fma + 13-op insert per pair.
// ---------------------------------------------------------------------------
__global__ __launch_bounds__(256) void knn_interp_kernel(
    const float* __restrict__ xyz_sa, const float* __restrict__ xyz_now,
    const float* __restrict__ pnT, u16* __restrict__ xcat)
{
  __shared__ float4 sp[1024];
  __shared__ int   s_idx[32][3];
  __shared__ float s_w[32][3];

  const int b  = blockIdx.y;
  const int n0 = blockIdx.x * 32;

  const int qg = threadIdx.x >> 4;   // 0..15 query group (2 queries)
  const int t  = threadIdx.x & 15;   // scanner 0..15
  const int nb = n0 + qg * 2;

  const float* xq = xyz_sa + (size_t)b * 3 * N_;
  float qx[2], qy[2], qz[2], qq[2];
  #pragma unroll
  for (int w = 0; w < 2; ++w) {
    int n = nb + w;
    qx[w] = xq[n]; qy[w] = xq[N_ + n]; qz[w] = xq[2 * N_ + n];
    qq[w] = qx[w] * qx[w] + qy[w] * qy[w] + qz[w] * qz[w];
  }

  float D0[2], D1[2], D2[2];
  int   I0[2], I1[2], I2[2];
  #pragma unroll
  for (int w = 0; w < 2; ++w) {
    D0[w] = 3.4e38f; D1[w] = 3.4e38f; D2[w] = 3.4e38f;
    I0[w] = 0; I1[w] = 0; I2[w] = 0;
  }

  const float* xb = xyz_now + (size_t)b * 3 * S_;
  for (int chunk = 0; chunk < 2; ++chunk) {
    const int sbase = chunk << 10;
    for (int i = threadIdx.x; i < 1024; i += 256) {
      int sg = sbase + i;
      float px = xb[sg], py = xb[S_ + sg], pz = xb[2 * S_ + sg];
      sp[i] = make_float4(-2.f * px, -2.f * py, -2.f * pz,
                          px * px + py * py + pz * pz);
    }
    __syncthreads();

    #pragma unroll 4
    for (int it = 0; it < 64; ++it) {
      int sl = (it << 4) | t;
      float4 p = sp[sl];
      int sg = sbase + sl;
      #pragma unroll
      for (int w = 0; w < 2; ++w) {
        float d = fmaf(p.x, qx[w], fmaf(p.y, qy[w], fmaf(p.z, qz[w], p.w)));
        insf(d, sg, D0[w], I0[w], D1[w], I1[w], D2[w], I2[w]);
      }
    }
    __syncthreads();   // protect sp before next chunk's staging
  }

  // merge the 16 scanners via shuffle butterfly (stays within 16-lane group)
  #pragma unroll
  for (int m = 1; m <= 8; m <<= 1) {
    #pragma unroll
    for (int w = 0; w < 2; ++w) {
      float e0 = __shfl_xor(D0[w], m), e1 = __shfl_xor(D1[w], m), e2 = __shfl_xor(D2[w], m);
      int   j0 = __shfl_xor(I0[w], m), j1 = __shfl_xor(I1[w], m), j2 = __shfl_xor(I2[w], m);
      insf(e0, j0, D0[w], I0[w], D1[w], I1[w], D2[w], I2[w]);
      insf(e1, j1, D0[w], I0[w], D1[w], I1[w], D2[w], I2[w]);
      insf(e2, j2, D0[w], I0[w], D1[w], I1[w], D2[w], I2[w]);
    }
  }

  if (t == 0) {
    #pragma unroll
    for (int w = 0; w < 2; ++w) {
      float d0 = D0[w] + qq[w];
      float d1 = D1[w] + qq[w];
      float d2 = D2[w] + qq[w];
      float r0 = 1.0f / (d0 + 1e-8f);
      float r1 = 1.0f / (d1 + 1e-8f);
      float r2 = 1.0f / (d2 + 1e-8f);
      float rs = 1.0f / (r0 + r1 + r2);
      int qi = qg * 2 + w;
      s_idx[qi][0] = I0[w];
      s_idx[qi][1] = I1[w];
      s_idx[qi][2] = I2[w];
      s_w[qi][0] = r0 * rs; s_w[qi][1] = r1 * rs; s_w[qi][2] = r2 * rs;
    }
  }
  __syncthreads();

  // Phase 2: wave-per-query gather; lane covers chunk 4+(l>>3), 4 channels.
  const int wave = threadIdx.x >> 6;
  const int lane = threadIdx.x & 63;
  const int c8 = lane >> 3;
  const int k4 = (lane & 7) * 4;
  const float* pb = pnT + (size_t)b * S_ * D2_ + c8 * 32 + k4;
  u16* ob = xcat + (((size_t)b * 12 + 4 + c8) * N_ + n0) * 32 + k4;
  #pragma unroll 2
  for (int i = 0; i < 8; ++i) {
    const int qi = wave * 8 + i;
    const int j0 = s_idx[qi][0], j1 = s_idx[qi][1], j2 = s_idx[qi][2];
    const float w0 = s_w[qi][0], w1 = s_w[qi][1], w2 = s_w[qi][2];
    float4 f0 = *(const float4*)(pb + (size_t)j0 * D2_);
    float4 f1 = *(const float4*)(pb + (size_t)j1 * D2_);
    float4 f2 = *(const float4*)(pb + (size_t)j2 * D2_);
    float rx = w0 * f0.x + w1 * f1.x + w2 * f2.x;
    float ry = w0 * f0.y + w1 * f1.y + w2 * f2.y;
    float rz = w0 * f0.z + w1 * f1.z + w2 * f2.z;
    float rw = w0 * f0.w + w1 * f1.w + w2 * f2.w;
    unsigned int lo = (unsigned int)f2bf(rx) | ((unsigned int)f2bf(ry) << 16);
    unsigned int hi = (unsigned int)f2bf(rz) | ((unsigned int)f2bf(rw) << 16);
    *(uint2*)(ob + (size_t)qi * 32) = make_uint2(lo, hi);
  }
}

// ---------------------------------------------------------------------------
union SMg {
  struct { u16 As[2][4096]; u16 Bs[2][4096]; } p;   // [128 rows][32 k] x dbuf
  u16 stage[128][136];
};

// ---------------------------------------------------------------------------
// GEMM1: y0[b,n,o] = W0 . xcat + b0. NO atomics: per-(block,wn) partial
// sums stored to unique slots; reduced later.
// partials1: [1024 slots][512]  (cols 0..255 sum, 256..511 sumsq)
// ---------------------------------------------------------------------------
__global__ __launch_bounds__(256) void gemm1_mfma_kernel(
    const u16* __restrict__ xcat, const u16* __restrict__ W0b,
    const float* __restrict__ b0, u16* __restrict__ y0b, float* __restrict__ partials)
{
  __shared__ SMg sm;

  const int bz = blockIdx.z;
  const int n0 = blockIdx.x * 128;
  const int o0 = blockIdx.y * 128;
  const int tid = threadIdx.x;
  const int wid = tid >> 6, lane = tid & 63;
  const int wo = wid & 1, wn = wid >> 1;
  const int m = lane & 15, g = lane >> 4;

  f32x4 acc[4][4];
  #pragma unroll
  for (int i = 0; i < 4; ++i)
    #pragma unroll
    for (int j = 0; j < 4; ++j) acc[i][j] = (f32x4){0.f, 0.f, 0.f, 0.f};

  auto STAGE = [&](int buf, int c) {
    const u16* asrc = W0b  + ((size_t)c * C1_ + o0) * 32;
    const u16* bsrc = xcat + (((size_t)bz * 12 + c) * N_ + n0) * 32;
    #pragma unroll
    for (int i2 = 0; i2 < 2; ++i2) {
      const int i = wid * 2 + i2;
      gld16(asrc + i * 512 + lane * 8, &sm.p.As[buf][i * 512]);
      gld16(bsrc + i * 512 + lane * 8, &sm.p.Bs[buf][i * 512]);
    }
  };

  STAGE(0, 0);
  __syncthreads();

  for (int kt = 0; kt < 12; ++kt) {
    const int cur = kt & 1;
    if (kt < 11) STAGE(cur ^ 1, kt + 1);

    bf16x8 af[4], bfv[4];
    #pragma unroll
    for (int f = 0; f < 4; ++f)
      af[f] = __builtin_bit_cast(bf16x8,
          *(const short8_*)&sm.p.As[cur][(wo * 64 + f * 16 + m) * 32 + g * 8]);
    #pragma unroll
    for (int f = 0; f < 4; ++f)
      bfv[f] = __builtin_bit_cast(bf16x8,
          *(const short8_*)&sm.p.Bs[cur][(wn * 64 + f * 16 + m) * 32 + g * 8]);
    #pragma unroll
    for (int i = 0; i < 4; ++i)
      #pragma unroll
      for (int j = 0; j < 4; ++j)
        acc[i][j] = __builtin_amdgcn_mfma_f32_16x16x32_bf16(af[i], bfv[j], acc[i][j], 0, 0, 0);

    __syncthreads();
  }

  const int slot = (blockIdx.x * 8 + bz) * 2 + wn;   // 0..1023 unique
  float* prow = partials + (size_t)slot * 512;

  #pragma unroll
  for (int of = 0; of < 4; ++of) {
    const int ol = wo * 64 + of * 16 + g * 4;
    const int ob = o0 + ol;
    float bias[4], s1[4], s2[4];
    #pragma unroll
    for (int r = 0; r < 4; ++r) { bias[r] = b0[ob + r]; s1[r] = 0.f; s2[r] = 0.f; }
    #pragma unroll
    for (int nf = 0; nf < 4; ++nf) {
      const int nl = wn * 64 + nf * 16 + m;
      float y[4];
      #pragma unroll
      for (int r = 0; r < 4; ++r) {
        y[r] = acc[of][nf][r] + bias[r];
        s1[r] += y[r]; s2[r] += y[r] * y[r];
      }
      unsigned int lo = (unsigned int)f2bf(y[0]) | ((unsigned int)f2bf(y[1]) << 16);
      unsigned int hi = (unsigned int)f2bf(y[2]) | ((unsigned int)f2bf(y[3]) << 16);
      *(uint2*)&sm.stage[nl][ol] = make_uint2(lo, hi);
    }
    #pragma unroll
    for (int mk = 1; mk < 16; mk <<= 1)
      #pragma unroll
      for (int r = 0; r < 4; ++r) {
        s1[r] += __shfl_xor(s1[r], mk);
        s2[r] += __shfl_xor(s2[r], mk);
      }
    if (m == 0) {
      *(float4*)(prow + ob)        = make_float4(s1[0], s1[1], s1[2], s1[3]);
      *(float4*)(prow + 256 + ob)  = make_float4(s2[0], s2[1], s2[2], s2[3]);
    }
  }
  __syncthreads();
  {
    const int rrow = tid >> 4;
    const int col  = (tid & 15) * 8;
    const int c    = (o0 + col) >> 5;
    const int ko   = (o0 + col) & 31;
    u16* dst = y0b + (((size_t)bz * 8 + c) * N_ + n0) * 32 + ko;
    #pragma unroll
    for (int pass = 0; pass < 8; ++pass) {
      const int r = pass * 16 + rrow;
      *(uint4*)(dst + (size_t)r * 32) = *(const uint4*)&sm.stage[r][col];
    }
  }
}

// ---------------------------------------------------------------------------
// reduce partials -> BN coef. grid = C blocks; partial row width R floats.
// ---------------------------------------------------------------------------
__global__ __launch_bounds__(256) void reduce_coef_kernel(
    const float* __restrict__ partials, int R, int C,
    const float* __restrict__ g, const float* __restrict__ be,
    float* __restrict__ coef)
{
  const int ch = blockIdx.x;
  const int tid = threadIdx.x;
  float s = 0.f, q = 0.f;
  #pragma unroll
  for (int k = 0; k < 4; ++k) {
    const float* row = partials + (size_t)(tid + k * 256) * R;
    s += row[ch];
    q += row[C + ch];
  }
  #pragma unroll
  for (int mk = 1; mk < 64; mk <<= 1) { s += __shfl_xor(s, mk); q += __shfl_xor(q, mk); }
  __shared__ float ls[4], lq[4];
  const int wid = tid >> 6;
  if ((tid & 63) == 0) { ls[wid] = s; lq[wid] = q; }
  __syncthreads();
  if (tid == 0) {
    s = ls[0] + ls[1] + ls[2] + ls[3];
    q = lq[0] + lq[1] + lq[2] + lq[3];
    const float invM = 1.0f / 65536.0f;   // B*N
    float mean = s * invM;
    float var  = q * invM - mean * mean;
    float a = g[ch] / sqrtf(var + BN_EPS);
    float c = be[ch] - mean * a;
    coef[ch] = a;
    coef[C + ch] = c;
  }
}

// ---------------------------------------------------------------------------
// BN0 + ReLU elementwise on k-chunked y0 [B][8][N][32] (bf16 -> bf16)
// ---------------------------------------------------------------------------
__global__ __launch_bounds__(256) void bn0relu_kernel(
    const u16* __restrict__ y0b, const float* __restrict__ coef, u16* __restrict__ y0r)
{
  __shared__ float cfa[C1_], cfc[C1_];
  cfa[threadIdx.x] = coef[threadIdx.x];
  cfc[threadIdx.x] = coef[C1_ + threadIdx.x];
  __syncthreads();
  const size_t total8 = (size_t)B_ * N_ * C1_ / 8;
  const size_t stride = (size_t)gridDim.x * blockDim.x;
  for (size_t i = (size_t)blockIdx.x * blockDim.x + threadIdx.x; i < total8; i += stride) {
    uint4 v = *(const uint4*)(y0b + i * 8);
    const int ch = (int)(((i >> 15) & 7) * 32 + ((i * 8) & 31));  // chunk*32 + k
    float f0 = fmaxf(0.f, fmaf(bf2f((u16)(v.x & 0xffff)), cfa[ch + 0], cfc[ch + 0]));
    float f1 = fmaxf(0.f, fmaf(bf2f((u16)(v.x >> 16)),    cfa[ch + 1], cfc[ch + 1]));
    float f2 = fmaxf(0.f, fmaf(bf2f((u16)(v.y & 0xffff)), cfa[ch + 2], cfc[ch + 2]));
    float f3 = fmaxf(0.f, fmaf(bf2f((u16)(v.y >> 16)),    cfa[ch + 3], cfc[ch + 3]));
    float f4 = fmaxf(0.f, fmaf(bf2f((u16)(v.z & 0xffff)), cfa[ch + 4], cfc[ch + 4]));
    float f5 = fmaxf(0.f, fmaf(bf2f((u16)(v.z >> 16)),    cfa[ch + 5], cfc[ch + 5]));
    float f6 = fmaxf(0.f, fmaf(bf2f((u16)(v.w & 0xffff)), cfa[ch + 6], cfc[ch + 6]));
    float f7 = fmaxf(0.f, fmaf(bf2f((u16)(v.w >> 16)),    cfa[ch + 7], cfc[ch + 7]));
    uint4 o;
    o.x = (unsigned int)f2bf(f0) | ((unsigned int)f2bf(f1) << 16);
    o.y = (unsigned int)f2bf(f2) | ((unsigned int)f2bf(f3) << 16);
    o.z = (unsigned int)f2bf(f4) | ((unsigned int)f2bf(f5) << 16);
    o.w = (unsigned int)f2bf(f6) | ((unsigned int)f2bf(f7) << 16);
    *(uint4*)(y0r + i * 8) = o;
  }
}

// ---------------------------------------------------------------------------
// GEMM2: y1b[b,p,n] = W1 . y0r + b1. partials2: [1024 slots][256].
// ---------------------------------------------------------------------------
__global__ __launch_bounds__(256) void gemm2_mfma_kernel(
    const u16* __restrict__ y0r, const u16* __restrict__ W1b,
    const float* __restrict__ b1, u16* __restrict__ y1b, float* __restrict__ partials)
{
  __shared__ SMg sm;

  const int bz = blockIdx.z;
  const int n0 = blockIdx.x * 128;
  const int tid = threadIdx.x;
  const int wid = tid >> 6, lane = tid & 63;
  const int wo = wid & 1, wn = wid >> 1;
  const int m = lane & 15, g = lane >> 4;

  f32x4 acc[4][4];
  #pragma unroll
  for (int i = 0; i < 4; ++i)
    #pragma unroll
    for (int j = 0; j < 4; ++j) acc[i][j] = (f32x4){0.f, 0.f, 0.f, 0.f};

  auto STAGE = [&](int buf, int c) {
    const u16* asrc = W1b + ((size_t)c * C2_) * 32;
    const u16* bsrc = y0r + (((size_t)bz * 8 + c) * N_ + n0) * 32;
    #pragma unroll
    for (int i2 = 0; i2 < 2; ++i2) {
      const int i = wid * 2 + i2;
      gld16(asrc + i * 512 + lane * 8, &sm.p.As[buf][i * 512]);
      gld16(bsrc + i * 512 + lane * 8, &sm.p.Bs[buf][i * 512]);
    }
  };

  STAGE(0, 0);
  __syncthreads();

  for (int kt = 0; kt < 8; ++kt) {
    const int cur = kt & 1;
    if (kt < 7) STAGE(cur ^ 1, kt + 1);

    bf16x8 af[4], bfv[4];
    #pragma unroll
    for (int f = 0; f < 4; ++f)
      af[f] = __builtin_bit_cast(bf16x8,
          *(const short8_*)&sm.p.As[cur][(wo * 64 + f * 16 + m) * 32 + g * 8]);
    #pragma unroll
    for (int f = 0; f < 4; ++f)
      bfv[f] = __builtin_bit_cast(bf16x8,
          *(const short8_*)&sm.p.Bs[cur][(wn * 64 + f * 16 + m) * 32 + g * 8]);
    #pragma unroll
    for (int i = 0; i < 4; ++i)
      #pragma unroll
      for (int j = 0; j < 4; ++j)
        acc[i][j] = __builtin_amdgcn_mfma_f32_16x16x32_bf16(af[i], bfv[j], acc[i][j], 0, 0, 0);

    __syncthreads();
  }

  const int slot = (blockIdx.x * 8 + bz) * 2 + wn;   // 0..1023 unique
  float* prow = partials + (size_t)slot * 256;

  #pragma unroll
  for (int of = 0; of < 4; ++of) {
    const int pb = wo * 64 + of * 16 + g * 4;
    float bias[4], s1[4], s2[4];
    #pragma unroll
    for (int r = 0; r < 4; ++r) { bias[r] = b1[pb + r]; s1[r] = 0.f; s2[r] = 0.f; }
    #pragma unroll
    for (int nf = 0; nf < 4; ++nf) {
      const int nl = wn * 64 + nf * 16 + m;
      #pragma unroll
      for (int r = 0; r < 4; ++r) {
        float y = acc[of][nf][r] + bias[r];
        s1[r] += y; s2[r] += y * y;
        sm.stage[pb + r][nl] = f2bf(y);
      }
    }
    #pragma unroll
    for (int mk = 1; mk < 16; mk <<= 1)
      #pragma unroll
      for (int r = 0; r < 4; ++r) {
        s1[r] += __shfl_xor(s1[r], mk);
        s2[r] += __shfl_xor(s2[r], mk);
      }
    if (m == 0) {
      *(float4*)(prow + pb)        = make_float4(s1[0], s1[1], s1[2], s1[3]);
      *(float4*)(prow + 128 + pb)  = make_float4(s2[0], s2[1], s2[2], s2[3]);
    }
  }
  __syncthreads();
  {
    #pragma unroll
    for (int pass = 0; pass < 8; ++pass) {
      const int idx = pass * 256 + tid;
      const int p = idx >> 4;
      const int c8 = (idx & 15) * 8;
      uint4 v = *(const uint4*)&sm.stage[p][c8];
      *(uint4*)(y1b + ((size_t)bz * C2_ + p) * N_ + n0 + c8) = v;
    }
  }
}

// ---------------------------------------------------------------------------
// final: BN1 + ReLU elementwise, bf16 in -> fp32 out  (y1b is [B][C2][N])
// ---------------------------------------------------------------------------
__global__ __launch_bounds__(256) void final_kernel(
    const u16* __restrict__ y1b, const float* __restrict__ cf, float* __restrict__ out)
{
  const size_t total4 = (size_t)B_ * C2_ * N_ / 4;
  const size_t stride = (size_t)gridDim.x * blockDim.x;
  for (size_t f = (size_t)blockIdx.x * blockDim.x + threadIdx.x; f < total4; f += stride) {
    size_t base = f * 4;
    int p = (int)((base >> 13) & (C2_ - 1));
    float a = cf[p], c = cf[C2_ + p];
    uint2 v = *(const uint2*)(y1b + base);
    float4 r;
    r.x = fmaxf(0.0f, fmaf(bf2f((u16)(v.x & 0xffff)), a, c));
    r.y = fmaxf(0.0f, fmaf(bf2f((u16)(v.x >> 16)),    a, c));
    r.z = fmaxf(0.0f, fmaf(bf2f((u16)(v.y & 0xffff)), a, c));
    r.w = fmaxf(0.0f, fmaf(bf2f((u16)(v.y >> 16)),    a, c));
    *(float4*)(out + base) = r;
  }
}

// ---------------------------------------------------------------------------
extern "C" void kernel_launch(void* const* d_in, const int* in_sizes, int n_in,
                              void* d_out, int out_size, void* d_ws, size_t ws_size,
                              hipStream_t stream)
{
  const float* xyz_sa     = (const float*)d_in[0];
  const float* xyz_now    = (const float*)d_in[1];
  const float* points_sa  = (const float*)d_in[2];
  const float* points_now = (const float*)d_in[3];
  const float* W0  = (const float*)d_in[4];
  const float* b0  = (const float*)d_in[5];
  const float* g0  = (const float*)d_in[6];
  const float* be0 = (const float*)d_in[7];
  const float* W1  = (const float*)d_in[8];
  const float* b1  = (const float*)d_in[9];
  const float* g1  = (const float*)d_in[10];
  const float* be1 = (const float*)d_in[11];

  const size_t MB = 1048576ull;
  char* base = (char*)d_ws;
  u16*   xcat  = (u16*)(base + 0);            // [B][12][N][32] bf16  48MB
  u16*   y0r   = (u16*)(base + 0);            // [B][8][N][32] bf16   32MB (xcat dead)
  float* pnT   = (float*)(base + 48 * MB);    // [B][S][256] f32      16MB (dead after knn)
  u16*   y1b   = (u16*)(base + 48 * MB);      // [B][C2][N] bf16      16MB (overlays pnT)
  u16*   y0b   = (u16*)(base + 64 * MB);      // [B][8][N][32] bf16   32MB
  u16*   W0b   = (u16*)(base + 96 * MB);      // [12][256][32] bf16
  u16*   W1b   = (u16*)(base + 96 * MB + 512 * 1024); // [8][128][32] bf16
  float* coef  = (float*)(base + 97 * MB);    // 768 f
  float* part1 = (float*)(base + 98 * MB);    // [1024][512] f32 2MB
  float* part2 = (float*)(base + 100 * MB);   // [1024][256] f32 1MB
  float* out   = (float*)d_out;

  hipLaunchKernelGGL(cvtW_kernel, dim3((C1_ * C0_ + 255) / 256), dim3(256), 0, stream,
                     W0, W0b, C1_, C0_);
  hipLaunchKernelGGL(cvtW_kernel, dim3((C2_ * C1_ + 255) / 256), dim3(256), 0, stream,
                     W1, W1b, C2_, C1_);
  hipLaunchKernelGGL(transpose_kernel, dim3(S_ / 32, D2_ / 32, B_), dim3(256), 0, stream,
                     points_now, pnT);
  hipLaunchKernelGGL(psaT_kernel, dim3(N_ / 32, D1_ / 32, B_), dim3(256), 0, stream,
                     points_sa, xcat);
  hipLaunchKernelGGL(knn_interp_kernel, dim3(N_ / 32, B_), dim3(256), 0, stream,
                     xyz_sa, xyz_now, pnT, xcat);
  hipLaunchKernelGGL(gemm1_mfma_kernel, dim3(N_ / 128, 2, B_), dim3(256), 0, stream,
                     xcat, W0b, b0, y0b, part1);
  hipLaunchKernelGGL(reduce_coef_kernel, dim3(C1_), dim3(256), 0, stream,
                     part1, 512, C1_, g0, be0, coef);
  hipLaunchKernelGGL(bn0relu_kernel, dim3(2048), dim3(256), 0, stream,
                     y0b, coef, y0r);
  hipLaunchKernelGGL(gemm2_mfma_kernel, dim3(N_ / 128, 1, B_), dim3(256), 0, stream,
                     y0r, W1b, b1, y1b, part2);
  hipLaunchKernelGGL(reduce_coef_kernel, dim3(C2_), dim3(256), 0, stream,
                     part2, 256, C2_, g1, be1, coef + 512);
  hipLaunchKernelGGL(final_kernel, dim3(2048), dim3(256), 0, stream,
                     y1b, coef + 512, out);
}

// Round 15
// 178.418 us; speedup vs baseline: 2.4382x; 1.0048x over previous
//
#include <hip/hip_runtime.h>

#define B_ 8
#define N_ 8192
#define S_ 2048
#define D1_ 128
#define D2_ 256
#define C0_ 384
#define C1_ 256
#define C2_ 128
#define BN_EPS 1e-5f

typedef unsigned long long ull;
typedef unsigned short u16;
typedef __bf16 bf16x8 __attribute__((ext_vector_type(8)));
typedef float f32x4 __attribute__((ext_vector_type(4)));
typedef short short8_ __attribute__((ext_vector_type(8)));

__device__ __forceinline__ u16 f2bf(float x) {
  unsigned int u = __float_as_uint(x);
  unsigned int r = u + 0x7fffu + ((u >> 16) & 1u);
  return (u16)(r >> 16);
}
__device__ __forceinline__ float bf2f(u16 h) {
  return __uint_as_float(((unsigned int)h) << 16);
}

// async global->LDS DMA, 16B/lane; wave-contiguous 1KB source panels.
__device__ __forceinline__ void gld16(const void* g, void* l) {
  __builtin_amdgcn_global_load_lds(
      (const __attribute__((address_space(1))) void*)g,
      (__attribute__((address_space(3))) void*)l,
      16, 0, 0);
}

// branchless sorted top-3 insert on (f32 d, i32 idx); strict < keeps earlier.
__device__ __forceinline__ void insf(float d, int i,
    float& D0, int& I0, float& D1, int& I1, float& D2, int& I2) {
  bool c2 = d < D2, c1 = d < D1, c0 = d < D0;
  D2 = c1 ? D1 : (c2 ? d : D2);  I2 = c1 ? I1 : (c2 ? i : I2);
  D1 = c0 ? D0 : (c1 ? d : D1);  I1 = c0 ? I0 : (c1 ? i : I1);
  D0 = c0 ? d : D0;              I0 = c0 ? i : I0;
}

// values-only sorted top-3 insert: 3 ops (2x med3 + min).
// D2' = 3rd smallest of {D0,D1,D2,d} = med3(D1,D2,d); D1' = med3(D0,D1,d);
// D0' = min(D0,d). (Uses OLD D1/D0 — order matters.)
__device__ __forceinline__ void insv(float d, float& D0, float& D1, float& D2) {
  D2 = __builtin_amdgcn_fmed3f(D1, D2, d);
  D1 = __builtin_amdgcn_fmed3f(D0, D1, d);
  D0 = fminf(D0, d);
}

// ---------------------------------------------------------------------------
// weights f32 [O][K] -> bf16 k-chunked [K/32][O][32]
// ---------------------------------------------------------------------------
__global__ void cvtW_kernel(const float* __restrict__ src, u16* __restrict__ dst,
                            int O, int K)
{
  int i = blockIdx.x * blockDim.x + threadIdx.x;
  if (i < O * K) {
    int o = i / K, kk = i - o * K;
    dst[(((size_t)(kk >> 5) * O + o) << 5) + (kk & 31)] = f2bf(src[i]);
  }
}

// ---------------------------------------------------------------------------
// transpose points_now [B][D2][S] -> pnT [B][S][D2]  (fp32, for knn gather)
// ---------------------------------------------------------------------------
__global__ __launch_bounds__(256) void transpose_kernel(
    const float* __restrict__ in, float* __restrict__ out)
{
  __shared__ float tile[32][33];
  const int b  = blockIdx.z;
  const int s0 = blockIdx.x * 32;
  const int d0 = blockIdx.y * 32;
  const int tx = threadIdx.x & 31, ty = threadIdx.x >> 5;

  const float* inb = in + ((size_t)b * D2_ + d0) * S_ + s0;
  #pragma unroll
  for (int r = 0; r < 4; ++r) {
    int d = r * 8 + ty;
    tile[d][tx] = inb[(size_t)d * S_ + tx];
  }
  __syncthreads();
  float* outb = out + ((size_t)b * S_ + s0) * D2_ + d0;
  #pragma unroll
  for (int r = 0; r < 4; ++r) {
    int s = r * 8 + ty;
    outb[(size_t)s * D2_ + tx] = tile[tx][s];
  }
}

// ---------------------------------------------------------------------------
// points_sa [B][D1][N] f32 -> xcat chunks 0..3  ([12][N][32] per batch, bf16)
// ---------------------------------------------------------------------------
__global__ __launch_bounds__(256) void psaT_kernel(
    const float* __restrict__ in, u16* __restrict__ xcat)
{
  __shared__ float tile[32][33];
  const int b  = blockIdx.z;
  const int n0 = blockIdx.x * 32;
  const int d0 = blockIdx.y * 32;     // chunk = d0>>5
  const int tx = threadIdx.x & 31, ty = threadIdx.x >> 5;

  const float* inb = in + ((size_t)b * D1_ + d0) * N_ + n0;
  #pragma unroll
  for (int r = 0; r < 4; ++r) {
    int d = r * 8 + ty;
    tile[d][tx] = inb[(size_t)d * N_ + tx];
  }
  __syncthreads();
  u16* outb = xcat + (((size_t)b * 12 + (d0 >> 5)) * N_ + n0) * 32;
  #pragma unroll
  for (int r = 0; r < 4; ++r) {
    int n = r * 8 + ty;
    outb[(size_t)n * 32 + tx] = f2bf(tile[tx][n]);
  }
}

// ---------------------------------------------------------------------------
// K1: 3-NN + interpolation, TWO-PASS. 32 queries/block, 2048 blocks.
// Pass 1: values-only top-3 via med3 (6 ops/pair) -> exact 3rd-smallest thr.
// Pass 2: re-scan (bit-identical d), rare (d<=thr) hits run (d,idx) insert
// under exec mask. sp re-staged per pass from L2 (17KB LDS, 8 blocks/CU).
// ---------------------------------------------------------------------------
__global__ __launch_bounds__(256) void knn_interp_kernel(
    const float* __restrict__ xyz_sa, const float* __restrict__ xyz_now,
    const float* __restrict__ pnT, u16* __restrict__ xcat)
{
  __shared__ float4 sp[1024];
  __shared__ int   s_idx[32][3];
  __shared__ float s_w[32][3];

  const int b  = blockIdx.y;
  const int n0 = blockIdx.x * 32;

  const int qg = threadIdx.x >> 4;   // 0..15 query group (2 queries)
  const int t  = threadIdx.x & 15;   // scanner 0..15
  const int nb = n0 + qg * 2;

  const float* xq = xyz_sa + (size_t)b * 3 * N_;
  float qx[2], qy[2], qz[2];
  #pragma unroll
  for (int w = 0; w < 2; ++w) {
    int n = nb + w;
    qx[w] = xq[n]; qy[w] = xq[N_ + n]; qz[w] = xq[2 * N_ + n];
  }

  const float* xb = xyz_now + (size_t)b * 3 * S_;

  // ---------------- PASS 1: values-only ----------------
  float D0[2], D1[2], D2[2];
  #pragma unroll
  for (int w = 0; w < 2; ++w) { D0[w] = 3.4e38f; D1[w] = 3.4e38f; D2[w] = 3.4e38f; }

  for (int chunk = 0; chunk < 2; ++chunk) {
    const int sbase = chunk << 10;
    for (int i = threadIdx.x; i < 1024; i += 256) {
      int sg = sbase + i;
      float px = xb[sg], py = xb[S_ + sg], pz = xb[2 * S_ + sg];
      sp[i] = make_float4(-2.f * px, -2.f * py, -2.f * pz,
                          px * px + py * py + pz * pz);
    }
    __syncthreads();

    #pragma unroll 4
    for (int it = 0; it < 64; ++it) {
      int sl = (it << 4) | t;
      float4 p = sp[sl];
      #pragma unroll
      for (int w = 0; w < 2; ++w) {
        float d = fmaf(p.x, qx[w], fmaf(p.y, qy[w], fmaf(p.z, qz[w], p.w)));
        insv(d, D0[w], D1[w], D2[w]);
      }
    }
    __syncthreads();
  }

  // values-only butterfly merge (all 16 lanes converge to the same triple)
  #pragma unroll
  for (int m = 1; m <= 8; m <<= 1) {
    #pragma unroll
    for (int w = 0; w < 2; ++w) {
      float e0 = __shfl_xor(D0[w], m), e1 = __shfl_xor(D1[w], m), e2 = __shfl_xor(D2[w], m);
      insv(e0, D0[w], D1[w], D2[w]);
      insv(e1, D0[w], D1[w], D2[w]);
      insv(e2, D0[w], D1[w], D2[w]);
    }
  }
  const float thr0 = D2[0], thr1 = D2[1];   // exact global 3rd-smallest

  // ---------------- PASS 2: (d,idx) for d <= thr ----------------
  float bD0[2], bD1[2], bD2[2];
  int   bI0[2], bI1[2], bI2[2];
  #pragma unroll
  for (int w = 0; w < 2; ++w) {
    bD0[w] = 3.4e38f; bD1[w] = 3.4e38f; bD2[w] = 3.4e38f;
    bI0[w] = 0; bI1[w] = 0; bI2[w] = 0;
  }

  for (int chunk = 0; chunk < 2; ++chunk) {
    const int sbase = chunk << 10;
    for (int i = threadIdx.x; i < 1024; i += 256) {
      int sg = sbase + i;
      float px = xb[sg], py = xb[S_ + sg], pz = xb[2 * S_ + sg];
      sp[i] = make_float4(-2.f * px, -2.f * py, -2.f * pz,
                          px * px + py * py + pz * pz);
    }
    __syncthreads();

    #pragma unroll 2
    for (int it = 0; it < 64; ++it) {
      int sl = (it << 4) | t;
      float4 p = sp[sl];
      int sg = sbase + sl;
      float da = fmaf(p.x, qx[0], fmaf(p.y, qy[0], fmaf(p.z, qz[0], p.w)));
      float db = fmaf(p.x, qx[1], fmaf(p.y, qy[1], fmaf(p.z, qz[1], p.w)));
      bool h0 = da <= thr0;
      bool h1 = db <= thr1;
      if (h0 | h1) {          // rare (~3 hits / 128 per query)
        if (h0) insf(da, sg, bD0[0], bI0[0], bD1[0], bI1[0], bD2[0], bI2[0]);
        if (h1) insf(db, sg, bD0[1], bI0[1], bD1[1], bI1[1], bD2[1], bI2[1]);
      }
    }
    __syncthreads();
  }

  // (d,idx) butterfly merge across scanners
  #pragma unroll
  for (int m = 1; m <= 8; m <<= 1) {
    #pragma unroll
    for (int w = 0; w < 2; ++w) {
      float e0 = __shfl_xor(bD0[w], m), e1 = __shfl_xor(bD1[w], m), e2 = __shfl_xor(bD2[w], m);
      int   j0 = __shfl_xor(bI0[w], m), j1 = __shfl_xor(bI1[w], m), j2 = __shfl_xor(bI2[w], m);
      insf(e0, j0, bD0[w], bI0[w], bD1[w], bI1[w], bD2[w], bI2[w]);
      insf(e1, j1, bD0[w], bI0[w], bD1[w], bI1[w], bD2[w], bI2[w]);
      insf(e2, j2, bD0[w], bI0[w], bD1[w], bI1[w], bD2[w], bI2[w]);
    }
  }

  if (t == 0) {
    #pragma unroll
    for (int w = 0; w < 2; ++w) {
      float qq = qx[w] * qx[w] + qy[w] * qy[w] + qz[w] * qz[w];
      float d0 = bD0[w] + qq;
      float d1 = bD1[w] + qq;
      float d2 = bD2[w] + qq;
      float r0 = 1.0f / (d0 + 1e-8f);
      float r1 = 1.0f / (d1 + 1e-8f);
      float r2 = 1.0f / (d2 + 1e-8f);
      float rs = 1.0f / (r0 + r1 + r2);
      int qi = qg * 2 + w;
      s_idx[qi][0] = bI0[w];
      s_idx[qi][1] = bI1[w];
      s_idx[qi][2] = bI2[w];
      s_w[qi][0] = r0 * rs; s_w[qi][1] = r1 * rs; s_w[qi][2] = r2 * rs;
    }
  }
  __syncthreads();

  // Phase 2: wave-per-query gather; lane covers chunk 4+(l>>3), 4 channels.
  const int wave = threadIdx.x >> 6;
  const int lane = threadIdx.x & 63;
  const int c8 = lane >> 3;
  const int k4 = (lane & 7) * 4;
  const float* pb = pnT + (size_t)b * S_ * D2_ + c8 * 32 + k4;
  u16* ob = xcat + (((size_t)b * 12 + 4 + c8) * N_ + n0) * 32 + k4;
  #pragma unroll 2
  for (int i = 0; i < 8; ++i) {
    const int qi = wave * 8 + i;
    const int j0 = s_idx[qi][0], j1 = s_idx[qi][1], j2 = s_idx[qi][2];
    const float w0 = s_w[qi][0], w1 = s_w[qi][1], w2 = s_w[qi][2];
    float4 f0 = *(const float4*)(pb + (size_t)j0 * D2_);
    float4 f1 = *(const float4*)(pb + (size_t)j1 * D2_);
    float4 f2 = *(const float4*)(pb + (size_t)j2 * D2_);
    float rx = w0 * f0.x + w1 * f1.x + w2 * f2.x;
    float ry = w0 * f0.y + w1 * f1.y + w2 * f2.y;
    float rz = w0 * f0.z + w1 * f1.z + w2 * f2.z;
    float rw = w0 * f0.w + w1 * f1.w + w2 * f2.w;
    unsigned int lo = (unsigned int)f2bf(rx) | ((unsigned int)f2bf(ry) << 16);
    unsigned int hi = (unsigned int)f2bf(rz) | ((unsigned int)f2bf(rw) << 16);
    *(uint2*)(ob + (size_t)qi * 32) = make_uint2(lo, hi);
  }
}

// ---------------------------------------------------------------------------
union SMg {
  struct { u16 As[2][4096]; u16 Bs[2][4096]; } p;   // [128 rows][32 k] x dbuf
  u16 stage[128][136];
};

// ---------------------------------------------------------------------------
// GEMM1: y0[b,n,o] = W0 . xcat + b0. NO atomics: per-(block,wn) partial
// sums stored to unique slots; reduced later.
// partials1: [1024 slots][512]  (cols 0..255 sum, 256..511 sumsq)
// ---------------------------------------------------------------------------
__global__ __launch_bounds__(256) void gemm1_mfma_kernel(
    const u16* __restrict__ xcat, const u16* __restrict__ W0b,
    const float* __restrict__ b0, u16* __restrict__ y0b, float* __restrict__ partials)
{
  __shared__ SMg sm;

  const int bz = blockIdx.z;
  const int n0 = blockIdx.x * 128;
  const int o0 = blockIdx.y * 128;
  const int tid = threadIdx.x;
  const int wid = tid >> 6, lane = tid & 63;
  const int wo = wid & 1, wn = wid >> 1;
  const int m = lane & 15, g = lane >> 4;

  f32x4 acc[4][4];
  #pragma unroll
  for (int i = 0; i < 4; ++i)
    #pragma unroll
    for (int j = 0; j < 4; ++j) acc[i][j] = (f32x4){0.f, 0.f, 0.f, 0.f};

  auto STAGE = [&](int buf, int c) {
    const u16* asrc = W0b  + ((size_t)c * C1_ + o0) * 32;
    const u16* bsrc = xcat + (((size_t)bz * 12 + c) * N_ + n0) * 32;
    #pragma unroll
    for (int i2 = 0; i2 < 2; ++i2) {
      const int i = wid * 2 + i2;
      gld16(asrc + i * 512 + lane * 8, &sm.p.As[buf][i * 512]);
      gld16(bsrc + i * 512 + lane * 8, &sm.p.Bs[buf][i * 512]);
    }
  };

  STAGE(0, 0);
  __syncthreads();

  for (int kt = 0; kt < 12; ++kt) {
    const int cur = kt & 1;
    if (kt < 11) STAGE(cur ^ 1, kt + 1);

    bf16x8 af[4], bfv[4];
    #pragma unroll
    for (int f = 0; f < 4; ++f)
      af[f] = __builtin_bit_cast(bf16x8,
          *(const short8_*)&sm.p.As[cur][(wo * 64 + f * 16 + m) * 32 + g * 8]);
    #pragma unroll
    for (int f = 0; f < 4; ++f)
      bfv[f] = __builtin_bit_cast(bf16x8,
          *(const short8_*)&sm.p.Bs[cur][(wn * 64 + f * 16 + m) * 32 + g * 8]);
    #pragma unroll
    for (int i = 0; i < 4; ++i)
      #pragma unroll
      for (int j = 0; j < 4; ++j)
        acc[i][j] = __builtin_amdgcn_mfma_f32_16x16x32_bf16(af[i], bfv[j], acc[i][j], 0, 0, 0);

    __syncthreads();
  }

  const int slot = (blockIdx.x * 8 + bz) * 2 + wn;   // 0..1023 unique
  float* prow = partials + (size_t)slot * 512;

  #pragma unroll
  for (int of = 0; of < 4; ++of) {
    const int ol = wo * 64 + of * 16 + g * 4;
    const int ob = o0 + ol;
    float bias[4], s1[4], s2[4];
    #pragma unroll
    for (int r = 0; r < 4; ++r) { bias[r] = b0[ob + r]; s1[r] = 0.f; s2[r] = 0.f; }
    #pragma unroll
    for (int nf = 0; nf < 4; ++nf) {
      const int nl = wn * 64 + nf * 16 + m;
      float y[4];
      #pragma unroll
      for (int r = 0; r < 4; ++r) {
        y[r] = acc[of][nf][r] + bias[r];
        s1[r] += y[r]; s2[r] += y[r] * y[r];
      }
      unsigned int lo = (unsigned int)f2bf(y[0]) | ((unsigned int)f2bf(y[1]) << 16);
      unsigned int hi = (unsigned int)f2bf(y[2]) | ((unsigned int)f2bf(y[3]) << 16);
      *(uint2*)&sm.stage[nl][ol] = make_uint2(lo, hi);
    }
    #pragma unroll
    for (int mk = 1; mk < 16; mk <<= 1)
      #pragma unroll
      for (int r = 0; r < 4; ++r) {
        s1[r] += __shfl_xor(s1[r], mk);
        s2[r] += __shfl_xor(s2[r], mk);
      }
    if (m == 0) {
      *(float4*)(prow + ob)        = make_float4(s1[0], s1[1], s1[2], s1[3]);
      *(float4*)(prow + 256 + ob)  = make_float4(s2[0], s2[1], s2[2], s2[3]);
    }
  }
  __syncthreads();
  {
    const int rrow = tid >> 4;
    const int col  = (tid & 15) * 8;
    const int c    = (o0 + col) >> 5;
    const int ko   = (o0 + col) & 31;
    u16* dst = y0b + (((size_t)bz * 8 + c) * N_ + n0) * 32 + ko;
    #pragma unroll
    for (int pass = 0; pass < 8; ++pass) {
      const int r = pass * 16 + rrow;
      *(uint4*)(dst + (size_t)r * 32) = *(const uint4*)&sm.stage[r][col];
    }
  }
}

// ---------------------------------------------------------------------------
// reduce partials -> BN coef. grid = C blocks; partial row width R floats.
// ---------------------------------------------------------------------------
__global__ __launch_bounds__(256) void reduce_coef_kernel(
    const float* __restrict__ partials, int R, int C,
    const float* __restrict__ g, const float* __restrict__ be,
    float* __restrict__ coef)
{
  const int ch = blockIdx.x;
  const int tid = threadIdx.x;
  float s = 0.f, q = 0.f;
  #pragma unroll
  for (int k = 0; k < 4; ++k) {
    const float* row = partials + (size_t)(tid + k * 256) * R;
    s += row[ch];
    q += row[C + ch];
  }
  #pragma unroll
  for (int mk = 1; mk < 64; mk <<= 1) { s += __shfl_xor(s, mk); q += __shfl_xor(q, mk); }
  __shared__ float ls[4], lq[4];
  const int wid = tid >> 6;
  if ((tid & 63) == 0) { ls[wid] = s; lq[wid] = q; }
  __syncthreads();
  if (tid == 0) {
    s = ls[0] + ls[1] + ls[2] + ls[3];
    q = lq[0] + lq[1] + lq[2] + lq[3];
    const float invM = 1.0f / 65536.0f;   // B*N
    float mean = s * invM;
    float var  = q * invM - mean * mean;
    float a = g[ch] / sqrtf(var + BN_EPS);
    float c = be[ch] - mean * a;
    coef[ch] = a;
    coef[C + ch] = c;
  }
}

// ---------------------------------------------------------------------------
// BN0 + ReLU elementwise on k-chunked y0 [B][8][N][32] (bf16 -> bf16)
// ---------------------------------------------------------------------------
__global__ __launch_bounds__(256) void bn0relu_kernel(
    const u16* __restrict__ y0b, const float* __restrict__ coef, u16* __restrict__ y0r)
{
  __shared__ float cfa[C1_], cfc[C1_];
  cfa[threadIdx.x] = coef[threadIdx.x];
  cfc[threadIdx.x] = coef[C1_ + threadIdx.x];
  __syncthreads();
  const size_t total8 = (size_t)B_ * N_ * C1_ / 8;
  const size_t stride = (size_t)gridDim.x * blockDim.x;
  for (size_t i = (size_t)blockIdx.x * blockDim.x + threadIdx.x; i < total8; i += stride) {
    uint4 v = *(const uint4*)(y0b + i * 8);
    const int ch = (int)(((i >> 15) & 7) * 32 + ((i * 8) & 31));  // chunk*32 + k
    float f0 = fmaxf(0.f, fmaf(bf2f((u16)(v.x & 0xffff)), cfa[ch + 0], cfc[ch + 0]));
    float f1 = fmaxf(0.f, fmaf(bf2f((u16)(v.x >> 16)),    cfa[ch + 1], cfc[ch + 1]));
    float f2 = fmaxf(0.f, fmaf(bf2f((u16)(v.y & 0xffff)), cfa[ch + 2], cfc[ch + 2]));
    float f3 = fmaxf(0.f, fmaf(bf2f((u16)(v.y >> 16)),    cfa[ch + 3], cfc[ch + 3]));
    float f4 = fmaxf(0.f, fmaf(bf2f((u16)(v.z & 0xffff)), cfa[ch + 4], cfc[ch + 4]));
    float f5 = fmaxf(0.f, fmaf(bf2f((u16)(v.z >> 16)),    cfa[ch + 5], cfc[ch + 5]));
    float f6 = fmaxf(0.f, fmaf(bf2f((u16)(v.w & 0xffff)), cfa[ch + 6], cfc[ch + 6]));
    float f7 = fmaxf(0.f, fmaf(bf2f((u16)(v.w >> 16)),    cfa[ch + 7], cfc[ch + 7]));
    uint4 o;
    o.x = (unsigned int)f2bf(f0) | ((unsigned int)f2bf(f1) << 16);
    o.y = (unsigned int)f2bf(f2) | ((unsigned int)f2bf(f3) << 16);
    o.z = (unsigned int)f2bf(f4) | ((unsigned int)f2bf(f5) << 16);
    o.w = (unsigned int)f2bf(f6) | ((unsigned int)f2bf(f7) << 16);
    *(uint4*)(y0r + i * 8) = o;
  }
}

// ---------------------------------------------------------------------------
// GEMM2: y1b[b,p,n] = W1 . y0r + b1. partials2: [1024 slots][256].
// ---------------------------------------------------------------------------
__global__ __launch_bounds__(256) void gemm2_mfma_kernel(
    const u16* __restrict__ y0r, const u16* __restrict__ W1b,
    const float* __restrict__ b1, u16* __restrict__ y1b, float* __restrict__ partials)
{
  __shared__ SMg sm;

  const int bz = blockIdx.z;
  const int n0 = blockIdx.x * 128;
  const int tid = threadIdx.x;
  const int wid = tid >> 6, lane = tid & 63;
  const int wo = wid & 1, wn = wid >> 1;
  const int m = lane & 15, g = lane >> 4;

  f32x4 acc[4][4];
  #pragma unroll
  for (int i = 0; i < 4; ++i)
    #pragma unroll
    for (int j = 0; j < 4; ++j) acc[i][j] = (f32x4){0.f, 0.f, 0.f, 0.f};

  auto STAGE = [&](int buf, int c) {
    const u16* asrc = W1b + ((size_t)c * C2_) * 32;
    const u16* bsrc = y0r + (((size_t)bz * 8 + c) * N_ + n0) * 32;
    #pragma unroll
    for (int i2 = 0; i2 < 2; ++i2) {
      const int i = wid * 2 + i2;
      gld16(asrc + i * 512 + lane * 8, &sm.p.As[buf][i * 512]);
      gld16(bsrc + i * 512 + lane * 8, &sm.p.Bs[buf][i * 512]);
    }
  };

  STAGE(0, 0);
  __syncthreads();

  for (int kt = 0; kt < 8; ++kt) {
    const int cur = kt & 1;
    if (kt < 7) STAGE(cur ^ 1, kt + 1);

    bf16x8 af[4], bfv[4];
    #pragma unroll
    for (int f = 0; f < 4; ++f)
      af[f] = __builtin_bit_cast(bf16x8,
          *(const short8_*)&sm.p.As[cur][(wo * 64 + f * 16 + m) * 32 + g * 8]);
    #pragma unroll
    for (int f = 0; f < 4; ++f)
      bfv[f] = __builtin_bit_cast(bf16x8,
          *(const short8_*)&sm.p.Bs[cur][(wn * 64 + f * 16 + m) * 32 + g * 8]);
    #pragma unroll
    for (int i = 0; i < 4; ++i)
      #pragma unroll
      for (int j = 0; j < 4; ++j)
        acc[i][j] = __builtin_amdgcn_mfma_f32_16x16x32_bf16(af[i], bfv[j], acc[i][j], 0, 0, 0);

    __syncthreads();
  }

  const int slot = (blockIdx.x * 8 + bz) * 2 + wn;   // 0..1023 unique
  float* prow = partials + (size_t)slot * 256;

  #pragma unroll
  for (int of = 0; of < 4; ++of) {
    const int pb = wo * 64 + of * 16 + g * 4;
    float bias[4], s1[4], s2[4];
    #pragma unroll
    for (int r = 0; r < 4; ++r) { bias[r] = b1[pb + r]; s1[r] = 0.f; s2[r] = 0.f; }
    #pragma unroll
    for (int nf = 0; nf < 4; ++nf) {
      const int nl = wn * 64 + nf * 16 + m;
      #pragma unroll
      for (int r = 0; r < 4; ++r) {
        float y = acc[of][nf][r] + bias[r];
        s1[r] += y; s2[r] += y * y;
        sm.stage[pb + r][nl] = f2bf(y);
      }
    }
    #pragma unroll
    for (int mk = 1; mk < 16; mk <<= 1)
      #pragma unroll
      for (int r = 0; r < 4; ++r) {
        s1[r] += __shfl_xor(s1[r], mk);
        s2[r] += __shfl_xor(s2[r], mk);
      }
    if (m == 0) {
      *(float4*)(prow + pb)        = make_float4(s1[0], s1[1], s1[2], s1[3]);
      *(float4*)(prow + 128 + pb)  = make_float4(s2[0], s2[1], s2[2], s2[3]);
    }
  }
  __syncthreads();
  {
    #pragma unroll
    for (int pass = 0; pass < 8; ++pass) {
      const int idx = pass * 256 + tid;
      const int p = idx >> 4;
      const int c8 = (idx & 15) * 8;
      uint4 v = *(const uint4*)&sm.stage[p][c8];
      *(uint4*)(y1b + ((size_t)bz * C2_ + p) * N_ + n0 + c8) = v;
    }
  }
}

// ---------------------------------------------------------------------------
// final: BN1 + ReLU elementwise, bf16 in -> fp32 out  (y1b is [B][C2][N])
// ---------------------------------------------------------------------------
__global__ __launch_bounds__(256) void final_kernel(
    const u16* __restrict__ y1b, const float* __restrict__ cf, float* __restrict__ out)
{
  const size_t total4 = (size_t)B_ * C2_ * N_ / 4;
  const size_t stride = (size_t)gridDim.x * blockDim.x;
  for (size_t f = (size_t)blockIdx.x * blockDim.x + threadIdx.x; f < total4; f += stride) {
    size_t base = f * 4;
    int p = (int)((base >> 13) & (C2_ - 1));
    float a = cf[p], c = cf[C2_ + p];
    uint2 v = *(const uint2*)(y1b + base);
    float4 r;
    r.x = fmaxf(0.0f, fmaf(bf2f((u16)(v.x & 0xffff)), a, c));
    r.y = fmaxf(0.0f, fmaf(bf2f((u16)(v.x >> 16)),    a, c));
    r.z = fmaxf(0.0f, fmaf(bf2f((u16)(v.y & 0xffff)), a, c));
    r.w = fmaxf(0.0f, fmaf(bf2f((u16)(v.y >> 16)),    a, c));
    *(float4*)(out + base) = r;
  }
}

// ---------------------------------------------------------------------------
extern "C" void kernel_launch(void* const* d_in, const int* in_sizes, int n_in,
                              void* d_out, int out_size, void* d_ws, size_t ws_size,
                              hipStream_t stream)
{
  const float* xyz_sa     = (const float*)d_in[0];
  const float* xyz_now    = (const float*)d_in[1];
  const float* points_sa  = (const float*)d_in[2];
  const float* points_now = (const float*)d_in[3];
  const float* W0  = (const float*)d_in[4];
  const float* b0  = (const float*)d_in[5];
  const float* g0  = (const float*)d_in[6];
  const float* be0 = (const float*)d_in[7];
  const float* W1  = (const float*)d_in[8];
  const float* b1  = (const float*)d_in[9];
  const float* g1  = (const float*)d_in[10];
  const float* be1 = (const float*)d_in[11];

  const size_t MB = 1048576ull;
  char* base = (char*)d_ws;
  u16*   xcat  = (u16*)(base + 0);            // [B][12][N][32] bf16  48MB
  u16*   y0r   = (u16*)(base + 0);            // [B][8][N][32] bf16   32MB (xcat dead)
  float* pnT   = (float*)(base + 48 * MB);    // [B][S][256] f32      16MB (dead after knn)
  u16*   y1b   = (u16*)(base + 48 * MB);      // [B][C2][N] bf16      16MB (overlays pnT)
  u16*   y0b   = (u16*)(base + 64 * MB);      // [B][8][N][32] bf16   32MB
  u16*   W0b   = (u16*)(base + 96 * MB);      // [12][256][32] bf16
  u16*   W1b   = (u16*)(base + 96 * MB + 512 * 1024); // [8][128][32] bf16
  float* coef  = (float*)(base + 97 * MB);    // 768 f
  float* part1 = (float*)(base + 98 * MB);    // [1024][512] f32 2MB
  float* part2 = (float*)(base + 100 * MB);   // [1024][256] f32 1MB
  float* out   = (float*)d_out;

  hipLaunchKernelGGL(cvtW_kernel, dim3((C1_ * C0_ + 255) / 256), dim3(256), 0, stream,
                     W0, W0b, C1_, C0_);
  hipLaunchKernelGGL(cvtW_kernel, dim3((C2_ * C1_ + 255) / 256), dim3(256), 0, stream,
                     W1, W1b, C2_, C1_);
  hipLaunchKernelGGL(transpose_kernel, dim3(S_ / 32, D2_ / 32, B_), dim3(256), 0, stream,
                     points_now, pnT);
  hipLaunchKernelGGL(psaT_kernel, dim3(N_ / 32, D1_ / 32, B_), dim3(256), 0, stream,
                     points_sa, xcat);
  hipLaunchKernelGGL(knn_interp_kernel, dim3(N_ / 32, B_), dim3(256), 0, stream,
                     xyz_sa, xyz_now, pnT, xcat);
  hipLaunchKernelGGL(gemm1_mfma_kernel, dim3(N_ / 128, 2, B_), dim3(256), 0, stream,
                     xcat, W0b, b0, y0b, part1);
  hipLaunchKernelGGL(reduce_coef_kernel, dim3(C1_), dim3(256), 0, stream,
                     part1, 512, C1_, g0, be0, coef);
  hipLaunchKernelGGL(bn0relu_kernel, dim3(2048), dim3(256), 0, stream,
                     y0b, coef, y0r);
  hipLaunchKernelGGL(gemm2_mfma_kernel, dim3(N_ / 128, 1, B_), dim3(256), 0, stream,
                     y0r, W1b, b1, y1b, part2);
  hipLaunchKernelGGL(reduce_coef_kernel, dim3(C2_), dim3(256), 0, stream,
                     part2, 256, C2_, g1, be1, coef + 512);
  hipLaunchKernelGGL(final_kernel, dim3(2048), dim3(256), 0, stream,
                     y1b, coef + 512, out);
}

// Round 16
// 173.124 us; speedup vs baseline: 2.5128x; 1.0306x over previous
//
#include <hip/hip_runtime.h>

#define B_ 8
#define N_ 8192
#define S_ 2048
#define D1_ 128
#define D2_ 256
#define C0_ 384
#define C1_ 256
#define C2_ 128
#define BN_EPS 1e-5f

typedef unsigned long long ull;
typedef unsigned short u16;
typedef __bf16 bf16x8 __attribute__((ext_vector_type(8)));
typedef float f32x4 __attribute__((ext_vector_type(4)));
typedef short short8_ __attribute__((ext_vector_type(8)));

__device__ __forceinline__ u16 f2bf(float x) {
  unsigned int u = __float_as_uint(x);
  unsigned int r = u + 0x7fffu + ((u >> 16) & 1u);
  return (u16)(r >> 16);
}
__device__ __forceinline__ float bf2f(u16 h) {
  return __uint_as_float(((unsigned int)h) << 16);
}

// async global->LDS DMA, 16B/lane; wave-contiguous 1KB source panels.
__device__ __forceinline__ void gld16(const void* g, void* l) {
  __builtin_amdgcn_global_load_lds(
      (const __attribute__((address_space(1))) void*)g,
      (__attribute__((address_space(3))) void*)l,
      16, 0, 0);
}

// branchless sorted top-3 insert on (f32 d, i32 idx); strict < keeps earlier.
__device__ __forceinline__ void insf(float d, int i,
    float& D0, int& I0, float& D1, int& I1, float& D2, int& I2) {
  bool c2 = d < D2, c1 = d < D1, c0 = d < D0;
  D2 = c1 ? D1 : (c2 ? d : D2);  I2 = c1 ? I1 : (c2 ? i : I2);
  D1 = c0 ? D0 : (c1 ? d : D1);  I1 = c0 ? I0 : (c1 ? i : I1);
  D0 = c0 ? d : D0;              I0 = c0 ? i : I0;
}

// ---------------------------------------------------------------------------
// weights f32 [O][K] -> bf16 k-chunked [K/32][O][32]
// ---------------------------------------------------------------------------
__global__ void cvtW_kernel(const float* __restrict__ src, u16* __restrict__ dst,
                            int O, int K)
{
  int i = blockIdx.x * blockDim.x + threadIdx.x;
  if (i < O * K) {
    int o = i / K, kk = i - o * K;
    dst[(((size_t)(kk >> 5) * O + o) << 5) + (kk & 31)] = f2bf(src[i]);
  }
}

// ---------------------------------------------------------------------------
// transpose points_now [B][D2][S] -> pnT [B][S][D2]  (fp32, for knn gather)
// ---------------------------------------------------------------------------
__global__ __launch_bounds__(256) void transpose_kernel(
    const float* __restrict__ in, float* __restrict__ out)
{
  __shared__ float tile[32][33];
  const int b  = blockIdx.z;
  const int s0 = blockIdx.x * 32;
  const int d0 = blockIdx.y * 32;
  const int tx = threadIdx.x & 31, ty = threadIdx.x >> 5;

  const float* inb = in + ((size_t)b * D2_ + d0) * S_ + s0;
  #pragma unroll
  for (int r = 0; r < 4; ++r) {
    int d = r * 8 + ty;
    tile[d][tx] = inb[(size_t)d * S_ + tx];
  }
  __syncthreads();
  float* outb = out + ((size_t)b * S_ + s0) * D2_ + d0;
  #pragma unroll
  for (int r = 0; r < 4; ++r) {
    int s = r * 8 + ty;
    outb[(size_t)s * D2_ + tx] = tile[tx][s];
  }
}

// ---------------------------------------------------------------------------
// points_sa [B][D1][N] f32 -> xcat chunks 0..3  ([12][N][32] per batch, bf16)
// ---------------------------------------------------------------------------
__global__ __launch_bounds__(256) void psaT_kernel(
    const float* __restrict__ in, u16* __restrict__ xcat)
{
  __shared__ float tile[32][33];
  const int b  = blockIdx.z;
  const int n0 = blockIdx.x * 32;
  const int d0 = blockIdx.y * 32;     // chunk = d0>>5
  const int tx = threadIdx.x & 31, ty = threadIdx.x >> 5;

  const float* inb = in + ((size_t)b * D1_ + d0) * N_ + n0;
  #pragma unroll
  for (int r = 0; r < 4; ++r) {
    int d = r * 8 + ty;
    tile[d][tx] = inb[(size_t)d * N_ + tx];
  }
  __syncthreads();
  u16* outb = xcat + (((size_t)b * 12 + (d0 >> 5)) * N_ + n0) * 32;
  #pragma unroll
  for (int r = 0; r < 4; ++r) {
    int n = r * 8 + ty;
    outb[(size_t)n * 32 + tx] = f2bf(tile[tx][n]);
  }
}

// ---------------------------------------------------------------------------
// K1: 3-NN + interpolation (round-14 form). 32 queries/block, 2048 blocks,
// 8 blocks/CU. Scan key d_rel = |p|^2 - 2 q.p; f32 (d,idx) insert, 16 ops.
// ---------------------------------------------------------------------------
__global__ __launch_bounds__(256) void knn_interp_kernel(
    const float* __restrict__ xyz_sa, const float* __restrict__ xyz_now,
    const float* __restrict__ pnT, u16* __restrict__ xcat)
{
  __shared__ float4 sp[1024];
  __shared__ int   s_idx[32][3];
  __shared__ float s_w[32][3];

  const int b  = blockIdx.y;
  const int n0 = blockIdx.x * 32;

  const int qg = threadIdx.x >> 4;   // 0..15 query group (2 queries)
  const int t  = threadIdx.x & 15;   // scanner 0..15
  const int nb = n0 + qg * 2;

  const float* xq = xyz_sa + (size_t)b * 3 * N_;
  float qx[2], qy[2], qz[2], qq[2];
  #pragma unroll
  for (int w = 0; w < 2; ++w) {
    int n = nb + w;
    qx[w] = xq[n]; qy[w] = xq[N_ + n]; qz[w] = xq[2 * N_ + n];
    qq[w] = qx[w] * qx[w] + qy[w] * qy[w] + qz[w] * qz[w];
  }

  float D0[2], D1[2], D2[2];
  int   I0[2], I1[2], I2[2];
  #pragma unroll
  for (int w = 0; w < 2; ++w) {
    D0[w] = 3.4e38f; D1[w] = 3.4e38f; D2[w] = 3.4e38f;
    I0[w] = 0; I1[w] = 0; I2[w] = 0;
  }

  const float* xb = xyz_now + (size_t)b * 3 * S_;
  for (int chunk = 0; chunk < 2; ++chunk) {
    const int sbase = chunk << 10;
    for (int i = threadIdx.x; i < 1024; i += 256) {
      int sg = sbase + i;
      float px = xb[sg], py = xb[S_ + sg], pz = xb[2 * S_ + sg];
      sp[i] = make_float4(-2.f * px, -2.f * py, -2.f * pz,
                          px * px + py * py + pz * pz);
    }
    __syncthreads();

    #pragma unroll 4
    for (int it = 0; it < 64; ++it) {
      int sl = (it << 4) | t;
      float4 p = sp[sl];
      int sg = sbase + sl;
      #pragma unroll
      for (int w = 0; w < 2; ++w) {
        float d = fmaf(p.x, qx[w], fmaf(p.y, qy[w], fmaf(p.z, qz[w], p.w)));
        insf(d, sg, D0[w], I0[w], D1[w], I1[w], D2[w], I2[w]);
      }
    }
    __syncthreads();   // protect sp before next chunk's staging
  }

  // merge the 16 scanners via shuffle butterfly (stays within 16-lane group)
  #pragma unroll
  for (int m = 1; m <= 8; m <<= 1) {
    #pragma unroll
    for (int w = 0; w < 2; ++w) {
      float e0 = __shfl_xor(D0[w], m), e1 = __shfl_xor(D1[w], m), e2 = __shfl_xor(D2[w], m);
      int   j0 = __shfl_xor(I0[w], m), j1 = __shfl_xor(I1[w], m), j2 = __shfl_xor(I2[w], m);
      insf(e0, j0, D0[w], I0[w], D1[w], I1[w], D2[w], I2[w]);
      insf(e1, j1, D0[w], I0[w], D1[w], I1[w], D2[w], I2[w]);
      insf(e2, j2, D0[w], I0[w], D1[w], I1[w], D2[w], I2[w]);
    }
  }

  if (t == 0) {
    #pragma unroll
    for (int w = 0; w < 2; ++w) {
      float d0 = D0[w] + qq[w];
      float d1 = D1[w] + qq[w];
      float d2 = D2[w] + qq[w];
      float r0 = 1.0f / (d0 + 1e-8f);
      float r1 = 1.0f / (d1 + 1e-8f);
      float r2 = 1.0f / (d2 + 1e-8f);
      float rs = 1.0f / (r0 + r1 + r2);
      int qi = qg * 2 + w;
      s_idx[qi][0] = I0[w];
      s_idx[qi][1] = I1[w];
      s_idx[qi][2] = I2[w];
      s_w[qi][0] = r0 * rs; s_w[qi][1] = r1 * rs; s_w[qi][2] = r2 * rs;
    }
  }
  __syncthreads();

  // Phase 2: wave-per-query gather; lane covers chunk 4+(l>>3), 4 channels.
  const int wave = threadIdx.x >> 6;
  const int lane = threadIdx.x & 63;
  const int c8 = lane >> 3;
  const int k4 = (lane & 7) * 4;
  const float* pb = pnT + (size_t)b * S_ * D2_ + c8 * 32 + k4;
  u16* ob = xcat + (((size_t)b * 12 + 4 + c8) * N_ + n0) * 32 + k4;
  #pragma unroll 2
  for (int i = 0; i < 8; ++i) {
    const int qi = wave * 8 + i;
    const int j0 = s_idx[qi][0], j1 = s_idx[qi][1], j2 = s_idx[qi][2];
    const float w0 = s_w[qi][0], w1 = s_w[qi][1], w2 = s_w[qi][2];
    float4 f0 = *(const float4*)(pb + (size_t)j0 * D2_);
    float4 f1 = *(const float4*)(pb + (size_t)j1 * D2_);
    float4 f2 = *(const float4*)(pb + (size_t)j2 * D2_);
    float rx = w0 * f0.x + w1 * f1.x + w2 * f2.x;
    float ry = w0 * f0.y + w1 * f1.y + w2 * f2.y;
    float rz = w0 * f0.z + w1 * f1.z + w2 * f2.z;
    float rw = w0 * f0.w + w1 * f1.w + w2 * f2.w;
    unsigned int lo = (unsigned int)f2bf(rx) | ((unsigned int)f2bf(ry) << 16);
    unsigned int hi = (unsigned int)f2bf(rz) | ((unsigned int)f2bf(rw) << 16);
    *(uint2*)(ob + (size_t)qi * 32) = make_uint2(lo, hi);
  }
}

// ---------------------------------------------------------------------------
union SMg {
  struct { u16 As[2][4096]; u16 Bs[2][4096]; } p;   // [128 rows][32 k] x dbuf
  u16 stage[128][136];
};

// ---------------------------------------------------------------------------
// GEMM1: y0[b,n,o] = W0 . xcat + b0. NO atomics: per-(block,wn) partial
// sums stored to unique slots; reduced later.
// partials1: [1024 slots][512]  (cols 0..255 sum, 256..511 sumsq)
// ---------------------------------------------------------------------------
__global__ __launch_bounds__(256) void gemm1_mfma_kernel(
    const u16* __restrict__ xcat, const u16* __restrict__ W0b,
    const float* __restrict__ b0, u16* __restrict__ y0b, float* __restrict__ partials)
{
  __shared__ SMg sm;

  const int bz = blockIdx.z;
  const int n0 = blockIdx.x * 128;
  const int o0 = blockIdx.y * 128;
  const int tid = threadIdx.x;
  const int wid = tid >> 6, lane = tid & 63;
  const int wo = wid & 1, wn = wid >> 1;
  const int m = lane & 15, g = lane >> 4;

  f32x4 acc[4][4];
  #pragma unroll
  for (int i = 0; i < 4; ++i)
    #pragma unroll
    for (int j = 0; j < 4; ++j) acc[i][j] = (f32x4){0.f, 0.f, 0.f, 0.f};

  auto STAGE = [&](int buf, int c) {
    const u16* asrc = W0b  + ((size_t)c * C1_ + o0) * 32;
    const u16* bsrc = xcat + (((size_t)bz * 12 + c) * N_ + n0) * 32;
    #pragma unroll
    for (int i2 = 0; i2 < 2; ++i2) {
      const int i = wid * 2 + i2;
      gld16(asrc + i * 512 + lane * 8, &sm.p.As[buf][i * 512]);
      gld16(bsrc + i * 512 + lane * 8, &sm.p.Bs[buf][i * 512]);
    }
  };

  STAGE(0, 0);
  __syncthreads();

  for (int kt = 0; kt < 12; ++kt) {
    const int cur = kt & 1;
    if (kt < 11) STAGE(cur ^ 1, kt + 1);

    bf16x8 af[4], bfv[4];
    #pragma unroll
    for (int f = 0; f < 4; ++f)
      af[f] = __builtin_bit_cast(bf16x8,
          *(const short8_*)&sm.p.As[cur][(wo * 64 + f * 16 + m) * 32 + g * 8]);
    #pragma unroll
    for (int f = 0; f < 4; ++f)
      bfv[f] = __builtin_bit_cast(bf16x8,
          *(const short8_*)&sm.p.Bs[cur][(wn * 64 + f * 16 + m) * 32 + g * 8]);
    #pragma unroll
    for (int i = 0; i < 4; ++i)
      #pragma unroll
      for (int j = 0; j < 4; ++j)
        acc[i][j] = __builtin_amdgcn_mfma_f32_16x16x32_bf16(af[i], bfv[j], acc[i][j], 0, 0, 0);

    __syncthreads();
  }

  const int slot = (blockIdx.x * 8 + bz) * 2 + wn;   // 0..1023 unique
  float* prow = partials + (size_t)slot * 512;

  #pragma unroll
  for (int of = 0; of < 4; ++of) {
    const int ol = wo * 64 + of * 16 + g * 4;
    const int ob = o0 + ol;
    float bias[4], s1[4], s2[4];
    #pragma unroll
    for (int r = 0; r < 4; ++r) { bias[r] = b0[ob + r]; s1[r] = 0.f; s2[r] = 0.f; }
    #pragma unroll
    for (int nf = 0; nf < 4; ++nf) {
      const int nl = wn * 64 + nf * 16 + m;
      float y[4];
      #pragma unroll
      for (int r = 0; r < 4; ++r) {
        y[r] = acc[of][nf][r] + bias[r];
        s1[r] += y[r]; s2[r] += y[r] * y[r];
      }
      unsigned int lo = (unsigned int)f2bf(y[0]) | ((unsigned int)f2bf(y[1]) << 16);
      unsigned int hi = (unsigned int)f2bf(y[2]) | ((unsigned int)f2bf(y[3]) << 16);
      *(uint2*)&sm.stage[nl][ol] = make_uint2(lo, hi);
    }
    #pragma unroll
    for (int mk = 1; mk < 16; mk <<= 1)
      #pragma unroll
      for (int r = 0; r < 4; ++r) {
        s1[r] += __shfl_xor(s1[r], mk);
        s2[r] += __shfl_xor(s2[r], mk);
      }
    if (m == 0) {
      *(float4*)(prow + ob)        = make_float4(s1[0], s1[1], s1[2], s1[3]);
      *(float4*)(prow + 256 + ob)  = make_float4(s2[0], s2[1], s2[2], s2[3]);
    }
  }
  __syncthreads();
  {
    const int rrow = tid >> 4;
    const int col  = (tid & 15) * 8;
    const int c    = (o0 + col) >> 5;
    const int ko   = (o0 + col) & 31;
    u16* dst = y0b + (((size_t)bz * 8 + c) * N_ + n0) * 32 + ko;
    #pragma unroll
    for (int pass = 0; pass < 8; ++pass) {
      const int r = pass * 16 + rrow;
      *(uint4*)(dst + (size_t)r * 32) = *(const uint4*)&sm.stage[r][col];
    }
  }
}

// ---------------------------------------------------------------------------
// reduce partials -> BN coef. grid = C blocks; partial row width R floats.
// ---------------------------------------------------------------------------
__global__ __launch_bounds__(256) void reduce_coef_kernel(
    const float* __restrict__ partials, int R, int C,
    const float* __restrict__ g, const float* __restrict__ be,
    float* __restrict__ coef)
{
  const int ch = blockIdx.x;
  const int tid = threadIdx.x;
  float s = 0.f, q = 0.f;
  #pragma unroll
  for (int k = 0; k < 4; ++k) {
    const float* row = partials + (size_t)(tid + k * 256) * R;
    s += row[ch];
    q += row[C + ch];
  }
  #pragma unroll
  for (int mk = 1; mk < 64; mk <<= 1) { s += __shfl_xor(s, mk); q += __shfl_xor(q, mk); }
  __shared__ float ls[4], lq[4];
  const int wid = tid >> 6;
  if ((tid & 63) == 0) { ls[wid] = s; lq[wid] = q; }
  __syncthreads();
  if (tid == 0) {
    s = ls[0] + ls[1] + ls[2] + ls[3];
    q = lq[0] + lq[1] + lq[2] + lq[3];
    const float invM = 1.0f / 65536.0f;   // B*N
    float mean = s * invM;
    float var  = q * invM - mean * mean;
    float a = g[ch] / sqrtf(var + BN_EPS);
    float c = be[ch] - mean * a;
    coef[ch] = a;
    coef[C + ch] = c;
  }
}

// ---------------------------------------------------------------------------
// GEMM2 (BN0+ReLU fused into B-staging): y1b[b,p,n] = W1 . relu(bn0(y0)) + b1
// A: async gld16 DMA. B: reg-staged (global uint4 -> coef transform ->
// ds_write), double-buffered, one barrier per K-step. Bit-identical to the
// old separate bn0relu pass (same bf16 round-trip). partials2: [1024][256].
// ---------------------------------------------------------------------------
__global__ __launch_bounds__(256) void gemm2_mfma_kernel(
    const u16* __restrict__ y0b, const float* __restrict__ coef,
    const u16* __restrict__ W1b, const float* __restrict__ b1,
    u16* __restrict__ y1b, float* __restrict__ partials)
{
  __shared__ SMg sm;
  __shared__ float cfa[C1_], cfc[C1_];

  const int bz = blockIdx.z;
  const int n0 = blockIdx.x * 128;
  const int tid = threadIdx.x;
  const int wid = tid >> 6, lane = tid & 63;
  const int wo = wid & 1, wn = wid >> 1;
  const int m = lane & 15, g = lane >> 4;

  cfa[tid] = coef[tid];
  cfc[tid] = coef[C1_ + tid];

  f32x4 acc[4][4];
  #pragma unroll
  for (int i = 0; i < 4; ++i)
    #pragma unroll
    for (int j = 0; j < 4; ++j) acc[i][j] = (f32x4){0.f, 0.f, 0.f, 0.f};

  auto STAGE_A = [&](int buf, int c) {
    const u16* asrc = W1b + ((size_t)c * C2_) * 32;
    #pragma unroll
    for (int i2 = 0; i2 < 2; ++i2) {
      const int i = wid * 2 + i2;
      gld16(asrc + i * 512 + lane * 8, &sm.p.As[buf][i * 512]);
    }
  };

  uint4 rb[2];
  auto BLOAD = [&](int c) {
    const u16* bsrc = y0b + (((size_t)bz * 8 + c) * N_ + n0) * 32 + tid * 8;
    rb[0] = *(const uint4*)bsrc;
    rb[1] = *(const uint4*)(bsrc + 2048);
  };
  auto BWRITE = [&](int buf, int c) {
    const int ch = c * 32 + (tid & 3) * 8;   // k-channel, constant per thread
    float a0 = cfa[ch + 0], a1 = cfa[ch + 1], a2 = cfa[ch + 2], a3 = cfa[ch + 3];
    float a4 = cfa[ch + 4], a5 = cfa[ch + 5], a6 = cfa[ch + 6], a7 = cfa[ch + 7];
    float c0 = cfc[ch + 0], c1 = cfc[ch + 1], c2 = cfc[ch + 2], c3 = cfc[ch + 3];
    float c4 = cfc[ch + 4], c5 = cfc[ch + 5], c6 = cfc[ch + 6], c7 = cfc[ch + 7];
    #pragma unroll
    for (int h = 0; h < 2; ++h) {
      uint4 v = rb[h];
      float f0 = fmaxf(0.f, fmaf(bf2f((u16)(v.x & 0xffff)), a0, c0));
      float f1 = fmaxf(0.f, fmaf(bf2f((u16)(v.x >> 16)),    a1, c1));
      float f2 = fmaxf(0.f, fmaf(bf2f((u16)(v.y & 0xffff)), a2, c2));
      float f3 = fmaxf(0.f, fmaf(bf2f((u16)(v.y >> 16)),    a3, c3));
      float f4 = fmaxf(0.f, fmaf(bf2f((u16)(v.z & 0xffff)), a4, c4));
      float f5 = fmaxf(0.f, fmaf(bf2f((u16)(v.z >> 16)),    a5, c5));
      float f6 = fmaxf(0.f, fmaf(bf2f((u16)(v.w & 0xffff)), a6, c6));
      float f7 = fmaxf(0.f, fmaf(bf2f((u16)(v.w >> 16)),    a7, c7));
      uint4 o;
      o.x = (unsigned int)f2bf(f0) | ((unsigned int)f2bf(f1) << 16);
      o.y = (unsigned int)f2bf(f2) | ((unsigned int)f2bf(f3) << 16);
      o.z = (unsigned int)f2bf(f4) | ((unsigned int)f2bf(f5) << 16);
      o.w = (unsigned int)f2bf(f6) | ((unsigned int)f2bf(f7) << 16);
      *(uint4*)&sm.p.Bs[buf][h * 2048 + tid * 8] = o;
    }
  };

  BLOAD(0);
  STAGE_A(0, 0);
  __syncthreads();            // cfa/cfc ready (also A tile landing)
  BWRITE(0, 0);
  __syncthreads();            // tile 0 fully ready

  for (int kt = 0; kt < 8; ++kt) {
    const int cur = kt & 1;
    if (kt < 7) { STAGE_A(cur ^ 1, kt + 1); BLOAD(kt + 1); }

    bf16x8 af[4], bfv[4];
    #pragma unroll
    for (int f = 0; f < 4; ++f)
      af[f] = __builtin_bit_cast(bf16x8,
          *(const short8_*)&sm.p.As[cur][(wo * 64 + f * 16 + m) * 32 + g * 8]);
    #pragma unroll
    for (int f = 0; f < 4; ++f)
      bfv[f] = __builtin_bit_cast(bf16x8,
          *(const short8_*)&sm.p.Bs[cur][(wn * 64 + f * 16 + m) * 32 + g * 8]);
    #pragma unroll
    for (int i = 0; i < 4; ++i)
      #pragma unroll
      for (int j = 0; j < 4; ++j)
        acc[i][j] = __builtin_amdgcn_mfma_f32_16x16x32_bf16(af[i], bfv[j], acc[i][j], 0, 0, 0);

    if (kt < 7) BWRITE(cur ^ 1, kt + 1);
    __syncthreads();
  }

  const int slot = (blockIdx.x * 8 + bz) * 2 + wn;   // 0..1023 unique
  float* prow = partials + (size_t)slot * 256;

  #pragma unroll
  for (int of = 0; of < 4; ++of) {
    const int pb = wo * 64 + of * 16 + g * 4;
    float bias[4], s1[4], s2[4];
    #pragma unroll
    for (int r = 0; r < 4; ++r) { bias[r] = b1[pb + r]; s1[r] = 0.f; s2[r] = 0.f; }
    #pragma unroll
    for (int nf = 0; nf < 4; ++nf) {
      const int nl = wn * 64 + nf * 16 + m;
      #pragma unroll
      for (int r = 0; r < 4; ++r) {
        float y = acc[of][nf][r] + bias[r];
        s1[r] += y; s2[r] += y * y;
        sm.stage[pb + r][nl] = f2bf(y);
      }
    }
    #pragma unroll
    for (int mk = 1; mk < 16; mk <<= 1)
      #pragma unroll
      for (int r = 0; r < 4; ++r) {
        s1[r] += __shfl_xor(s1[r], mk);
        s2[r] += __shfl_xor(s2[r], mk);
      }
    if (m == 0) {
      *(float4*)(prow + pb)        = make_float4(s1[0], s1[1], s1[2], s1[3]);
      *(float4*)(prow + 128 + pb)  = make_float4(s2[0], s2[1], s2[2], s2[3]);
    }
  }
  __syncthreads();
  {
    #pragma unroll
    for (int pass = 0; pass < 8; ++pass) {
      const int idx = pass * 256 + tid;
      const int p = idx >> 4;
      const int c8 = (idx & 15) * 8;
      uint4 v = *(const uint4*)&sm.stage[p][c8];
      *(uint4*)(y1b + ((size_t)bz * C2_ + p) * N_ + n0 + c8) = v;
    }
  }
}

// ---------------------------------------------------------------------------
// final: BN1 + ReLU elementwise, bf16 in -> fp32 out  (y1b is [B][C2][N])
// ---------------------------------------------------------------------------
__global__ __launch_bounds__(256) void final_kernel(
    const u16* __restrict__ y1b, const float* __restrict__ cf, float* __restrict__ out)
{
  const size_t total4 = (size_t)B_ * C2_ * N_ / 4;
  const size_t stride = (size_t)gridDim.x * blockDim.x;
  for (size_t f = (size_t)blockIdx.x * blockDim.x + threadIdx.x; f < total4; f += stride) {
    size_t base = f * 4;
    int p = (int)((base >> 13) & (C2_ - 1));
    float a = cf[p], c = cf[C2_ + p];
    uint2 v = *(const uint2*)(y1b + base);
    float4 r;
    r.x = fmaxf(0.0f, fmaf(bf2f((u16)(v.x & 0xffff)), a, c));
    r.y = fmaxf(0.0f, fmaf(bf2f((u16)(v.x >> 16)),    a, c));
    r.z = fmaxf(0.0f, fmaf(bf2f((u16)(v.y & 0xffff)), a, c));
    r.w = fmaxf(0.0f, fmaf(bf2f((u16)(v.y >> 16)),    a, c));
    *(float4*)(out + base) = r;
  }
}

// ---------------------------------------------------------------------------
extern "C" void kernel_launch(void* const* d_in, const int* in_sizes, int n_in,
                              void* d_out, int out_size, void* d_ws, size_t ws_size,
                              hipStream_t stream)
{
  const float* xyz_sa     = (const float*)d_in[0];
  const float* xyz_now    = (const float*)d_in[1];
  const float* points_sa  = (const float*)d_in[2];
  const float* points_now = (const float*)d_in[3];
  const float* W0  = (const float*)d_in[4];
  const float* b0  = (const float*)d_in[5];
  const float* g0  = (const float*)d_in[6];
  const float* be0 = (const float*)d_in[7];
  const float* W1  = (const float*)d_in[8];
  const float* b1  = (const float*)d_in[9];
  const float* g1  = (const float*)d_in[10];
  const float* be1 = (const float*)d_in[11];

  const size_t MB = 1048576ull;
  char* base = (char*)d_ws;
  u16*   xcat  = (u16*)(base + 0);            // [B][12][N][32] bf16  48MB
  float* pnT   = (float*)(base + 48 * MB);    // [B][S][256] f32      16MB (dead after knn)
  u16*   y1b   = (u16*)(base + 48 * MB);      // [B][C2][N] bf16      16MB (overlays pnT)
  u16*   y0b   = (u16*)(base + 64 * MB);      // [B][8][N][32] bf16   32MB
  u16*   W0b   = (u16*)(base + 96 * MB);      // [12][256][32] bf16
  u16*   W1b   = (u16*)(base + 96 * MB + 512 * 1024); // [8][128][32] bf16
  float* coef  = (float*)(base + 97 * MB);    // 768 f
  float* part1 = (float*)(base + 98 * MB);    // [1024][512] f32 2MB
  float* part2 = (float*)(base + 100 * MB);   // [1024][256] f32 1MB
  float* out   = (float*)d_out;

  hipLaunchKernelGGL(cvtW_kernel, dim3((C1_ * C0_ + 255) / 256), dim3(256), 0, stream,
                     W0, W0b, C1_, C0_);
  hipLaunchKernelGGL(cvtW_kernel, dim3((C2_ * C1_ + 255) / 256), dim3(256), 0, stream,
                     W1, W1b, C2_, C1_);
  hipLaunchKernelGGL(transpose_kernel, dim3(S_ / 32, D2_ / 32, B_), dim3(256), 0, stream,
                     points_now, pnT);
  hipLaunchKernelGGL(psaT_kernel, dim3(N_ / 32, D1_ / 32, B_), dim3(256), 0, stream,
                     points_sa, xcat);
  hipLaunchKernelGGL(knn_interp_kernel, dim3(N_ / 32, B_), dim3(256), 0, stream,
                     xyz_sa, xyz_now, pnT, xcat);
  hipLaunchKernelGGL(gemm1_mfma_kernel, dim3(N_ / 128, 2, B_), dim3(256), 0, stream,
                     xcat, W0b, b0, y0b, part1);
  hipLaunchKernelGGL(reduce_coef_kernel, dim3(C1_), dim3(256), 0, stream,
                     part1, 512, C1_, g0, be0, coef);
  hipLaunchKernelGGL(gemm2_mfma_kernel, dim3(N_ / 128, 1, B_), dim3(256), 0, stream,
                     y0b, coef, W1b, b1, y1b, part2);
  hipLaunchKernelGGL(reduce_coef_kernel, dim3(C2_), dim3(256), 0, stream,
                     part2, 256, C2_, g1, be1, coef + 512);
  hipLaunchKernelGGL(final_kernel, dim3(2048), dim3(256), 0, stream,
                     y1b, coef + 512, out);
}

// Round 17
// 166.660 us; speedup vs baseline: 2.6102x; 1.0388x over previous
//
#include <hip/hip_runtime.h>

#define B_ 8
#define N_ 8192
#define S_ 2048
#define D1_ 128
#define D2_ 256
#define C0_ 384
#define C1_ 256
#define C2_ 128
#define BN_EPS 1e-5f

typedef unsigned long long ull;
typedef unsigned short u16;
typedef __bf16 bf16x8 __attribute__((ext_vector_type(8)));
typedef float f32x4 __attribute__((ext_vector_type(4)));
typedef short short8_ __attribute__((ext_vector_type(8)));

__device__ __forceinline__ u16 f2bf(float x) {
  unsigned int u = __float_as_uint(x);
  unsigned int r = u + 0x7fffu + ((u >> 16) & 1u);
  return (u16)(r >> 16);
}
__device__ __forceinline__ float bf2f(u16 h) {
  return __uint_as_float(((unsigned int)h) << 16);
}

// async global->LDS DMA, 16B/lane; wave-contiguous 1KB source panels.
__device__ __forceinline__ void gld16(const void* g, void* l) {
  __builtin_amdgcn_global_load_lds(
      (const __attribute__((address_space(1))) void*)g,
      (__attribute__((address_space(3))) void*)l,
      16, 0, 0);
}

// sorted top-3 insert on (f32 d, i32 idx); strict < keeps earlier index.
// floats via med3/min (3 ops), indices via 3 cmp + 5 cndmask. 11 ops total.
// Value results identical to the cndmask version (med3 returns the same
// element); index tie-break identical (strict <).
__device__ __forceinline__ void insf(float d, int i,
    float& D0, int& I0, float& D1, int& I1, float& D2, int& I2) {
  bool c2 = d < D2, c1 = d < D1, c0 = d < D0;
  D2 = __builtin_amdgcn_fmed3f(D1, D2, d);   // 3rd smallest of {D0..D2,d}
  D1 = __builtin_amdgcn_fmed3f(D0, D1, d);   // 2nd smallest
  D0 = fminf(D0, d);                          // smallest
  I2 = c1 ? I1 : (c2 ? i : I2);
  I1 = c0 ? I0 : (c1 ? i : I1);
  I0 = c0 ? i : I0;
}

// ---------------------------------------------------------------------------
// prep: fused weight-convert (k-chunked) + pnT transpose + psaT transpose.
// flat grid: [0,384) cvt W0; [384,512) cvt W1; [512,4608) transpose pnT;
// [4608,12800) psaT. All bodies identical to the previously-passing kernels.
// ---------------------------------------------------------------------------
__global__ __launch_bounds__(256) void prep_kernel(
    const float* __restrict__ W0, u16* __restrict__ W0b,
    const float* __restrict__ W1, u16* __restrict__ W1b,
    const float* __restrict__ points_now, float* __restrict__ pnT,
    const float* __restrict__ points_sa, u16* __restrict__ xcat)
{
  const int bid = blockIdx.x;
  const int tid = threadIdx.x;

  if (bid < 384) {                       // W0 [256][384] -> [12][256][32]
    int i = bid * 256 + tid;
    int o = i / C0_, kk = i - o * C0_;
    W0b[(((size_t)(kk >> 5) * C1_ + o) << 5) + (kk & 31)] = f2bf(W0[i]);
    return;
  }
  if (bid < 512) {                       // W1 [128][256] -> [8][128][32]
    int i = (bid - 384) * 256 + tid;
    int o = i / C1_, kk = i - o * C1_;
    W1b[(((size_t)(kk >> 5) * C2_ + o) << 5) + (kk & 31)] = f2bf(W1[i]);
    return;
  }

  __shared__ float tile[32][33];
  const int tx = tid & 31, ty = tid >> 5;

  if (bid < 4608) {                      // points_now [B][D2][S] -> pnT [B][S][D2]
    const int f  = bid - 512;            // (64, 8, 8)
    const int s0 = (f & 63) * 32;
    const int d0 = ((f >> 6) & 7) * 32;
    const int b  = f >> 9;
    const float* inb = points_now + ((size_t)b * D2_ + d0) * S_ + s0;
    #pragma unroll
    for (int r = 0; r < 4; ++r) {
      int d = r * 8 + ty;
      tile[d][tx] = inb[(size_t)d * S_ + tx];
    }
    __syncthreads();
    float* outb = pnT + ((size_t)b * S_ + s0) * D2_ + d0;
    #pragma unroll
    for (int r = 0; r < 4; ++r) {
      int s = r * 8 + ty;
      outb[(size_t)s * D2_ + tx] = tile[tx][s];
    }
    return;
  }

  {                                      // points_sa [B][D1][N] -> xcat chunks 0..3
    const int f  = bid - 4608;           // (256, 4, 8)
    const int n0 = (f & 255) * 32;
    const int d0 = ((f >> 8) & 3) * 32;
    const int b  = f >> 10;
    const float* inb = points_sa + ((size_t)b * D1_ + d0) * N_ + n0;
    #pragma unroll
    for (int r = 0; r < 4; ++r) {
      int d = r * 8 + ty;
      tile[d][tx] = inb[(size_t)d * N_ + tx];
    }
    __syncthreads();
    u16* outb = xcat + (((size_t)b * 12 + (d0 >> 5)) * N_ + n0) * 32;
    #pragma unroll
    for (int r = 0; r < 4; ++r) {
      int n = r * 8 + ty;
      outb[(size_t)n * 32 + tx] = f2bf(tile[tx][n]);
    }
  }
}

// ---------------------------------------------------------------------------
// K1: 3-NN + interpolation. 32 queries/block, 2048 blocks, 8 blocks/CU.
// Scan key d_rel = |p|^2 - 2 q.p; med3-based (d,idx) insert, 14 ops/pair.
// ---------------------------------------------------------------------------
__global__ __launch_bounds__(256) void knn_interp_kernel(
    const float* __restrict__ xyz_sa, const float* __restrict__ xyz_now,
    const float* __restrict__ pnT, u16* __restrict__ xcat)
{
  __shared__ float4 sp[1024];
  __shared__ int   s_idx[32][3];
  __shared__ float s_w[32][3];

  const int b  = blockIdx.y;
  const int n0 = blockIdx.x * 32;

  const int qg = threadIdx.x >> 4;   // 0..15 query group (2 queries)
  const int t  = threadIdx.x & 15;   // scanner 0..15
  const int nb = n0 + qg * 2;

  const float* xq = xyz_sa + (size_t)b * 3 * N_;
  float qx[2], qy[2], qz[2], qq[2];
  #pragma unroll
  for (int w = 0; w < 2; ++w) {
    int n = nb + w;
    qx[w] = xq[n]; qy[w] = xq[N_ + n]; qz[w] = xq[2 * N_ + n];
    qq[w] = qx[w] * qx[w] + qy[w] * qy[w] + qz[w] * qz[w];
  }

  float D0[2], D1[2], D2[2];
  int   I0[2], I1[2], I2[2];
  #pragma unroll
  for (int w = 0; w < 2; ++w) {
    D0[w] = 3.4e38f; D1[w] = 3.4e38f; D2[w] = 3.4e38f;
    I0[w] = 0; I1[w] = 0; I2[w] = 0;
  }

  const float* xb = xyz_now + (size_t)b * 3 * S_;
  for (int chunk = 0; chunk < 2; ++chunk) {
    const int sbase = chunk << 10;
    for (int i = threadIdx.x; i < 1024; i += 256) {
      int sg = sbase + i;
      float px = xb[sg], py = xb[S_ + sg], pz = xb[2 * S_ + sg];
      sp[i] = make_float4(-2.f * px, -2.f * py, -2.f * pz,
                          px * px + py * py + pz * pz);
    }
    __syncthreads();

    #pragma unroll 4
    for (int it = 0; it < 64; ++it) {
      int sl = (it << 4) | t;
      float4 p = sp[sl];
      int sg = sbase + sl;
      #pragma unroll
      for (int w = 0; w < 2; ++w) {
        float d = fmaf(p.x, qx[w], fmaf(p.y, qy[w], fmaf(p.z, qz[w], p.w)));
        insf(d, sg, D0[w], I0[w], D1[w], I1[w], D2[w], I2[w]);
      }
    }
    __syncthreads();   // protect sp before next chunk's staging
  }

  // merge the 16 scanners via shuffle butterfly (stays within 16-lane group)
  #pragma unroll
  for (int m = 1; m <= 8; m <<= 1) {
    #pragma unroll
    for (int w = 0; w < 2; ++w) {
      float e0 = __shfl_xor(D0[w], m), e1 = __shfl_xor(D1[w], m), e2 = __shfl_xor(D2[w], m);
      int   j0 = __shfl_xor(I0[w], m), j1 = __shfl_xor(I1[w], m), j2 = __shfl_xor(I2[w], m);
      insf(e0, j0, D0[w], I0[w], D1[w], I1[w], D2[w], I2[w]);
      insf(e1, j1, D0[w], I0[w], D1[w], I1[w], D2[w], I2[w]);
      insf(e2, j2, D0[w], I0[w], D1[w], I1[w], D2[w], I2[w]);
    }
  }

  if (t == 0) {
    #pragma unroll
    for (int w = 0; w < 2; ++w) {
      float d0 = D0[w] + qq[w];
      float d1 = D1[w] + qq[w];
      float d2 = D2[w] + qq[w];
      float r0 = 1.0f / (d0 + 1e-8f);
      float r1 = 1.0f / (d1 + 1e-8f);
      float r2 = 1.0f / (d2 + 1e-8f);
      float rs = 1.0f / (r0 + r1 + r2);
      int qi = qg * 2 + w;
      s_idx[qi][0] = I0[w];
      s_idx[qi][1] = I1[w];
      s_idx[qi][2] = I2[w];
      s_w[qi][0] = r0 * rs; s_w[qi][1] = r1 * rs; s_w[qi][2] = r2 * rs;
    }
  }
  __syncthreads();

  // Phase 2: wave-per-query gather; lane covers chunk 4+(l>>3), 4 channels.
  const int wave = threadIdx.x >> 6;
  const int lane = threadIdx.x & 63;
  const int c8 = lane >> 3;
  const int k4 = (lane & 7) * 4;
  const float* pb = pnT + (size_t)b * S_ * D2_ + c8 * 32 + k4;
  u16* ob = xcat + (((size_t)b * 12 + 4 + c8) * N_ + n0) * 32 + k4;
  #pragma unroll 2
  for (int i = 0; i < 8; ++i) {
    const int qi = wave * 8 + i;
    const int j0 = s_idx[qi][0], j1 = s_idx[qi][1], j2 = s_idx[qi][2];
    const float w0 = s_w[qi][0], w1 = s_w[qi][1], w2 = s_w[qi][2];
    float4 f0 = *(const float4*)(pb + (size_t)j0 * D2_);
    float4 f1 = *(const float4*)(pb + (size_t)j1 * D2_);
    float4 f2 = *(const float4*)(pb + (size_t)j2 * D2_);
    float rx = w0 * f0.x + w1 * f1.x + w2 * f2.x;
    float ry = w0 * f0.y + w1 * f1.y + w2 * f2.y;
    float rz = w0 * f0.z + w1 * f1.z + w2 * f2.z;
    float rw = w0 * f0.w + w1 * f1.w + w2 * f2.w;
    unsigned int lo = (unsigned int)f2bf(rx) | ((unsigned int)f2bf(ry) << 16);
    unsigned int hi = (unsigned int)f2bf(rz) | ((unsigned int)f2bf(rw) << 16);
    *(uint2*)(ob + (size_t)qi * 32) = make_uint2(lo, hi);
  }
}

// ---------------------------------------------------------------------------
union SMg {
  struct { u16 As[2][4096]; u16 Bs[2][4096]; } p;   // [128 rows][32 k] x dbuf
  u16 stage[128][136];
};

// ---------------------------------------------------------------------------
// GEMM1: y0[b,n,o] = W0 . xcat + b0. NO atomics: per-(block,wn) partial
// sums stored to unique slots; reduced later.
// partials1: [1024 slots][512]  (cols 0..255 sum, 256..511 sumsq)
// ---------------------------------------------------------------------------
__global__ __launch_bounds__(256) void gemm1_mfma_kernel(
    const u16* __restrict__ xcat, const u16* __restrict__ W0b,
    const float* __restrict__ b0, u16* __restrict__ y0b, float* __restrict__ partials)
{
  __shared__ SMg sm;

  const int bz = blockIdx.z;
  const int n0 = blockIdx.x * 128;
  const int o0 = blockIdx.y * 128;
  const int tid = threadIdx.x;
  const int wid = tid >> 6, lane = tid & 63;
  const int wo = wid & 1, wn = wid >> 1;
  const int m = lane & 15, g = lane >> 4;

  f32x4 acc[4][4];
  #pragma unroll
  for (int i = 0; i < 4; ++i)
    #pragma unroll
    for (int j = 0; j < 4; ++j) acc[i][j] = (f32x4){0.f, 0.f, 0.f, 0.f};

  auto STAGE = [&](int buf, int c) {
    const u16* asrc = W0b  + ((size_t)c * C1_ + o0) * 32;
    const u16* bsrc = xcat + (((size_t)bz * 12 + c) * N_ + n0) * 32;
    #pragma unroll
    for (int i2 = 0; i2 < 2; ++i2) {
      const int i = wid * 2 + i2;
      gld16(asrc + i * 512 + lane * 8, &sm.p.As[buf][i * 512]);
      gld16(bsrc + i * 512 + lane * 8, &sm.p.Bs[buf][i * 512]);
    }
  };

  STAGE(0, 0);
  __syncthreads();

  for (int kt = 0; kt < 12; ++kt) {
    const int cur = kt & 1;
    if (kt < 11) STAGE(cur ^ 1, kt + 1);

    bf16x8 af[4], bfv[4];
    #pragma unroll
    for (int f = 0; f < 4; ++f)
      af[f] = __builtin_bit_cast(bf16x8,
          *(const short8_*)&sm.p.As[cur][(wo * 64 + f * 16 + m) * 32 + g * 8]);
    #pragma unroll
    for (int f = 0; f < 4; ++f)
      bfv[f] = __builtin_bit_cast(bf16x8,
          *(const short8_*)&sm.p.Bs[cur][(wn * 64 + f * 16 + m) * 32 + g * 8]);
    #pragma unroll
    for (int i = 0; i < 4; ++i)
      #pragma unroll
      for (int j = 0; j < 4; ++j)
        acc[i][j] = __builtin_amdgcn_mfma_f32_16x16x32_bf16(af[i], bfv[j], acc[i][j], 0, 0, 0);

    __syncthreads();
  }

  const int slot = (blockIdx.x * 8 + bz) * 2 + wn;   // 0..1023 unique
  float* prow = partials + (size_t)slot * 512;

  #pragma unroll
  for (int of = 0; of < 4; ++of) {
    const int ol = wo * 64 + of * 16 + g * 4;
    const int ob = o0 + ol;
    float bias[4], s1[4], s2[4];
    #pragma unroll
    for (int r = 0; r < 4; ++r) { bias[r] = b0[ob + r]; s1[r] = 0.f; s2[r] = 0.f; }
    #pragma unroll
    for (int nf = 0; nf < 4; ++nf) {
      const int nl = wn * 64 + nf * 16 + m;
      float y[4];
      #pragma unroll
      for (int r = 0; r < 4; ++r) {
        y[r] = acc[of][nf][r] + bias[r];
        s1[r] += y[r]; s2[r] += y[r] * y[r];
      }
      unsigned int lo = (unsigned int)f2bf(y[0]) | ((unsigned int)f2bf(y[1]) << 16);
      unsigned int hi = (unsigned int)f2bf(y[2]) | ((unsigned int)f2bf(y[3]) << 16);
      *(uint2*)&sm.stage[nl][ol] = make_uint2(lo, hi);
    }
    #pragma unroll
    for (int mk = 1; mk < 16; mk <<= 1)
      #pragma unroll
      for (int r = 0; r < 4; ++r) {
        s1[r] += __shfl_xor(s1[r], mk);
        s2[r] += __shfl_xor(s2[r], mk);
      }
    if (m == 0) {
      *(float4*)(prow + ob)        = make_float4(s1[0], s1[1], s1[2], s1[3]);
      *(float4*)(prow + 256 + ob)  = make_float4(s2[0], s2[1], s2[2], s2[3]);
    }
  }
  __syncthreads();
  {
    const int rrow = tid >> 4;
    const int col  = (tid & 15) * 8;
    const int c    = (o0 + col) >> 5;
    const int ko   = (o0 + col) & 31;
    u16* dst = y0b + (((size_t)bz * 8 + c) * N_ + n0) * 32 + ko;
    #pragma unroll
    for (int pass = 0; pass < 8; ++pass) {
      const int r = pass * 16 + rrow;
      *(uint4*)(dst + (size_t)r * 32) = *(const uint4*)&sm.stage[r][col];
    }
  }
}

// ---------------------------------------------------------------------------
// reduce partials -> BN coef. grid = C blocks; partial row width R floats.
// ---------------------------------------------------------------------------
__global__ __launch_bounds__(256) void reduce_coef_kernel(
    const float* __restrict__ partials, int R, int C,
    const float* __restrict__ g, const float* __restrict__ be,
    float* __restrict__ coef)
{
  const int ch = blockIdx.x;
  const int tid = threadIdx.x;
  float s = 0.f, q = 0.f;
  #pragma unroll
  for (int k = 0; k < 4; ++k) {
    const float* row = partials + (size_t)(tid + k * 256) * R;
    s += row[ch];
    q += row[C + ch];
  }
  #pragma unroll
  for (int mk = 1; mk < 64; mk <<= 1) { s += __shfl_xor(s, mk); q += __shfl_xor(q, mk); }
  __shared__ float ls[4], lq[4];
  const int wid = tid >> 6;
  if ((tid & 63) == 0) { ls[wid] = s; lq[wid] = q; }
  __syncthreads();
  if (tid == 0) {
    s = ls[0] + ls[1] + ls[2] + ls[3];
    q = lq[0] + lq[1] + lq[2] + lq[3];
    const float invM = 1.0f / 65536.0f;   // B*N
    float mean = s * invM;
    float var  = q * invM - mean * mean;
    float a = g[ch] / sqrtf(var + BN_EPS);
    float c = be[ch] - mean * a;
    coef[ch] = a;
    coef[C + ch] = c;
  }
}

// ---------------------------------------------------------------------------
// GEMM2 (BN0+ReLU fused into B-staging): y1b[b,p,n] = W1 . relu(bn0(y0)) + b1
// ---------------------------------------------------------------------------
__global__ __launch_bounds__(256) void gemm2_mfma_kernel(
    const u16* __restrict__ y0b, const float* __restrict__ coef,
    const u16* __restrict__ W1b, const float* __restrict__ b1,
    u16* __restrict__ y1b, float* __restrict__ partials)
{
  __shared__ SMg sm;
  __shared__ float cfa[C1_], cfc[C1_];

  const int bz = blockIdx.z;
  const int n0 = blockIdx.x * 128;
  const int tid = threadIdx.x;
  const int wid = tid >> 6, lane = tid & 63;
  const int wo = wid & 1, wn = wid >> 1;
  const int m = lane & 15, g = lane >> 4;

  cfa[tid] = coef[tid];
  cfc[tid] = coef[C1_ + tid];

  f32x4 acc[4][4];
  #pragma unroll
  for (int i = 0; i < 4; ++i)
    #pragma unroll
    for (int j = 0; j < 4; ++j) acc[i][j] = (f32x4){0.f, 0.f, 0.f, 0.f};

  auto STAGE_A = [&](int buf, int c) {
    const u16* asrc = W1b + ((size_t)c * C2_) * 32;
    #pragma unroll
    for (int i2 = 0; i2 < 2; ++i2) {
      const int i = wid * 2 + i2;
      gld16(asrc + i * 512 + lane * 8, &sm.p.As[buf][i * 512]);
    }
  };

  uint4 rb[2];
  auto BLOAD = [&](int c) {
    const u16* bsrc = y0b + (((size_t)bz * 8 + c) * N_ + n0) * 32 + tid * 8;
    rb[0] = *(const uint4*)bsrc;
    rb[1] = *(const uint4*)(bsrc + 2048);
  };
  auto BWRITE = [&](int buf, int c) {
    const int ch = c * 32 + (tid & 3) * 8;
    float a0 = cfa[ch + 0], a1 = cfa[ch + 1], a2 = cfa[ch + 2], a3 = cfa[ch + 3];
    float a4 = cfa[ch + 4], a5 = cfa[ch + 5], a6 = cfa[ch + 6], a7 = cfa[ch + 7];
    float c0 = cfc[ch + 0], c1 = cfc[ch + 1], c2 = cfc[ch + 2], c3 = cfc[ch + 3];
    float c4 = cfc[ch + 4], c5 = cfc[ch + 5], c6 = cfc[ch + 6], c7 = cfc[ch + 7];
    #pragma unroll
    for (int h = 0; h < 2; ++h) {
      uint4 v = rb[h];
      float f0 = fmaxf(0.f, fmaf(bf2f((u16)(v.x & 0xffff)), a0, c0));
      float f1 = fmaxf(0.f, fmaf(bf2f((u16)(v.x >> 16)),    a1, c1));
      float f2 = fmaxf(0.f, fmaf(bf2f((u16)(v.y & 0xffff)), a2, c2));
      float f3 = fmaxf(0.f, fmaf(bf2f((u16)(v.y >> 16)),    a3, c3));
      float f4 = fmaxf(0.f, fmaf(bf2f((u16)(v.z & 0xffff)), a4, c4));
      float f5 = fmaxf(0.f, fmaf(bf2f((u16)(v.z >> 16)),    a5, c5));
      float f6 = fmaxf(0.f, fmaf(bf2f((u16)(v.w & 0xffff)), a6, c6));
      float f7 = fmaxf(0.f, fmaf(bf2f((u16)(v.w >> 16)),    a7, c7));
      uint4 o;
      o.x = (unsigned int)f2bf(f0) | ((unsigned int)f2bf(f1) << 16);
      o.y = (unsigned int)f2bf(f2) | ((unsigned int)f2bf(f3) << 16);
      o.z = (unsigned int)f2bf(f4) | ((unsigned int)f2bf(f5) << 16);
      o.w = (unsigned int)f2bf(f6) | ((unsigned int)f2bf(f7) << 16);
      *(uint4*)&sm.p.Bs[buf][h * 2048 + tid * 8] = o;
    }
  };

  BLOAD(0);
  STAGE_A(0, 0);
  __syncthreads();            // cfa/cfc ready (also A tile landing)
  BWRITE(0, 0);
  __syncthreads();            // tile 0 fully ready

  for (int kt = 0; kt < 8; ++kt) {
    const int cur = kt & 1;
    if (kt < 7) { STAGE_A(cur ^ 1, kt + 1); BLOAD(kt + 1); }

    bf16x8 af[4], bfv[4];
    #pragma unroll
    for (int f = 0; f < 4; ++f)
      af[f] = __builtin_bit_cast(bf16x8,
          *(const short8_*)&sm.p.As[cur][(wo * 64 + f * 16 + m) * 32 + g * 8]);
    #pragma unroll
    for (int f = 0; f < 4; ++f)
      bfv[f] = __builtin_bit_cast(bf16x8,
          *(const short8_*)&sm.p.Bs[cur][(wn * 64 + f * 16 + m) * 32 + g * 8]);
    #pragma unroll
    for (int i = 0; i < 4; ++i)
      #pragma unroll
      for (int j = 0; j < 4; ++j)
        acc[i][j] = __builtin_amdgcn_mfma_f32_16x16x32_bf16(af[i], bfv[j], acc[i][j], 0, 0, 0);

    if (kt < 7) BWRITE(cur ^ 1, kt + 1);
    __syncthreads();
  }

  const int slot = (blockIdx.x * 8 + bz) * 2 + wn;   // 0..1023 unique
  float* prow = partials + (size_t)slot * 256;

  #pragma unroll
  for (int of = 0; of < 4; ++of) {
    const int pb = wo * 64 + of * 16 + g * 4;
    float bias[4], s1[4], s2[4];
    #pragma unroll
    for (int r = 0; r < 4; ++r) { bias[r] = b1[pb + r]; s1[r] = 0.f; s2[r] = 0.f; }
    #pragma unroll
    for (int nf = 0; nf < 4; ++nf) {
      const int nl = wn * 64 + nf * 16 + m;
      #pragma unroll
      for (int r = 0; r < 4; ++r) {
        float y = acc[of][nf][r] + bias[r];
        s1[r] += y; s2[r] += y * y;
        sm.stage[pb + r][nl] = f2bf(y);
      }
    }
    #pragma unroll
    for (int mk = 1; mk < 16; mk <<= 1)
      #pragma unroll
      for (int r = 0; r < 4; ++r) {
        s1[r] += __shfl_xor(s1[r], mk);
        s2[r] += __shfl_xor(s2[r], mk);
      }
    if (m == 0) {
      *(float4*)(prow + pb)        = make_float4(s1[0], s1[1], s1[2], s1[3]);
      *(float4*)(prow + 128 + pb)  = make_float4(s2[0], s2[1], s2[2], s2[3]);
    }
  }
  __syncthreads();
  {
    #pragma unroll
    for (int pass = 0; pass < 8; ++pass) {
      const int idx = pass * 256 + tid;
      const int p = idx >> 4;
      const int c8 = (idx & 15) * 8;
      uint4 v = *(const uint4*)&sm.stage[p][c8];
      *(uint4*)(y1b + ((size_t)bz * C2_ + p) * N_ + n0 + c8) = v;
    }
  }
}

// ---------------------------------------------------------------------------
// final: BN1 + ReLU elementwise, bf16 in -> fp32 out  (y1b is [B][C2][N])
// ---------------------------------------------------------------------------
__global__ __launch_bounds__(256) void final_kernel(
    const u16* __restrict__ y1b, const float* __restrict__ cf, float* __restrict__ out)
{
  const size_t total4 = (size_t)B_ * C2_ * N_ / 4;
  const size_t stride = (size_t)gridDim.x * blockDim.x;
  for (size_t f = (size_t)blockIdx.x * blockDim.x + threadIdx.x; f < total4; f += stride) {
    size_t base = f * 4;
    int p = (int)((base >> 13) & (C2_ - 1));
    float a = cf[p], c = cf[C2_ + p];
    uint2 v = *(const uint2*)(y1b + base);
    float4 r;
    r.x = fmaxf(0.0f, fmaf(bf2f((u16)(v.x & 0xffff)), a, c));
    r.y = fmaxf(0.0f, fmaf(bf2f((u16)(v.x >> 16)),    a, c));
    r.z = fmaxf(0.0f, fmaf(bf2f((u16)(v.y & 0xffff)), a, c));
    r.w = fmaxf(0.0f, fmaf(bf2f((u16)(v.y >> 16)),    a, c));
    *(float4*)(out + base) = r;
  }
}

// ---------------------------------------------------------------------------
extern "C" void kernel_launch(void* const* d_in, const int* in_sizes, int n_in,
                              void* d_out, int out_size, void* d_ws, size_t ws_size,
                              hipStream_t stream)
{
  const float* xyz_sa     = (const float*)d_in[0];
  const float* xyz_now    = (const float*)d_in[1];
  const float* points_sa  = (const float*)d_in[2];
  const float* points_now = (const float*)d_in[3];
  const float* W0  = (const float*)d_in[4];
  const float* b0  = (const float*)d_in[5];
  const float* g0  = (const float*)d_in[6];
  const float* be0 = (const float*)d_in[7];
  const float* W1  = (const float*)d_in[8];
  const float* b1  = (const float*)d_in[9];
  const float* g1  = (const float*)d_in[10];
  const float* be1 = (const float*)d_in[11];

  const size_t MB = 1048576ull;
  char* base = (char*)d_ws;
  u16*   xcat  = (u16*)(base + 0);            // [B][12][N][32] bf16  48MB
  float* pnT   = (float*)(base + 48 * MB);    // [B][S][256] f32      16MB (dead after knn)
  u16*   y1b   = (u16*)(base + 48 * MB);      // [B][C2][N] bf16      16MB (overlays pnT)
  u16*   y0b   = (u16*)(base + 64 * MB);      // [B][8][N][32] bf16   32MB
  u16*   W0b   = (u16*)(base + 96 * MB);      // [12][256][32] bf16
  u16*   W1b   = (u16*)(base + 96 * MB + 512 * 1024); // [8][128][32] bf16
  float* coef  = (float*)(base + 97 * MB);    // 768 f
  float* part1 = (float*)(base + 98 * MB);    // [1024][512] f32 2MB
  float* part2 = (float*)(base + 100 * MB);   // [1024][256] f32 1MB
  float* out   = (float*)d_out;

  hipLaunchKernelGGL(prep_kernel, dim3(12800), dim3(256), 0, stream,
                     W0, W0b, W1, W1b, points_now, pnT, points_sa, xcat);
  hipLaunchKernelGGL(knn_interp_kernel, dim3(N_ / 32, B_), dim3(256), 0, stream,
                     xyz_sa, xyz_now, pnT, xcat);
  hipLaunchKernelGGL(gemm1_mfma_kernel, dim3(N_ / 128, 2, B_), dim3(256), 0, stream,
                     xcat, W0b, b0, y0b, part1);
  hipLaunchKernelGGL(reduce_coef_kernel, dim3(C1_), dim3(256), 0, stream,
                     part1, 512, C1_, g0, be0, coef);
  hipLaunchKernelGGL(gemm2_mfma_kernel, dim3(N_ / 128, 1, B_), dim3(256), 0, stream,
                     y0b, coef, W1b, b1, y1b, part2);
  hipLaunchKernelGGL(reduce_coef_kernel, dim3(C2_), dim3(256), 0, stream,
                     part2, 256, C2_, g1, be1, coef + 512);
  hipLaunchKernelGGL(final_kernel, dim3(2048), dim3(256), 0, stream,
                     y1b, coef + 512, out);
}

// Round 18
// 161.611 us; speedup vs baseline: 2.6918x; 1.0312x over previous
//
#include <hip/hip_runtime.h>

#define B_ 8
#define N_ 8192
#define S_ 2048
#define D1_ 128
#define D2_ 256
#define C0_ 384
#define C1_ 256
#define C2_ 128
#define BN_EPS 1e-5f

typedef unsigned long long ull;
typedef unsigned short u16;
typedef __bf16 bf16x8 __attribute__((ext_vector_type(8)));
typedef float f32x4 __attribute__((ext_vector_type(4)));
typedef short short8_ __attribute__((ext_vector_type(8)));

__device__ __forceinline__ u16 f2bf(float x) {
  unsigned int u = __float_as_uint(x);
  unsigned int r = u + 0x7fffu + ((u >> 16) & 1u);
  return (u16)(r >> 16);
}
__device__ __forceinline__ float bf2f(u16 h) {
  return __uint_as_float(((unsigned int)h) << 16);
}

// async global->LDS DMA, 16B/lane; wave-contiguous 1KB source panels.
__device__ __forceinline__ void gld16(const void* g, void* l) {
  __builtin_amdgcn_global_load_lds(
      (const __attribute__((address_space(1))) void*)g,
      (__attribute__((address_space(3))) void*)l,
      16, 0, 0);
}

// branchless sorted top-3 insert on (f32 d, i32 idx); strict < keeps earlier.
// Pure cndmask form — measured fastest (r14/r16: 79us; med3 variant: 84.5us,
// broke cmp/cndmask dual-issue pairing). Do not "optimize" with med3.
__device__ __forceinline__ void insf(float d, int i,
    float& D0, int& I0, float& D1, int& I1, float& D2, int& I2) {
  bool c2 = d < D2, c1 = d < D1, c0 = d < D0;
  D2 = c1 ? D1 : (c2 ? d : D2);  I2 = c1 ? I1 : (c2 ? i : I2);
  D1 = c0 ? D0 : (c1 ? d : D1);  I1 = c0 ? I0 : (c1 ? i : I1);
  D0 = c0 ? d : D0;              I0 = c0 ? i : I0;
}

// ---------------------------------------------------------------------------
// prep: fused weight-convert (k-chunked) + pnT transpose + psaT transpose.
// flat grid: [0,384) cvt W0; [384,512) cvt W1; [512,4608) transpose pnT;
// [4608,12800) psaT.
// ---------------------------------------------------------------------------
__global__ __launch_bounds__(256) void prep_kernel(
    const float* __restrict__ W0, u16* __restrict__ W0b,
    const float* __restrict__ W1, u16* __restrict__ W1b,
    const float* __restrict__ points_now, float* __restrict__ pnT,
    const float* __restrict__ points_sa, u16* __restrict__ xcat)
{
  const int bid = blockIdx.x;
  const int tid = threadIdx.x;

  if (bid < 384) {                       // W0 [256][384] -> [12][256][32]
    int i = bid * 256 + tid;
    int o = i / C0_, kk = i - o * C0_;
    W0b[(((size_t)(kk >> 5) * C1_ + o) << 5) + (kk & 31)] = f2bf(W0[i]);
    return;
  }
  if (bid < 512) {                       // W1 [128][256] -> [8][128][32]
    int i = (bid - 384) * 256 + tid;
    int o = i / C1_, kk = i - o * C1_;
    W1b[(((size_t)(kk >> 5) * C2_ + o) << 5) + (kk & 31)] = f2bf(W1[i]);
    return;
  }

  __shared__ float tile[32][33];
  const int tx = tid & 31, ty = tid >> 5;

  if (bid < 4608) {                      // points_now [B][D2][S] -> pnT [B][S][D2]
    const int f  = bid - 512;            // (64, 8, 8)
    const int s0 = (f & 63) * 32;
    const int d0 = ((f >> 6) & 7) * 32;
    const int b  = f >> 9;
    const float* inb = points_now + ((size_t)b * D2_ + d0) * S_ + s0;
    #pragma unroll
    for (int r = 0; r < 4; ++r) {
      int d = r * 8 + ty;
      tile[d][tx] = inb[(size_t)d * S_ + tx];
    }
    __syncthreads();
    float* outb = pnT + ((size_t)b * S_ + s0) * D2_ + d0;
    #pragma unroll
    for (int r = 0; r < 4; ++r) {
      int s = r * 8 + ty;
      outb[(size_t)s * D2_ + tx] = tile[tx][s];
    }
    return;
  }

  {                                      // points_sa [B][D1][N] -> xcat chunks 0..3
    const int f  = bid - 4608;           // (256, 4, 8)
    const int n0 = (f & 255) * 32;
    const int d0 = ((f >> 8) & 3) * 32;
    const int b  = f >> 10;
    const float* inb = points_sa + ((size_t)b * D1_ + d0) * N_ + n0;
    #pragma unroll
    for (int r = 0; r < 4; ++r) {
      int d = r * 8 + ty;
      tile[d][tx] = inb[(size_t)d * N_ + tx];
    }
    __syncthreads();
    u16* outb = xcat + (((size_t)b * 12 + (d0 >> 5)) * N_ + n0) * 32;
    #pragma unroll
    for (int r = 0; r < 4; ++r) {
      int n = r * 8 + ty;
      outb[(size_t)n * 32 + tx] = f2bf(tile[tx][n]);
    }
  }
}

// ---------------------------------------------------------------------------
// K1: 3-NN + interpolation. 32 queries/block, 2048 blocks, 8 blocks/CU.
// Scan key d_rel = |p|^2 - 2 q.p; cndmask (d,idx) insert (r14 form).
// ---------------------------------------------------------------------------
__global__ __launch_bounds__(256) void knn_interp_kernel(
    const float* __restrict__ xyz_sa, const float* __restrict__ xyz_now,
    const float* __restrict__ pnT, u16* __restrict__ xcat)
{
  __shared__ float4 sp[1024];
  __shared__ int   s_idx[32][3];
  __shared__ float s_w[32][3];

  const int b  = blockIdx.y;
  const int n0 = blockIdx.x * 32;

  const int qg = threadIdx.x >> 4;   // 0..15 query group (2 queries)
  const int t  = threadIdx.x & 15;   // scanner 0..15
  const int nb = n0 + qg * 2;

  const float* xq = xyz_sa + (size_t)b * 3 * N_;
  float qx[2], qy[2], qz[2], qq[2];
  #pragma unroll
  for (int w = 0; w < 2; ++w) {
    int n = nb + w;
    qx[w] = xq[n]; qy[w] = xq[N_ + n]; qz[w] = xq[2 * N_ + n];
    qq[w] = qx[w] * qx[w] + qy[w] * qy[w] + qz[w] * qz[w];
  }

  float D0[2], D1[2], D2[2];
  int   I0[2], I1[2], I2[2];
  #pragma unroll
  for (int w = 0; w < 2; ++w) {
    D0[w] = 3.4e38f; D1[w] = 3.4e38f; D2[w] = 3.4e38f;
    I0[w] = 0; I1[w] = 0; I2[w] = 0;
  }

  const float* xb = xyz_now + (size_t)b * 3 * S_;
  for (int chunk = 0; chunk < 2; ++chunk) {
    const int sbase = chunk << 10;
    for (int i = threadIdx.x; i < 1024; i += 256) {
      int sg = sbase + i;
      float px = xb[sg], py = xb[S_ + sg], pz = xb[2 * S_ + sg];
      sp[i] = make_float4(-2.f * px, -2.f * py, -2.f * pz,
                          px * px + py * py + pz * pz);
    }
    __syncthreads();

    #pragma unroll 4
    for (int it = 0; it < 64; ++it) {
      int sl = (it << 4) | t;
      float4 p = sp[sl];
      int sg = sbase + sl;
      #pragma unroll
      for (int w = 0; w < 2; ++w) {
        float d = fmaf(p.x, qx[w], fmaf(p.y, qy[w], fmaf(p.z, qz[w], p.w)));
        insf(d, sg, D0[w], I0[w], D1[w], I1[w], D2[w], I2[w]);
      }
    }
    __syncthreads();   // protect sp before next chunk's staging
  }

  // merge the 16 scanners via shuffle butterfly (stays within 16-lane group)
  #pragma unroll
  for (int m = 1; m <= 8; m <<= 1) {
    #pragma unroll
    for (int w = 0; w < 2; ++w) {
      float e0 = __shfl_xor(D0[w], m), e1 = __shfl_xor(D1[w], m), e2 = __shfl_xor(D2[w], m);
      int   j0 = __shfl_xor(I0[w], m), j1 = __shfl_xor(I1[w], m), j2 = __shfl_xor(I2[w], m);
      insf(e0, j0, D0[w], I0[w], D1[w], I1[w], D2[w], I2[w]);
      insf(e1, j1, D0[w], I0[w], D1[w], I1[w], D2[w], I2[w]);
      insf(e2, j2, D0[w], I0[w], D1[w], I1[w], D2[w], I2[w]);
    }
  }

  if (t == 0) {
    #pragma unroll
    for (int w = 0; w < 2; ++w) {
      float d0 = D0[w] + qq[w];
      float d1 = D1[w] + qq[w];
      float d2 = D2[w] + qq[w];
      float r0 = 1.0f / (d0 + 1e-8f);
      float r1 = 1.0f / (d1 + 1e-8f);
      float r2 = 1.0f / (d2 + 1e-8f);
      float rs = 1.0f / (r0 + r1 + r2);
      int qi = qg * 2 + w;
      s_idx[qi][0] = I0[w];
      s_idx[qi][1] = I1[w];
      s_idx[qi][2] = I2[w];
      s_w[qi][0] = r0 * rs; s_w[qi][1] = r1 * rs; s_w[qi][2] = r2 * rs;
    }
  }
  __syncthreads();

  // Phase 2: wave-per-query gather; lane covers chunk 4+(l>>3), 4 channels.
  const int wave = threadIdx.x >> 6;
  const int lane = threadIdx.x & 63;
  const int c8 = lane >> 3;
  const int k4 = (lane & 7) * 4;
  const float* pb = pnT + (size_t)b * S_ * D2_ + c8 * 32 + k4;
  u16* ob = xcat + (((size_t)b * 12 + 4 + c8) * N_ + n0) * 32 + k4;
  #pragma unroll 2
  for (int i = 0; i < 8; ++i) {
    const int qi = wave * 8 + i;
    const int j0 = s_idx[qi][0], j1 = s_idx[qi][1], j2 = s_idx[qi][2];
    const float w0 = s_w[qi][0], w1 = s_w[qi][1], w2 = s_w[qi][2];
    float4 f0 = *(const float4*)(pb + (size_t)j0 * D2_);
    float4 f1 = *(const float4*)(pb + (size_t)j1 * D2_);
    float4 f2 = *(const float4*)(pb + (size_t)j2 * D2_);
    float rx = w0 * f0.x + w1 * f1.x + w2 * f2.x;
    float ry = w0 * f0.y + w1 * f1.y + w2 * f2.y;
    float rz = w0 * f0.z + w1 * f1.z + w2 * f2.z;
    float rw = w0 * f0.w + w1 * f1.w + w2 * f2.w;
    unsigned int lo = (unsigned int)f2bf(rx) | ((unsigned int)f2bf(ry) << 16);
    unsigned int hi = (unsigned int)f2bf(rz) | ((unsigned int)f2bf(rw) << 16);
    *(uint2*)(ob + (size_t)qi * 32) = make_uint2(lo, hi);
  }
}

// ---------------------------------------------------------------------------
union SMg {
  struct { u16 As[2][4096]; u16 Bs[2][4096]; } p;   // [128 rows][32 k] x dbuf
  u16 stage[128][136];
};

// ---------------------------------------------------------------------------
// GEMM1: y0[b,n,o] = W0 . xcat + b0. NO atomics: per-(block,wn) partial
// sums stored to unique slots; reduced later.
// partials1: [1024 slots][512]  (cols 0..255 sum, 256..511 sumsq)
// ---------------------------------------------------------------------------
__global__ __launch_bounds__(256) void gemm1_mfma_kernel(
    const u16* __restrict__ xcat, const u16* __restrict__ W0b,
    const float* __restrict__ b0, u16* __restrict__ y0b, float* __restrict__ partials)
{
  __shared__ SMg sm;

  const int bz = blockIdx.z;
  const int n0 = blockIdx.x * 128;
  const int o0 = blockIdx.y * 128;
  const int tid = threadIdx.x;
  const int wid = tid >> 6, lane = tid & 63;
  const int wo = wid & 1, wn = wid >> 1;
  const int m = lane & 15, g = lane >> 4;

  f32x4 acc[4][4];
  #pragma unroll
  for (int i = 0; i < 4; ++i)
    #pragma unroll
    for (int j = 0; j < 4; ++j) acc[i][j] = (f32x4){0.f, 0.f, 0.f, 0.f};

  auto STAGE = [&](int buf, int c) {
    const u16* asrc = W0b  + ((size_t)c * C1_ + o0) * 32;
    const u16* bsrc = xcat + (((size_t)bz * 12 + c) * N_ + n0) * 32;
    #pragma unroll
    for (int i2 = 0; i2 < 2; ++i2) {
      const int i = wid * 2 + i2;
      gld16(asrc + i * 512 + lane * 8, &sm.p.As[buf][i * 512]);
      gld16(bsrc + i * 512 + lane * 8, &sm.p.Bs[buf][i * 512]);
    }
  };

  STAGE(0, 0);
  __syncthreads();

  for (int kt = 0; kt < 12; ++kt) {
    const int cur = kt & 1;
    if (kt < 11) STAGE(cur ^ 1, kt + 1);

    bf16x8 af[4], bfv[4];
    #pragma unroll
    for (int f = 0; f < 4; ++f)
      af[f] = __builtin_bit_cast(bf16x8,
          *(const short8_*)&sm.p.As[cur][(wo * 64 + f * 16 + m) * 32 + g * 8]);
    #pragma unroll
    for (int f = 0; f < 4; ++f)
      bfv[f] = __builtin_bit_cast(bf16x8,
          *(const short8_*)&sm.p.Bs[cur][(wn * 64 + f * 16 + m) * 32 + g * 8]);
    #pragma unroll
    for (int i = 0; i < 4; ++i)
      #pragma unroll
      for (int j = 0; j < 4; ++j)
        acc[i][j] = __builtin_amdgcn_mfma_f32_16x16x32_bf16(af[i], bfv[j], acc[i][j], 0, 0, 0);

    __syncthreads();
  }

  const int slot = (blockIdx.x * 8 + bz) * 2 + wn;   // 0..1023 unique
  float* prow = partials + (size_t)slot * 512;

  #pragma unroll
  for (int of = 0; of < 4; ++of) {
    const int ol = wo * 64 + of * 16 + g * 4;
    const int ob = o0 + ol;
    float bias[4], s1[4], s2[4];
    #pragma unroll
    for (int r = 0; r < 4; ++r) { bias[r] = b0[ob + r]; s1[r] = 0.f; s2[r] = 0.f; }
    #pragma unroll
    for (int nf = 0; nf < 4; ++nf) {
      const int nl = wn * 64 + nf * 16 + m;
      float y[4];
      #pragma unroll
      for (int r = 0; r < 4; ++r) {
        y[r] = acc[of][nf][r] + bias[r];
        s1[r] += y[r]; s2[r] += y[r] * y[r];
      }
      unsigned int lo = (unsigned int)f2bf(y[0]) | ((unsigned int)f2bf(y[1]) << 16);
      unsigned int hi = (unsigned int)f2bf(y[2]) | ((unsigned int)f2bf(y[3]) << 16);
      *(uint2*)&sm.stage[nl][ol] = make_uint2(lo, hi);
    }
    #pragma unroll
    for (int mk = 1; mk < 16; mk <<= 1)
      #pragma unroll
      for (int r = 0; r < 4; ++r) {
        s1[r] += __shfl_xor(s1[r], mk);
        s2[r] += __shfl_xor(s2[r], mk);
      }
    if (m == 0) {
      *(float4*)(prow + ob)        = make_float4(s1[0], s1[1], s1[2], s1[3]);
      *(float4*)(prow + 256 + ob)  = make_float4(s2[0], s2[1], s2[2], s2[3]);
    }
  }
  __syncthreads();
  {
    const int rrow = tid >> 4;
    const int col  = (tid & 15) * 8;
    const int c    = (o0 + col) >> 5;
    const int ko   = (o0 + col) & 31;
    u16* dst = y0b + (((size_t)bz * 8 + c) * N_ + n0) * 32 + ko;
    #pragma unroll
    for (int pass = 0; pass < 8; ++pass) {
      const int r = pass * 16 + rrow;
      *(uint4*)(dst + (size_t)r * 32) = *(const uint4*)&sm.stage[r][col];
    }
  }
}

// ---------------------------------------------------------------------------
// reduce partials -> BN coef. grid = C blocks; partial row width R floats.
// ---------------------------------------------------------------------------
__global__ __launch_bounds__(256) void reduce_coef_kernel(
    const float* __restrict__ partials, int R, int C,
    const float* __restrict__ g, const float* __restrict__ be,
    float* __restrict__ coef)
{
  const int ch = blockIdx.x;
  const int tid = threadIdx.x;
  float s = 0.f, q = 0.f;
  #pragma unroll
  for (int k = 0; k < 4; ++k) {
    const float* row = partials + (size_t)(tid + k * 256) * R;
    s += row[ch];
    q += row[C + ch];
  }
  #pragma unroll
  for (int mk = 1; mk < 64; mk <<= 1) { s += __shfl_xor(s, mk); q += __shfl_xor(q, mk); }
  __shared__ float ls[4], lq[4];
  const int wid = tid >> 6;
  if ((tid & 63) == 0) { ls[wid] = s; lq[wid] = q; }
  __syncthreads();
  if (tid == 0) {
    s = ls[0] + ls[1] + ls[2] + ls[3];
    q = lq[0] + lq[1] + lq[2] + lq[3];
    const float invM = 1.0f / 65536.0f;   // B*N
    float mean = s * invM;
    float var  = q * invM - mean * mean;
    float a = g[ch] / sqrtf(var + BN_EPS);
    float c = be[ch] - mean * a;
    coef[ch] = a;
    coef[C + ch] = c;
  }
}

// ---------------------------------------------------------------------------
// GEMM2 (BN0+ReLU fused into B-staging): y1b[b,p,n] = W1 . relu(bn0(y0)) + b1
// ---------------------------------------------------------------------------
__global__ __launch_bounds__(256) void gemm2_mfma_kernel(
    const u16* __restrict__ y0b, const float* __restrict__ coef,
    const u16* __restrict__ W1b, const float* __restrict__ b1,
    u16* __restrict__ y1b, float* __restrict__ partials)
{
  __shared__ SMg sm;
  __shared__ float cfa[C1_], cfc[C1_];

  const int bz = blockIdx.z;
  const int n0 = blockIdx.x * 128;
  const int tid = threadIdx.x;
  const int wid = tid >> 6, lane = tid & 63;
  const int wo = wid & 1, wn = wid >> 1;
  const int m = lane & 15, g = lane >> 4;

  cfa[tid] = coef[tid];
  cfc[tid] = coef[C1_ + tid];

  f32x4 acc[4][4];
  #pragma unroll
  for (int i = 0; i < 4; ++i)
    #pragma unroll
    for (int j = 0; j < 4; ++j) acc[i][j] = (f32x4){0.f, 0.f, 0.f, 0.f};

  auto STAGE_A = [&](int buf, int c) {
    const u16* asrc = W1b + ((size_t)c * C2_) * 32;
    #pragma unroll
    for (int i2 = 0; i2 < 2; ++i2) {
      const int i = wid * 2 + i2;
      gld16(asrc + i * 512 + lane * 8, &sm.p.As[buf][i * 512]);
    }
  };

  uint4 rb[2];
  auto BLOAD = [&](int c) {
    const u16* bsrc = y0b + (((size_t)bz * 8 + c) * N_ + n0) * 32 + tid * 8;
    rb[0] = *(const uint4*)bsrc;
    rb[1] = *(const uint4*)(bsrc + 2048);
  };
  auto BWRITE = [&](int buf, int c) {
    const int ch = c * 32 + (tid & 3) * 8;
    float a0 = cfa[ch + 0], a1 = cfa[ch + 1], a2 = cfa[ch + 2], a3 = cfa[ch + 3];
    float a4 = cfa[ch + 4], a5 = cfa[ch + 5], a6 = cfa[ch + 6], a7 = cfa[ch + 7];
    float c0 = cfc[ch + 0], c1 = cfc[ch + 1], c2 = cfc[ch + 2], c3 = cfc[ch + 3];
    float c4 = cfc[ch + 4], c5 = cfc[ch + 5], c6 = cfc[ch + 6], c7 = cfc[ch + 7];
    #pragma unroll
    for (int h = 0; h < 2; ++h) {
      uint4 v = rb[h];
      float f0 = fmaxf(0.f, fmaf(bf2f((u16)(v.x & 0xffff)), a0, c0));
      float f1 = fmaxf(0.f, fmaf(bf2f((u16)(v.x >> 16)),    a1, c1));
      float f2 = fmaxf(0.f, fmaf(bf2f((u16)(v.y & 0xffff)), a2, c2));
      float f3 = fmaxf(0.f, fmaf(bf2f((u16)(v.y >> 16)),    a3, c3));
      float f4 = fmaxf(0.f, fmaf(bf2f((u16)(v.z & 0xffff)), a4, c4));
      float f5 = fmaxf(0.f, fmaf(bf2f((u16)(v.z >> 16)),    a5, c5));
      float f6 = fmaxf(0.f, fmaf(bf2f((u16)(v.w & 0xffff)), a6, c6));
      float f7 = fmaxf(0.f, fmaf(bf2f((u16)(v.w >> 16)),    a7, c7));
      uint4 o;
      o.x = (unsigned int)f2bf(f0) | ((unsigned int)f2bf(f1) << 16);
      o.y = (unsigned int)f2bf(f2) | ((unsigned int)f2bf(f3) << 16);
      o.z = (unsigned int)f2bf(f4) | ((unsigned int)f2bf(f5) << 16);
      o.w = (unsigned int)f2bf(f6) | ((unsigned int)f2bf(f7) << 16);
      *(uint4*)&sm.p.Bs[buf][h * 2048 + tid * 8] = o;
    }
  };

  BLOAD(0);
  STAGE_A(0, 0);
  __syncthreads();            // cfa/cfc ready (also A tile landing)
  BWRITE(0, 0);
  __syncthreads();            // tile 0 fully ready

  for (int kt = 0; kt < 8; ++kt) {
    const int cur = kt & 1;
    if (kt < 7) { STAGE_A(cur ^ 1, kt + 1); BLOAD(kt + 1); }

    bf16x8 af[4], bfv[4];
    #pragma unroll
    for (int f = 0; f < 4; ++f)
      af[f] = __builtin_bit_cast(bf16x8,
          *(const short8_*)&sm.p.As[cur][(wo * 64 + f * 16 + m) * 32 + g * 8]);
    #pragma unroll
    for (int f = 0; f < 4; ++f)
      bfv[f] = __builtin_bit_cast(bf16x8,
          *(const short8_*)&sm.p.Bs[cur][(wn * 64 + f * 16 + m) * 32 + g * 8]);
    #pragma unroll
    for (int i = 0; i < 4; ++i)
      #pragma unroll
      for (int j = 0; j < 4; ++j)
        acc[i][j] = __builtin_amdgcn_mfma_f32_16x16x32_bf16(af[i], bfv[j], acc[i][j], 0, 0, 0);

    if (kt < 7) BWRITE(cur ^ 1, kt + 1);
    __syncthreads();
  }

  const int slot = (blockIdx.x * 8 + bz) * 2 + wn;   // 0..1023 unique
  float* prow = partials + (size_t)slot * 256;

  #pragma unroll
  for (int of = 0; of < 4; ++of) {
    const int pb = wo * 64 + of * 16 + g * 4;
    float bias[4], s1[4], s2[4];
    #pragma unroll
    for (int r = 0; r < 4; ++r) { bias[r] = b1[pb + r]; s1[r] = 0.f; s2[r] = 0.f; }
    #pragma unroll
    for (int nf = 0; nf < 4; ++nf) {
      const int nl = wn * 64 + nf * 16 + m;
      #pragma unroll
      for (int r = 0; r < 4; ++r) {
        float y = acc[of][nf][r] + bias[r];
        s1[r] += y; s2[r] += y * y;
        sm.stage[pb + r][nl] = f2bf(y);
      }
    }
    #pragma unroll
    for (int mk = 1; mk < 16; mk <<= 1)
      #pragma unroll
      for (int r = 0; r < 4; ++r) {
        s1[r] += __shfl_xor(s1[r], mk);
        s2[r] += __shfl_xor(s2[r], mk);
      }
    if (m == 0) {
      *(float4*)(prow + pb)        = make_float4(s1[0], s1[1], s1[2], s1[3]);
      *(float4*)(prow + 128 + pb)  = make_float4(s2[0], s2[1], s2[2], s2[3]);
    }
  }
  __syncthreads();
  {
    #pragma unroll
    for (int pass = 0; pass < 8; ++pass) {
      const int idx = pass * 256 + tid;
      const int p = idx >> 4;
      const int c8 = (idx & 15) * 8;
      uint4 v = *(const uint4*)&sm.stage[p][c8];
      *(uint4*)(y1b + ((size_t)bz * C2_ + p) * N_ + n0 + c8) = v;
    }
  }
}

// ---------------------------------------------------------------------------
// final: BN1 + ReLU elementwise, bf16 in -> fp32 out  (y1b is [B][C2][N])
// ---------------------------------------------------------------------------
__global__ __launch_bounds__(256) void final_kernel(
    const u16* __restrict__ y1b, const float* __restrict__ cf, float* __restrict__ out)
{
  const size_t total4 = (size_t)B_ * C2_ * N_ / 4;
  const size_t stride = (size_t)gridDim.x * blockDim.x;
  for (size_t f = (size_t)blockIdx.x * blockDim.x + threadIdx.x; f < total4; f += stride) {
    size_t base = f * 4;
    int p = (int)((base >> 13) & (C2_ - 1));
    float a = cf[p], c = cf[C2_ + p];
    uint2 v = *(const uint2*)(y1b + base);
    float4 r;
    r.x = fmaxf(0.0f, fmaf(bf2f((u16)(v.x & 0xffff)), a, c));
    r.y = fmaxf(0.0f, fmaf(bf2f((u16)(v.x >> 16)),    a, c));
    r.z = fmaxf(0.0f, fmaf(bf2f((u16)(v.y & 0xffff)), a, c));
    r.w = fmaxf(0.0f, fmaf(bf2f((u16)(v.y >> 16)),    a, c));
    *(float4*)(out + base) = r;
  }
}

// ---------------------------------------------------------------------------
extern "C" void kernel_launch(void* const* d_in, const int* in_sizes, int n_in,
                              void* d_out, int out_size, void* d_ws, size_t ws_size,
                              hipStream_t stream)
{
  const float* xyz_sa     = (const float*)d_in[0];
  const float* xyz_now    = (const float*)d_in[1];
  const float* points_sa  = (const float*)d_in[2];
  const float* points_now = (const float*)d_in[3];
  const float* W0  = (const float*)d_in[4];
  const float* b0  = (const float*)d_in[5];
  const float* g0  = (const float*)d_in[6];
  const float* be0 = (const float*)d_in[7];
  const float* W1  = (const float*)d_in[8];
  const float* b1  = (const float*)d_in[9];
  const float* g1  = (const float*)d_in[10];
  const float* be1 = (const float*)d_in[11];

  const size_t MB = 1048576ull;
  char* base = (char*)d_ws;
  u16*   xcat  = (u16*)(base + 0);            // [B][12][N][32] bf16  48MB
  float* pnT   = (float*)(base + 48 * MB);    // [B][S][256] f32      16MB (dead after knn)
  u16*   y1b   = (u16*)(base + 48 * MB);      // [B][C2][N] bf16      16MB (overlays pnT)
  u16*   y0b   = (u16*)(base + 64 * MB);      // [B][8][N][32] bf16   32MB
  u16*   W0b   = (u16*)(base + 96 * MB);      // [12][256][32] bf16
  u16*   W1b   = (u16*)(base + 96 * MB + 512 * 1024); // [8][128][32] bf16
  float* coef  = (float*)(base + 97 * MB);    // 768 f
  float* part1 = (float*)(base + 98 * MB);    // [1024][512] f32 2MB
  float* part2 = (float*)(base + 100 * MB);   // [1024][256] f32 1MB
  float* out   = (float*)d_out;

  hipLaunchKernelGGL(prep_kernel, dim3(12800), dim3(256), 0, stream,
                     W0, W0b, W1, W1b, points_now, pnT, points_sa, xcat);
  hipLaunchKernelGGL(knn_interp_kernel, dim3(N_ / 32, B_), dim3(256), 0, stream,
                     xyz_sa, xyz_now, pnT, xcat);
  hipLaunchKernelGGL(gemm1_mfma_kernel, dim3(N_ / 128, 2, B_), dim3(256), 0, stream,
                     xcat, W0b, b0, y0b, part1);
  hipLaunchKernelGGL(reduce_coef_kernel, dim3(C1_), dim3(256), 0, stream,
                     part1, 512, C1_, g0, be0, coef);
  hipLaunchKernelGGL(gemm2_mfma_kernel, dim3(N_ / 128, 1, B_), dim3(256), 0, stream,
                     y0b, coef, W1b, b1, y1b, part2);
  hipLaunchKernelGGL(reduce_coef_kernel, dim3(C2_), dim3(256), 0, stream,
                     part2, 256, C2_, g1, be1, coef + 512);
  hipLaunchKernelGGL(final_kernel, dim3(2048), dim3(256), 0, stream,
                     y1b, coef + 512, out);
}